// Round 9
// baseline (475.866 us; speedup 1.0000x reference)
//
#include <hip/hip_runtime.h>
#include <hip/hip_bf16.h>
#include <math.h>

// Problem constants
#define BB   64
#define SS   1024
#define S1C  1025
#define DD   64
#define NHD  4
#define NBH  (BB * NHD)      // 256
#define DHD  16
#define DFFC 256
#define NLAY 3
#define NTOK (BB * S1C)      // 65600 = 32 * 2050
#define SPAD 1056            // padded key/seq length (66 * 16)
#define TGRP3 6              // tile-triple groups: wave covers t0, t0+22, t0+44
#define FTQ   32             // tokens per block (k_encqkv) - 2 token-tiles/wave
#define FT2   32             // tokens per block (k_block) - 2 token-tiles/wave
#define OPAD 68              // ot row stride in floats (ys overlays at 136 shorts)
#define QSCL 0.36067376022224085f   // 0.25 * log2(e) folded into q

typedef const float* fp;
typedef __attribute__((ext_vector_type(8))) short bf16x8;
typedef __attribute__((ext_vector_type(4))) float f32x4;
typedef __attribute__((ext_vector_type(2))) unsigned int u32x2;
typedef __attribute__((ext_vector_type(4))) unsigned int u32x4;

#if __has_builtin(__builtin_amdgcn_exp2f)
#define RAW_EXP2(x) __builtin_amdgcn_exp2f(x)
#else
#define RAW_EXP2(x) __expf(0.6931471805599453f * (x))
#endif
#if __has_builtin(__builtin_amdgcn_rcpf)
#define RAW_RCP(x) __builtin_amdgcn_rcpf(x)
#else
#define RAW_RCP(x) (1.0f / (x))
#endif

__device__ __forceinline__ float gelu_exact(float x) {
    return 0.5f * x * (1.0f + erff(x * 0.7071067811865475f));
}
// A&S 7.1.26 erf approximation, |err| <= 1.5e-7 (<< bf16 rounding noise)
__device__ __forceinline__ float erf_fast(float x) {
    float ax = fabsf(x);
    float t = RAW_RCP(1.0f + 0.3275911f * ax);
    float p = t * (0.254829592f + t * (-0.284496736f + t * (1.421413741f +
              t * (-1.453152027f + t * 1.061405429f))));
    float e = RAW_EXP2(ax * ax * -1.4426950408889634f);
    float r = 1.0f - p * e;
    return copysignf(r, x);
}
__device__ __forceinline__ float gelu_fast(float x) {
    return 0.5f * x * (1.0f + erf_fast(x * 0.7071067811865475f));
}
// RTNE float->bf16 (finite values), 3 ops
__device__ __forceinline__ short f2b(float f) {
    unsigned u = __float_as_uint(f);
    return (short)((u + 0x7fffu + ((u >> 16) & 1u)) >> 16);
}

// pack 4 fp32 exp results -> 4 bf16 in one u32x2 via v_cvt_pk_bf16_f32
__device__ __forceinline__ u32x2 pack4exp(f32x4 c, bool valid) {
    float e0 = valid ? RAW_EXP2(c[0]) : 0.f;
    float e1 = valid ? RAW_EXP2(c[1]) : 0.f;
    float e2 = valid ? RAW_EXP2(c[2]) : 0.f;
    float e3 = valid ? RAW_EXP2(c[3]) : 0.f;
    unsigned r0, r1;
    asm("v_cvt_pk_bf16_f32 %0, %1, %2" : "=v"(r0) : "v"(e0), "v"(e1));
    asm("v_cvt_pk_bf16_f32 %0, %1, %2" : "=v"(r1) : "v"(e2), "v"(e3));
    return (u32x2){r0, r1};
}
// pack 4 fp32 -> 4 bf16 via cvt_pk (RTNE)
__device__ __forceinline__ u32x2 pack4cvt(float x0, float x1, float x2, float x3) {
    unsigned r0, r1;
    asm("v_cvt_pk_bf16_f32 %0, %1, %2" : "=v"(r0) : "v"(x0), "v"(x1));
    asm("v_cvt_pk_bf16_f32 %0, %1, %2" : "=v"(r1) : "v"(x2), "v"(x3));
    return (u32x2){r0, r1};
}

// ---------------------------------------------------------------------------
// Kernel W: one-shot weight convert+transpose to bf16 [n][k] fragments.
// ---------------------------------------------------------------------------
__global__ __launch_bounds__(256) void k_wconv(
    fp wq, fp wk, fp wv, fp wo, fp w1, fp w2,
    short* __restrict__ wqkvT, short* __restrict__ woT,
    short* __restrict__ w1T, short* __restrict__ w2T)
{
    int l = blockIdx.y;
    int i = blockIdx.x * 256 + threadIdx.x;
    if (i < 12288) {
        int p = i >> 12, rem = i & 4095;
        int d = rem >> 6, j = rem & 63;
        fp src = (p == 0 ? wq : p == 1 ? wk : wv) + (size_t)l * 4096;
        float v = src[j * 64 + d];
        if (p == 0) v *= QSCL;
        wqkvT[(size_t)l * 12288 + i] = f2b(v);
    } else if (i < 16384) {
        int rem = i - 12288;
        woT[(size_t)l * 4096 + rem] = f2b(wo[(size_t)l * 4096 + (rem & 63) * 64 + (rem >> 6)]);
    } else if (i < 32768) {
        int rem = i - 16384;
        w1T[(size_t)l * 16384 + rem] = f2b(w1[(size_t)l * 16384 + (rem & 63) * 256 + (rem >> 6)]);
    } else {
        int rem = i - 32768;
        w2T[(size_t)l * 16384 + rem] = f2b(w2[(size_t)l * 16384 + (rem & 255) * 64 + (rem >> 8)]);
    }
}

// ---------------------------------------------------------------------------
// Kernel 0: zero the pad regions of the bf16 q/k/v buffers (rows 1025..1055).
// ---------------------------------------------------------------------------
__global__ __launch_bounds__(64) void k_zero(
    short* __restrict__ qb, short* __restrict__ kb, short* __restrict__ vbt)
{
    int bh = blockIdx.x, t = threadIdx.x;
    for (int i = t; i < 31 * 16; i += 64) {
        int r = i >> 4, c = i & 15;
        size_t idx = ((size_t)bh * SPAD + 1025 + r) * 16 + c;
        qb[idx] = 0; kb[idx] = 0;
    }
    for (int i = t; i < 16 * 31; i += 64) {
        int e = i / 31, c = i % 31;
        vbt[((size_t)bh * 16 + e) * SPAD + 1025 + c] = 0;
    }
}

// ---------------------------------------------------------------------------
// Kernel 1+2 fused (r20): encoder MLP + sos + positional encoding directly
// into an LDS tile (32 tokens), then the layer-0 MFMA Q/K/V projection from
// LDS. Removes the xb global round-trip and one dispatch.
// xs rows padded to 72 shorts (144 B): b128 reads are <=2-way bank aliased.
// ---------------------------------------------------------------------------
__global__ __launch_bounds__(256) void k_encqkv(
    fp in_seq, fp enc_w1, fp enc_b1, fp enc_w2, fp enc_b2, fp sos,
    const short* __restrict__ wqkvT, fp bq, fp bk, fp bv,
    float* __restrict__ x,
    short* __restrict__ qb, short* __restrict__ kb, short* __restrict__ vbt)
{
    int t = threadIdx.x;
    int tok0 = blockIdx.x * FTQ;
    int w = t >> 6, d = t & 63;
    __shared__ float e[4][48];
    __shared__ short xs[FTQ][72];

    // ---- encode phase: 8 passes x 4 tokens (wave w -> token i*4+w) ----
    int i2 = (d >> 1) * 2;
    float factor = RAW_EXP2((float)i2 * (-9.210340371976184f / 64.0f) * 1.4426950408889634f);
    for (int i = 0; i < 8; ++i) {
        int tl = i * 4 + w;
        int tok = tok0 + tl;
        int b = tok / S1C, s = tok % S1C;
        float val;
        if (s == 0) {
            val = sos[d];
        } else {
            float tin = in_seq[b * SS + (s - 1)];
            if (d < 48) e[w][d] = gelu_fast(tin * enc_w1[d] + enc_b1[d]);
            float acc = enc_b2[d];
            for (int j = 0; j < 48; ++j) acc += e[w][j] * enc_w2[j * DD + d];
            val = acc;
        }
        float ang = (float)s * factor;
        val += (d & 1) ? __cosf(ang) : __sinf(ang);
        x[(size_t)tok * DD + d] = val;
        xs[tl][d] = f2b(val);
    }
    __syncthreads();

    // ---- QKV phase (identical to old k_qkv, A-fragments from LDS) ----
    int l = t & 63;
    int quad = l >> 4, lo = l & 15;
    bf16x8 a0 = *(const bf16x8*)&xs[lo][quad * 8];
    bf16x8 a1 = *(const bf16x8*)&xs[lo][32 + quad * 8];
    bf16x8 a2 = *(const bf16x8*)&xs[16 + lo][quad * 8];
    bf16x8 a3 = *(const bf16x8*)&xs[16 + lo][32 + quad * 8];

    int n = w * 16 + lo;
    #pragma unroll
    for (int p = 0; p < 3; ++p) {
        const short* wT = wqkvT + (size_t)p * 4096 + (size_t)n * 64;
        bf16x8 b0 = *(const bf16x8*)(wT + quad * 8);
        bf16x8 b1 = *(const bf16x8*)(wT + 32 + quad * 8);
        f32x4 c0 = __builtin_amdgcn_mfma_f32_16x16x32_bf16(a0, b0, (f32x4){0,0,0,0}, 0, 0, 0);
        c0 = __builtin_amdgcn_mfma_f32_16x16x32_bf16(a1, b1, c0, 0, 0, 0);
        f32x4 c1 = __builtin_amdgcn_mfma_f32_16x16x32_bf16(a2, b0, (f32x4){0,0,0,0}, 0, 0, 0);
        c1 = __builtin_amdgcn_mfma_f32_16x16x32_bf16(a3, b1, c1, 0, 0, 0);
        float bias = (p == 0) ? bq[n] * QSCL : (p == 1) ? bk[n] : bv[n];
        #pragma unroll
        for (int r = 0; r < 4; ++r) {
            int tok = tok0 + quad * 4 + r;
            int bb0 = tok / S1C, ss0 = tok % S1C;
            int bh = bb0 * NHD + w;
            short val = f2b(c0[r] + bias);
            int tok2 = tok + 16;
            int bb1 = tok2 / S1C, ss1 = tok2 % S1C;
            int bh2 = bb1 * NHD + w;
            short val2 = f2b(c1[r] + bias);
            if (p == 0) {
                qb[((size_t)bh * SPAD + ss0) * 16 + lo] = val;
                qb[((size_t)bh2 * SPAD + ss1) * 16 + lo] = val2;
            } else if (p == 1) {
                kb[((size_t)bh * SPAD + ss0) * 16 + lo] = val;
                kb[((size_t)bh2 * SPAD + ss1) * 16 + lo] = val2;
            } else {
                vbt[((size_t)bh * 16 + lo) * SPAD + ss0] = val;
                vbt[((size_t)bh2 * 16 + lo) * SPAD + ss1] = val2;
            }
        }
    }
}

// ---------------------------------------------------------------------------
// Kernel 3: single-pass flash MFMA attention. r22: three q-tiles per wave
// with a SINGLE P buffer. Safety: within STEP(ch) the tr-reads of P(ch-1)
// are issued and fully drained (lgkmcnt(0), memory-clobbered) BEFORE the
// ds_writes of P(ch) issue, and DS ops from one wave process in order — so
// reusing the same buffer cannot clobber in-flight reads, and the next
// STEP's tr-reads (issued after the writes) observe the new data.
// LDS: 4 waves x 3264 B = 13056 B/block (was 26112 double-buffered).
// ---------------------------------------------------------------------------
__global__ __launch_bounds__(256) void k_attn(
    const short* __restrict__ qb, const short* __restrict__ kb,
    const short* __restrict__ vbt, short* __restrict__ ob)
{
    int bid = blockIdx.x;
    int bh  = bid % NBH;           // 6 blocks of a bh share bid%8 (XCD/L2)
    int grp = bid / NBH;           // 0..5
    int b = bh >> 2, h = bh & 3;
    int t = threadIdx.x;
    int w = t >> 6, l = t & 63;
    int quad = l >> 4, lo = l & 15;
    int t0 = grp * 4 + w;          // 0..23
    if (t0 > 21) t0 = 21;          // clamp: duplicate waves write identical data
    int t1 = t0 + 22;              // 22..43
    int t2 = t0 + 44;              // 44..65
    int qg0 = t0 * 16, qg1 = t1 * 16, qg2 = t2 * 16;

    // Per-wave P^T tiles, SINGLE buffer:
    // [wave][t0 1088B | t1 1088B | t2 1088B], subtile pitch 136 B.
    __shared__ u32x2 ptmem[4][408];
    char* ptc = (char*)&ptmem[w][0];
    unsigned ptbase = (unsigned)(uintptr_t)ptc;

    const short* qbase = qb + (size_t)bh * SPAD * 16;
    const short* kbase = kb + (size_t)bh * SPAD * 16;
    const short* vbase = vbt + (size_t)bh * 16 * SPAD;

    bf16x8 aQ0 = {0,0,0,0,0,0,0,0}, aQ1 = {0,0,0,0,0,0,0,0}, aQ2 = {0,0,0,0,0,0,0,0};
    if (quad < 2) {
        aQ0 = *(const bf16x8*)(qbase + ((size_t)(qg0 + lo)) * 16 + quad * 8);
        aQ1 = *(const bf16x8*)(qbase + ((size_t)(qg1 + lo)) * 16 + quad * 8);
        aQ2 = *(const bf16x8*)(qbase + ((size_t)(qg2 + lo)) * 16 + quad * 8);
    }

    const short ONE = 0x3F80;
    bf16x8 aOne = {ONE, ONE, ONE, ONE, ONE, ONE, ONE, ONE};

    f32x4 oc0 = {0.f,0.f,0.f,0.f}, oc1 = {0.f,0.f,0.f,0.f}, oc2 = {0.f,0.f,0.f,0.f};
    f32x4 dn0 = {0.f,0.f,0.f,0.f}, dn1 = {0.f,0.f,0.f,0.f}, dn2 = {0.f,0.f,0.f,0.f};

    // Write byte-offset within a tile: key k0 = lo (k1 = 16+lo is +544).
    unsigned wo0 = (unsigned)((lo >> 2) * 136 + (lo & 3) * 32 + quad * 8);
    // tr-read byte-offset: group quad reads subtile 2*quad (128 B window)
    unsigned ro = (unsigned)(quad * 272 + lo * 8);
    unsigned rdp = ptbase + ro;            // read addr
    char* wbp = ptc + wo0;                 // write base (lane-resolved)

    // Rotating prefetch registers
    bf16x8 kxA, kyA, kxB, kyB, vA, vB;

    // ---- prologue: issue K(0),V(0),K(1); produce P(0) ----
    {
        const short* k0p = kbase + (size_t)lo * 16 + (quad & 1) * 8;
        kxA = *(const bf16x8*)k0p;
        kyA = *(const bf16x8*)(k0p + 256);
        vA  = *(const bf16x8*)(vbase + (size_t)lo * SPAD + quad * 8);
        const short* k1p = kbase + (size_t)(32 + lo) * 16 + (quad & 1) * 8;
        kxB = *(const bf16x8*)k1p;
        kyB = *(const bf16x8*)(k1p + 256);

        f32x4 c0 = __builtin_amdgcn_mfma_f32_16x16x32_bf16(aQ0, kxA, (f32x4){0.f,0.f,0.f,0.f}, 0, 0, 0);
        f32x4 c1 = __builtin_amdgcn_mfma_f32_16x16x32_bf16(aQ1, kxA, (f32x4){0.f,0.f,0.f,0.f}, 0, 0, 0);
        f32x4 c2 = __builtin_amdgcn_mfma_f32_16x16x32_bf16(aQ2, kxA, (f32x4){0.f,0.f,0.f,0.f}, 0, 0, 0);
        *(u32x2*)(wbp)        = pack4exp(c0, true);
        *(u32x2*)(wbp + 1088) = pack4exp(c1, true);
        *(u32x2*)(wbp + 2176) = pack4exp(c2, true);
        c0 = __builtin_amdgcn_mfma_f32_16x16x32_bf16(aQ0, kyA, (f32x4){0.f,0.f,0.f,0.f}, 0, 0, 0);
        c1 = __builtin_amdgcn_mfma_f32_16x16x32_bf16(aQ1, kyA, (f32x4){0.f,0.f,0.f,0.f}, 0, 0, 0);
        c2 = __builtin_amdgcn_mfma_f32_16x16x32_bf16(aQ2, kyA, (f32x4){0.f,0.f,0.f,0.f}, 0, 0, 0);
        *(u32x2*)(wbp + 544)  = pack4exp(c0, true);
        *(u32x2*)(wbp + 1632) = pack4exp(c1, true);
        *(u32x2*)(wbp + 2720) = pack4exp(c2, true);
    }

// Pipelined step: produce chunk CH, consume chunk CH-1. Single P buffer:
// tr-reads (issued first, drained before writes) rely on in-order DS.
#define STEP(CH, TAIL, KXC, KYC, KXN, KYN, VP, VC) do {                       \
    int ch_ = (CH);                                                            \
    if (!(TAIL)) {                                                             \
        const short* kn_ = kbase + (size_t)((ch_ + 1) * 32 + lo) * 16 + (quad & 1) * 8; \
        KXN = *(const bf16x8*)kn_;                                             \
        KYN = *(const bf16x8*)(kn_ + 256);                                     \
    }                                                                          \
    VC = *(const bf16x8*)(vbase + (size_t)lo * SPAD + ch_ * 32 + quad * 8);    \
    u32x2 p00_, p01_, p10_, p11_, p20_, p21_;                                  \
    asm volatile("ds_read_b64_tr_b16 %0, %1"             : "=v"(p00_) : "v"(rdp) : "memory"); \
    asm volatile("ds_read_b64_tr_b16 %0, %1 offset:136"  : "=v"(p01_) : "v"(rdp) : "memory"); \
    asm volatile("ds_read_b64_tr_b16 %0, %1 offset:1088" : "=v"(p10_) : "v"(rdp) : "memory"); \
    asm volatile("ds_read_b64_tr_b16 %0, %1 offset:1224" : "=v"(p11_) : "v"(rdp) : "memory"); \
    asm volatile("ds_read_b64_tr_b16 %0, %1 offset:2176" : "=v"(p20_) : "v"(rdp) : "memory"); \
    asm volatile("ds_read_b64_tr_b16 %0, %1 offset:2312" : "=v"(p21_) : "v"(rdp) : "memory"); \
    u32x2 wt0x_, wt1x_, wt2x_, wt0y_, wt1y_, wt2y_;                            \
    {                                                                          \
        f32x4 c0_ = __builtin_amdgcn_mfma_f32_16x16x32_bf16(aQ0, KXC, (f32x4){0.f,0.f,0.f,0.f}, 0, 0, 0); \
        f32x4 c1_ = __builtin_amdgcn_mfma_f32_16x16x32_bf16(aQ1, KXC, (f32x4){0.f,0.f,0.f,0.f}, 0, 0, 0); \
        f32x4 c2_ = __builtin_amdgcn_mfma_f32_16x16x32_bf16(aQ2, KXC, (f32x4){0.f,0.f,0.f,0.f}, 0, 0, 0); \
        bool v0_ = !(TAIL) || (lo == 0);                                       \
        wt0x_ = pack4exp(c0_, v0_);                                            \
        wt1x_ = pack4exp(c1_, v0_);                                            \
        wt2x_ = pack4exp(c2_, v0_);                                            \
        c0_ = __builtin_amdgcn_mfma_f32_16x16x32_bf16(aQ0, KYC, (f32x4){0.f,0.f,0.f,0.f}, 0, 0, 0); \
        c1_ = __builtin_amdgcn_mfma_f32_16x16x32_bf16(aQ1, KYC, (f32x4){0.f,0.f,0.f,0.f}, 0, 0, 0); \
        c2_ = __builtin_amdgcn_mfma_f32_16x16x32_bf16(aQ2, KYC, (f32x4){0.f,0.f,0.f,0.f}, 0, 0, 0); \
        bool v1_ = !(TAIL);                                                    \
        wt0y_ = pack4exp(c0_, v1_);                                            \
        wt1y_ = pack4exp(c1_, v1_);                                            \
        wt2y_ = pack4exp(c2_, v1_);                                            \
    }                                                                          \
    asm volatile("s_waitcnt lgkmcnt(0)" ::: "memory");                         \
    __builtin_amdgcn_sched_barrier(0);                                         \
    u32x4 q0_; q0_[0] = p00_[0]; q0_[1] = p00_[1]; q0_[2] = p01_[0]; q0_[3] = p01_[1]; \
    u32x4 q1_; q1_[0] = p10_[0]; q1_[1] = p10_[1]; q1_[2] = p11_[0]; q1_[3] = p11_[1]; \
    u32x4 q2_; q2_[0] = p20_[0]; q2_[1] = p20_[1]; q2_[2] = p21_[0]; q2_[3] = p21_[1]; \
    bf16x8 pB0_ = __builtin_bit_cast(bf16x8, q0_);                             \
    bf16x8 pB1_ = __builtin_bit_cast(bf16x8, q1_);                             \
    bf16x8 pB2_ = __builtin_bit_cast(bf16x8, q2_);                             \
    oc0 = __builtin_amdgcn_mfma_f32_16x16x32_bf16(VP, pB0_, oc0, 0, 0, 0);     \
    dn0 = __builtin_amdgcn_mfma_f32_16x16x32_bf16(aOne, pB0_, dn0, 0, 0, 0);   \
    oc1 = __builtin_amdgcn_mfma_f32_16x16x32_bf16(VP, pB1_, oc1, 0, 0, 0);     \
    dn1 = __builtin_amdgcn_mfma_f32_16x16x32_bf16(aOne, pB1_, dn1, 0, 0, 0);   \
    oc2 = __builtin_amdgcn_mfma_f32_16x16x32_bf16(VP, pB2_, oc2, 0, 0, 0);     \
    dn2 = __builtin_amdgcn_mfma_f32_16x16x32_bf16(aOne, pB2_, dn2, 0, 0, 0);   \
    *(u32x2*)(wbp)        = wt0x_;                                             \
    *(u32x2*)(wbp + 544)  = wt0y_;                                             \
    *(u32x2*)(wbp + 1088) = wt1x_;                                             \
    *(u32x2*)(wbp + 1632) = wt1y_;                                             \
    *(u32x2*)(wbp + 2176) = wt2x_;                                             \
    *(u32x2*)(wbp + 2720) = wt2y_;                                             \
} while (0)

    for (int chp = 1; chp < 31; chp += 2) {
        STEP(chp,     0, kxA, kyA, kxB, kyB, vA, vB);
        STEP(chp + 1, 0, kxB, kyB, kxA, kyA, vB, vA);
    }
    STEP(31, 0, kxA, kyA, kxB, kyB, vA, vB);
    STEP(32, 1, kxB, kyB, kxA, kyA, vB, vA);
#undef STEP

    // ---- epilogue: consume P(32), V(32) is in vA ----
    {
        u32x2 p00, p01, p10, p11, p20, p21;
        asm volatile("ds_read_b64_tr_b16 %0, %1"             : "=v"(p00) : "v"(rdp) : "memory");
        asm volatile("ds_read_b64_tr_b16 %0, %1 offset:136"  : "=v"(p01) : "v"(rdp) : "memory");
        asm volatile("ds_read_b64_tr_b16 %0, %1 offset:1088" : "=v"(p10) : "v"(rdp) : "memory");
        asm volatile("ds_read_b64_tr_b16 %0, %1 offset:1224" : "=v"(p11) : "v"(rdp) : "memory");
        asm volatile("ds_read_b64_tr_b16 %0, %1 offset:2176" : "=v"(p20) : "v"(rdp) : "memory");
        asm volatile("ds_read_b64_tr_b16 %0, %1 offset:2312" : "=v"(p21) : "v"(rdp) : "memory");
        asm volatile("s_waitcnt lgkmcnt(0)" ::: "memory");
        __builtin_amdgcn_sched_barrier(0);
        u32x4 q0; q0[0] = p00[0]; q0[1] = p00[1]; q0[2] = p01[0]; q0[3] = p01[1];
        u32x4 q1; q1[0] = p10[0]; q1[1] = p10[1]; q1[2] = p11[0]; q1[3] = p11[1];
        u32x4 q2; q2[0] = p20[0]; q2[1] = p20[1]; q2[2] = p21[0]; q2[3] = p21[1];
        bf16x8 pB0 = __builtin_bit_cast(bf16x8, q0);
        bf16x8 pB1 = __builtin_bit_cast(bf16x8, q1);
        bf16x8 pB2 = __builtin_bit_cast(bf16x8, q2);
        oc0 = __builtin_amdgcn_mfma_f32_16x16x32_bf16(vA, pB0, oc0, 0, 0, 0);
        dn0 = __builtin_amdgcn_mfma_f32_16x16x32_bf16(aOne, pB0, dn0, 0, 0, 0);
        oc1 = __builtin_amdgcn_mfma_f32_16x16x32_bf16(vA, pB1, oc1, 0, 0, 0);
        dn1 = __builtin_amdgcn_mfma_f32_16x16x32_bf16(aOne, pB1, dn1, 0, 0, 0);
        oc2 = __builtin_amdgcn_mfma_f32_16x16x32_bf16(vA, pB2, oc2, 0, 0, 0);
        dn2 = __builtin_amdgcn_mfma_f32_16x16x32_bf16(aOne, pB2, dn2, 0, 0, 0);
    }

    {
        int qrow = qg0 + lo;
        if (qrow < S1C) {
            float inv = 1.0f / dn0[0];
            unsigned p0 = (unsigned short)f2b(oc0[0] * inv) | ((unsigned)(unsigned short)f2b(oc0[1] * inv) << 16);
            unsigned p1 = (unsigned short)f2b(oc0[2] * inv) | ((unsigned)(unsigned short)f2b(oc0[3] * inv) << 16);
            *(uint2*)(ob + ((size_t)b * S1C + qrow) * DD + h * DHD + quad * 4) = make_uint2(p0, p1);
        }
    }
    {
        int qrow = qg1 + lo;
        if (qrow < S1C) {
            float inv = 1.0f / dn1[0];
            unsigned p0 = (unsigned short)f2b(oc1[0] * inv) | ((unsigned)(unsigned short)f2b(oc1[1] * inv) << 16);
            unsigned p1 = (unsigned short)f2b(oc1[2] * inv) | ((unsigned)(unsigned short)f2b(oc1[3] * inv) << 16);
            *(uint2*)(ob + ((size_t)b * S1C + qrow) * DD + h * DHD + quad * 4) = make_uint2(p0, p1);
        }
    }
    {
        int qrow = qg2 + lo;
        if (qrow < S1C) {
            float inv = 1.0f / dn2[0];
            unsigned p0 = (unsigned short)f2b(oc2[0] * inv) | ((unsigned)(unsigned short)f2b(oc2[1] * inv) << 16);
            unsigned p1 = (unsigned short)f2b(oc2[2] * inv) | ((unsigned)(unsigned short)f2b(oc2[3] * inv) << 16);
            *(uint2*)(ob + ((size_t)b * S1C + qrow) * DD + h * DHD + quad * 4) = make_uint2(p0, p1);
        }
    }
}

// ---------------------------------------------------------------------------
// Kernel 4: fused transformer tail (r19 measured-best version).
// ---------------------------------------------------------------------------
__global__ __launch_bounds__(256) void k_block(
    const short* __restrict__ ob, float* __restrict__ x,
    const short* __restrict__ woT, fp bo, fp ln1s, fp ln1b,
    const short* __restrict__ w1T, fp b1, const short* __restrict__ w2T, fp b2,
    fp ln2s, fp ln2b,
    const short* __restrict__ wqkvTn, fp bqn, fp bkn, fp bvn,
    short* __restrict__ qb, short* __restrict__ kb, short* __restrict__ vbt,
    int has_next)
{
    int blk = blockIdx.x, t = threadIdx.x;
    int tok0 = blk * FT2;
    int w = t >> 6, l = t & 63;
    int quad = l >> 4, lo = l & 15;

    __shared__ float otf[FT2][OPAD];          // 8704 B; ys overlays (136-short rows)
    __shared__ u32x2 hidtr[2][8][136];        // 17408 B: [tile][kchunk][subtiles]
    short* ysb = (short*)&otf[0][0];
    char*  hidc = (char*)&hidtr[0][0][0];
    unsigned hidbase = (unsigned)(uintptr_t)hidc;

    // ---- LN lane mapping + entry prefetch (hidden under oproj) ----
    int tt8 = t >> 3;            // token 0..31
    int d8s = (t & 7) * 8;       // dim base
    const float* xrow = x + (size_t)(tok0 + tt8) * DD + d8s;
    float4 xpa = *(const float4*)xrow;
    float4 xpb = *(const float4*)(xrow + 4);
    float4 s1a = *(const float4*)(ln1s + d8s);
    float4 s1b = *(const float4*)(ln1s + d8s + 4);
    float4 b1a = *(const float4*)(ln1b + d8s);
    float4 b1b = *(const float4*)(ln1b + d8s + 4);

    // ---- oproj (both token-tiles, weights loaded once) ----
    {
        const short* obp0 = ob + ((size_t)(tok0 + lo)) * DD;
        const short* obp1 = ob + ((size_t)(tok0 + 16 + lo)) * DD;
        bf16x8 a0 = *(const bf16x8*)(obp0 + quad * 8);
        bf16x8 a1 = *(const bf16x8*)(obp0 + 32 + quad * 8);
        bf16x8 a2 = *(const bf16x8*)(obp1 + quad * 8);
        bf16x8 a3 = *(const bf16x8*)(obp1 + 32 + quad * 8);
        int n = w * 16 + lo;
        const short* wT = woT + (size_t)n * 64;
        bf16x8 b0 = *(const bf16x8*)(wT + quad * 8);
        bf16x8 bb = *(const bf16x8*)(wT + 32 + quad * 8);
        f32x4 c0 = __builtin_amdgcn_mfma_f32_16x16x32_bf16(a0, b0, (f32x4){0,0,0,0}, 0, 0, 0);
        c0 = __builtin_amdgcn_mfma_f32_16x16x32_bf16(a1, bb, c0, 0, 0, 0);
        f32x4 c1 = __builtin_amdgcn_mfma_f32_16x16x32_bf16(a2, b0, (f32x4){0,0,0,0}, 0, 0, 0);
        c1 = __builtin_amdgcn_mfma_f32_16x16x32_bf16(a3, bb, c1, 0, 0, 0);
        float bov = bo[n];
        #pragma unroll
        for (int r = 0; r < 4; ++r) {
            otf[quad * 4 + r][n] = c0[r] + bov;
            otf[16 + quad * 4 + r][n] = c1[r] + bov;
        }
    }
    __syncthreads();

    // ---- LN1 (8 lanes per token) ----
    float yv[8];
    {
        float4 o0 = *(const float4*)&otf[tt8][d8s];
        float4 o1 = *(const float4*)&otf[tt8][d8s + 4];
        float v0 = o0.x + xpa.x, v1 = o0.y + xpa.y, v2 = o0.z + xpa.z, v3 = o0.w + xpa.w;
        float v4 = o1.x + xpb.x, v5 = o1.y + xpb.y, v6 = o1.z + xpb.z, v7 = o1.w + xpb.w;
        float sum = ((v0 + v1) + (v2 + v3)) + ((v4 + v5) + (v6 + v7));
        float vs = v0 * v0;
        vs = fmaf(v1, v1, vs); vs = fmaf(v2, v2, vs); vs = fmaf(v3, v3, vs);
        vs = fmaf(v4, v4, vs); vs = fmaf(v5, v5, vs); vs = fmaf(v6, v6, vs);
        vs = fmaf(v7, v7, vs);
        sum += __shfl_xor(sum, 1, 64); sum += __shfl_xor(sum, 2, 64); sum += __shfl_xor(sum, 4, 64);
        vs  += __shfl_xor(vs , 1, 64); vs  += __shfl_xor(vs , 2, 64); vs  += __shfl_xor(vs , 4, 64);
        float mean = sum * (1.0f / 64.0f);
        float var = vs * (1.0f / 64.0f) - mean * mean;
        float rs = rsqrtf(var + 1e-5f);
        yv[0] = (v0 - mean) * rs * s1a.x + b1a.x;
        yv[1] = (v1 - mean) * rs * s1a.y + b1a.y;
        yv[2] = (v2 - mean) * rs * s1a.z + b1a.z;
        yv[3] = (v3 - mean) * rs * s1a.w + b1a.w;
        yv[4] = (v4 - mean) * rs * s1b.x + b1b.x;
        yv[5] = (v5 - mean) * rs * s1b.y + b1b.y;
        yv[6] = (v6 - mean) * rs * s1b.z + b1b.z;
        yv[7] = (v7 - mean) * rs * s1b.w + b1b.w;
        u32x2 pa = pack4cvt(yv[0], yv[1], yv[2], yv[3]);
        u32x2 pb = pack4cvt(yv[4], yv[5], yv[6], yv[7]);
        *(u32x4*)&ysb[tt8 * 136 + d8s] = (u32x4){pa[0], pa[1], pb[0], pb[1]};
    }
    __syncthreads();

    // ---- FFN1: hid = gelu(y @ w1 + b1), tr-layout packed b64 writes ----
    {
        bf16x8 a0 = *(const bf16x8*)&ysb[(size_t)lo * 136 + quad * 8];
        bf16x8 a1 = *(const bf16x8*)&ysb[(size_t)lo * 136 + 32 + quad * 8];
        bf16x8 a2 = *(const bf16x8*)&ysb[(size_t)(16 + lo) * 136 + quad * 8];
        bf16x8 a3 = *(const bf16x8*)&ysb[(size_t)(16 + lo) * 136 + 32 + quad * 8];
        unsigned hoff = (unsigned)(w * 2176 + (lo >> 2) * 136 + (lo & 3) * 32 + quad * 8);
        #pragma unroll
        for (int i = 0; i < 4; ++i) {
            int n = w * 64 + i * 16 + lo;
            const short* wT = w1T + (size_t)n * 64;
            bf16x8 b0 = *(const bf16x8*)(wT + quad * 8);
            bf16x8 bb = *(const bf16x8*)(wT + 32 + quad * 8);
            f32x4 c0 = __builtin_amdgcn_mfma_f32_16x16x32_bf16(a0, b0, (f32x4){0,0,0,0}, 0, 0, 0);
            c0 = __builtin_amdgcn_mfma_f32_16x16x32_bf16(a1, bb, c0, 0, 0, 0);
            f32x4 c1 = __builtin_amdgcn_mfma_f32_16x16x32_bf16(a2, b0, (f32x4){0,0,0,0}, 0, 0, 0);
            c1 = __builtin_amdgcn_mfma_f32_16x16x32_bf16(a3, bb, c1, 0, 0, 0);
            float b1v = b1[n];
            unsigned off = hoff + (i >> 1) * 1088 + (i & 1) * 544;
            *(u32x2*)(hidc + off) = pack4cvt(
                gelu_fast(c0[0] + b1v), gelu_fast(c0[1] + b1v),
                gelu_fast(c0[2] + b1v), gelu_fast(c0[3] + b1v));
            *(u32x2*)(hidc + 8704 + off) = pack4cvt(
                gelu_fast(c1[0] + b1v), gelu_fast(c1[1] + b1v),
                gelu_fast(c1[2] + b1v), gelu_fast(c1[3] + b1v));
        }
    }
    __syncthreads();

    // ---- FFN2: out = hid @ w2 + b2 (K=256), tr-read A-frags, depth-2 pipe ----
    {
        f32x4 c20 = {0.f,0.f,0.f,0.f}, c21 = {0.f,0.f,0.f,0.f};
        const short* wT2 = w2T + (size_t)(w * 16 + lo) * 256;
        unsigned ro = (unsigned)(quad * 272 + lo * 8);
        unsigned tb0 = hidbase + ro;
        unsigned tb1 = hidbase + 8704 + ro;
        u32x2 pA0, pA1, pA2, pA3, pB0, pB1, pB2, pB3;

#define TRRD(dst, addr, OFFSTR) \
    asm volatile("ds_read_b64_tr_b16 %0, %1 offset:" OFFSTR : "=v"(dst) : "v"(addr))
#define ISS(P0,P1,P2,P3, O1, O2) \
    TRRD(P0, tb0, O1); TRRD(P1, tb0, O2); TRRD(P2, tb1, O1); TRRD(P3, tb1, O2)
#define W4 asm volatile("s_waitcnt lgkmcnt(4)" ::: "memory"); __builtin_amdgcn_sched_barrier(0)
#define W0 asm volatile("s_waitcnt lgkmcnt(0)" ::: "memory"); __builtin_amdgcn_sched_barrier(0)
#define CONS(P0,P1,P2,P3, BF) do { \
    u32x4 q0_; q0_[0]=P0[0]; q0_[1]=P0[1]; q0_[2]=P1[0]; q0_[3]=P1[1]; \
    u32x4 q1_; q1_[0]=P2[0]; q1_[1]=P2[1]; q1_[2]=P3[0]; q1_[3]=P3[1]; \
    c20 = __builtin_amdgcn_mfma_f32_16x16x32_bf16(__builtin_bit_cast(bf16x8,q0_), BF, c20, 0,0,0); \
    c21 = __builtin_amdgcn_mfma_f32_16x16x32_bf16(__builtin_bit_cast(bf16x8,q1_), BF, c21, 0,0,0); \
} while (0)

        bf16x8 bfA = *(const bf16x8*)(wT2 + quad * 8);
        ISS(pA0,pA1,pA2,pA3, "0",    "136");
        bf16x8 bfB = *(const bf16x8*)(wT2 + 32 + quad * 8);
        ISS(pB0,pB1,pB2,pB3, "1088", "1224");
        W4; CONS(pA0,pA1,pA2,pA3, bfA);
        bfA = *(const bf16x8*)(wT2 + 64 + quad * 8);
        ISS(pA0,pA1,pA2,pA3, "2176", "2312");
        W4; CONS(pB0,pB1,pB2,pB3, bfB);
        bfB = *(const bf16x8*)(wT2 + 96 + quad * 8);
        ISS(pB0,pB1,pB2,pB3, "3264", "3400");
        W4; CONS(pA0,pA1,pA2,pA3, bfA);
        bfA = *(const bf16x8*)(wT2 + 128 + quad * 8);
        ISS(pA0,pA1,pA2,pA3, "4352", "4488");
        W4; CONS(pB0,pB1,pB2,pB3, bfB);
        bfB = *(const bf16x8*)(wT2 + 160 + quad * 8);
        ISS(pB0,pB1,pB2,pB3, "5440", "5576");
        W4; CONS(pA0,pA1,pA2,pA3, bfA);
        bfA = *(const bf16x8*)(wT2 + 192 + quad * 8);
        ISS(pA0,pA1,pA2,pA3, "6528", "6664");
        W4; CONS(pB0,pB1,pB2,pB3, bfB);
        bfB = *(const bf16x8*)(wT2 + 224 + quad * 8);
        ISS(pB0,pB1,pB2,pB3, "7616", "7752");
        W4; CONS(pA0,pA1,pA2,pA3, bfA);
        W0; CONS(pB0,pB1,pB2,pB3, bfB);
#undef TRRD
#undef ISS
#undef W4
#undef W0
#undef CONS

        float b2v = b2[w * 16 + lo];
        #pragma unroll
        for (int r = 0; r < 4; ++r) {
            otf[quad * 4 + r][w * 16 + lo] = c20[r] + b2v;
            otf[16 + quad * 4 + r][w * 16 + lo] = c21[r] + b2v;
        }
    }
    __syncthreads();

    // ---- LN2 (8 lanes per token); residual = yv (registers) ----
    {
        float4 s2a = *(const float4*)(ln2s + d8s);
        float4 s2b = *(const float4*)(ln2s + d8s + 4);
        float4 b2a = *(const float4*)(ln2b + d8s);
        float4 b2b = *(const float4*)(ln2b + d8s + 4);
        float4 o0 = *(const float4*)&otf[tt8][d8s];
        float4 o1 = *(const float4*)&otf[tt8][d8s + 4];
        float v0 = o0.x + yv[0], v1 = o0.y + yv[1], v2 = o0.z + yv[2], v3 = o0.w + yv[3];
        float v4 = o1.x + yv[4], v5 = o1.y + yv[5], v6 = o1.z + yv[6], v7 = o1.w + yv[7];
        float sum = ((v0 + v1) + (v2 + v3)) + ((v4 + v5) + (v6 + v7));
        float vs = v0 * v0;
        vs = fmaf(v1, v1, vs); vs = fmaf(v2, v2, vs); vs = fmaf(v3, v3, vs);
        vs = fmaf(v4, v4, vs); vs = fmaf(v5, v5, vs); vs = fmaf(v6, v6, vs);
        vs = fmaf(v7, v7, vs);
        sum += __shfl_xor(sum, 1, 64); sum += __shfl_xor(sum, 2, 64); sum += __shfl_xor(sum, 4, 64);
        vs  += __shfl_xor(vs , 1, 64); vs  += __shfl_xor(vs , 2, 64); vs  += __shfl_xor(vs , 4, 64);
        float mean = sum * (1.0f / 64.0f);
        float var = vs * (1.0f / 64.0f) - mean * mean;
        float rs = rsqrtf(var + 1e-5f);
        float y0 = (v0 - mean) * rs * s2a.x + b2a.x;
        float y1 = (v1 - mean) * rs * s2a.y + b2a.y;
        float y2 = (v2 - mean) * rs * s2a.z + b2a.z;
        float y3 = (v3 - mean) * rs * s2a.w + b2a.w;
        float y4 = (v4 - mean) * rs * s2b.x + b2b.x;
        float y5 = (v5 - mean) * rs * s2b.y + b2b.y;
        float y6 = (v6 - mean) * rs * s2b.z + b2b.z;
        float y7 = (v7 - mean) * rs * s2b.w + b2b.w;
        float* xo = x + (size_t)(tok0 + tt8) * DD + d8s;
        *(float4*)xo = make_float4(y0, y1, y2, y3);
        *(float4*)(xo + 4) = make_float4(y4, y5, y6, y7);
        u32x2 pa = pack4cvt(y0, y1, y2, y3);
        u32x2 pb = pack4cvt(y4, y5, y6, y7);
        *(u32x4*)&ysb[tt8 * 136 + d8s] = (u32x4){pa[0], pa[1], pb[0], pb[1]};
    }
    __syncthreads();

    // ---- next-layer QKV, both tiles ----
    if (has_next) {
        bf16x8 a0 = *(const bf16x8*)&ysb[(size_t)lo * 136 + quad * 8];
        bf16x8 a1 = *(const bf16x8*)&ysb[(size_t)lo * 136 + 32 + quad * 8];
        bf16x8 a2 = *(const bf16x8*)&ysb[(size_t)(16 + lo) * 136 + quad * 8];
        bf16x8 a3 = *(const bf16x8*)&ysb[(size_t)(16 + lo) * 136 + 32 + quad * 8];
        int n = w * 16 + lo;
        #pragma unroll
        for (int p = 0; p < 3; ++p) {
            const short* wT = wqkvTn + (size_t)p * 4096 + (size_t)n * 64;
            bf16x8 b0 = *(const bf16x8*)(wT + quad * 8);
            bf16x8 bb = *(const bf16x8*)(wT + 32 + quad * 8);
            f32x4 c0 = __builtin_amdgcn_mfma_f32_16x16x32_bf16(a0, b0, (f32x4){0,0,0,0}, 0, 0, 0);
            c0 = __builtin_amdgcn_mfma_f32_16x16x32_bf16(a1, bb, c0, 0, 0, 0);
            f32x4 c1 = __builtin_amdgcn_mfma_f32_16x16x32_bf16(a2, b0, (f32x4){0,0,0,0}, 0, 0, 0);
            c1 = __builtin_amdgcn_mfma_f32_16x16x32_bf16(a3, bb, c1, 0, 0, 0);
            float bias = (p == 0) ? bqn[n] * QSCL : (p == 1) ? bkn[n] : bvn[n];
            #pragma unroll
            for (int r = 0; r < 4; ++r) {
                int tok = tok0 + quad * 4 + r;
                int bb0 = tok / S1C, ss0 = tok % S1C;
                int bh = bb0 * NHD + w;
                short val = f2b(c0[r] + bias);
                int tok2 = tok + 16;
                int bb1 = tok2 / S1C, ss1 = tok2 % S1C;
                int bh2 = bb1 * NHD + w;
                short val2 = f2b(c1[r] + bias);
                if (p == 0) {
                    qb[((size_t)bh * SPAD + ss0) * 16 + lo] = val;
                    qb[((size_t)bh2 * SPAD + ss1) * 16 + lo] = val2;
                } else if (p == 1) {
                    kb[((size_t)bh * SPAD + ss0) * 16 + lo] = val;
                    kb[((size_t)bh2 * SPAD + ss1) * 16 + lo] = val2;
                } else {
                    vbt[((size_t)bh * 16 + lo) * SPAD + ss0] = val;
                    vbt[((size_t)bh2 * 16 + lo) * SPAD + ss1] = val2;
                }
            }
        }
    }
}

// ---------------------------------------------------------------------------
// Kernel 6: head MLPs. One block (64 thr) per batch element.
// ---------------------------------------------------------------------------
__global__ __launch_bounds__(64) void k_head(
    const float* __restrict__ x, fp proj_vars, fp param_vars,
    const int* __restrict__ materials,
    fp pw1, fp pb1, fp pw2, fp pb2, fp pw3, fp pb3,
    fp pw4, fp pb4, fp pw5, fp pb5,
    fp ipw1, fp ipb1, fp ipw2, fp ipb2,
    fp hw1, fp hb1, fp hw2, fp hb2, fp hw3, fp hb3,
    float* __restrict__ out)
{
    int b = blockIdx.x;
    int tid = threadIdx.x;
    __shared__ float A[80], Bf[80], pp[8], mi[32];

    if (tid < 3) A[tid] = proj_vars[b * 3 + tid];
    A[3 + tid] = x[((size_t)b * S1C + 0) * DD + tid];
    __syncthreads();

    if (tid < 34) {
        float a = pb1[tid];
        for (int i = 0; i < 67; ++i) a += A[i] * pw1[i * 34 + tid];
        Bf[tid] = gelu_exact(a);
    }
    __syncthreads();
    if (tid < 11) {
        float a = pb2[tid];
        for (int i = 0; i < 34; ++i) a += Bf[i] * pw2[i * 11 + tid];
        A[tid] = gelu_exact(a);
    }
    __syncthreads();
    if (tid < 36) {
        float a = pb3[tid];
        for (int i = 0; i < 11; ++i) a += A[i] * pw3[i * 36 + tid];
        Bf[tid] = gelu_exact(a);
    }
    __syncthreads();
    if (tid < 22) {
        float a = pb4[tid];
        for (int i = 0; i < 36; ++i) a += Bf[i] * pw4[i * 22 + tid];
        A[tid] = gelu_exact(a);
    }
    __syncthreads();
    if (tid < 24) {
        float a = pb5[tid];
        for (int i = 0; i < 22; ++i) a += A[i] * pw5[i * 24 + tid];
        mi[3 + tid] = a;
    }
    if (tid < 3) {
        float a = ipb1[tid];
        for (int i = 0; i < 3; ++i) a += param_vars[b * 3 + i] * ipw1[i * 3 + tid];
        pp[tid] = gelu_exact(a);
    }
    __syncthreads();
    if (tid < 3) {
        float a = ipb2[tid];
        for (int i = 0; i < 3; ++i) a += pp[i] * ipw2[i * 3 + tid];
        mi[tid] = a;
    }
    __syncthreads();

    int m = materials[b];
    if (tid < 15) {
        float a = hb1[m * 15 + tid];
        for (int i = 0; i < 27; ++i) a += mi[i] * hw1[(m * 27 + i) * 15 + tid];
        A[tid] = gelu_exact(a);
    }
    __syncthreads();
    if (tid < 18) {
        float a = hb2[m * 18 + tid];
        for (int i = 0; i < 15; ++i) a += A[i] * hw2[(m * 15 + i) * 18 + tid];
        Bf[tid] = gelu_exact(a);
    }
    __syncthreads();
    if (tid == 0) {
        float a = hb3[m];
        for (int i = 0; i < 18; ++i) a += Bf[i] * hw3[m * 18 + i];
        out[b] = a;
    }
}

// ---------------------------------------------------------------------------
extern "C" void kernel_launch(void* const* d_in, const int* in_sizes, int n_in,
                              void* d_out, int out_size, void* d_ws, size_t ws_size,
                              hipStream_t stream) {
    fp in_seq     = (fp)d_in[0];
    fp proj_vars  = (fp)d_in[1];
    fp param_vars = (fp)d_in[2];
    const int* materials = (const int*)d_in[3];
    fp enc_w1 = (fp)d_in[4];
    fp enc_b1 = (fp)d_in[5];
    fp enc_w2 = (fp)d_in[6];
    fp enc_b2 = (fp)d_in[7];
    fp sos    = (fp)d_in[8];
    fp tl_wq  = (fp)d_in[9];
    fp tl_wk  = (fp)d_in[10];
    fp tl_wv  = (fp)d_in[11];
    fp tl_bq  = (fp)d_in[12];
    fp tl_bk  = (fp)d_in[13];
    fp tl_bv  = (fp)d_in[14];
    fp tl_wo  = (fp)d_in[15];
    fp tl_bo  = (fp)d_in[16];
    fp tl_ln1s = (fp)d_in[17];
    fp tl_ln1b = (fp)d_in[18];
    fp tl_ln2s = (fp)d_in[19];
    fp tl_ln2b = (fp)d_in[20];
    fp tl_fw1 = (fp)d_in[21];
    fp tl_fb1 = (fp)d_in[22];
    fp tl_fw2 = (fp)d_in[23];
    fp tl_fb2 = (fp)d_in[24];
    fp pw1 = (fp)d_in[25]; fp pb1 = (fp)d_in[26];
    fp pw2 = (fp)d_in[27]; fp pb2 = (fp)d_in[28];
    fp pw3 = (fp)d_in[29]; fp pb3 = (fp)d_in[30];
    fp pw4 = (fp)d_in[31]; fp pb4 = (fp)d_in[32];
    fp pw5 = (fp)d_in[33]; fp pb5 = (fp)d_in[34];
    fp ipw1 = (fp)d_in[35]; fp ipb1 = (fp)d_in[36];
    fp ipw2 = (fp)d_in[37]; fp ipb2 = (fp)d_in[38];
    fp hw1 = (fp)d_in[39]; fp hb1 = (fp)d_in[40];
    fp hw2 = (fp)d_in[41]; fp hb2 = (fp)d_in[42];
    fp hw3 = (fp)d_in[43]; fp hb3 = (fp)d_in[44];

    // Workspace layout (xb slot retained but unused since r20 fusion)
    float* x  = (float*)d_ws;                           // NTOK*64 fp32
    short* ob = (short*)(x + (size_t)NTOK * DD);        // NTOK*64 bf16
    short* xb = ob + (size_t)NTOK * DD;                 // NTOK*64 bf16 (unused)
    short* qb = xb + (size_t)NTOK * DD;
    short* kb = qb + (size_t)NBH * SPAD * 16;
    short* vbt = kb + (size_t)NBH * SPAD * 16;
    short* wqkvT = vbt + (size_t)NBH * 16 * SPAD;       // 3 x 12288
    short* woT = wqkvT + (size_t)NLAY * 12288;          // 3 x 4096
    short* w1T = woT + (size_t)NLAY * 4096;             // 3 x 16384
    short* w2T = w1T + (size_t)NLAY * 16384;            // 3 x 16384

    k_wconv<<<dim3(192, NLAY), 256, 0, stream>>>(
        tl_wq, tl_wk, tl_wv, tl_wo, tl_fw1, tl_fw2, wqkvT, woT, w1T, w2T);
    k_zero<<<NBH, 64, 0, stream>>>(qb, kb, vbt);
    k_encqkv<<<NTOK / FTQ, 256, 0, stream>>>(
        in_seq, enc_w1, enc_b1, enc_w2, enc_b2, sos,
        wqkvT, tl_bq, tl_bk, tl_bv,
        x, qb, kb, vbt);

    for (int l = 0; l < NLAY; ++l) {
        k_attn<<<NBH * TGRP3, 256, 0, stream>>>(qb, kb, vbt, ob);
        int ln = (l + 1 < NLAY) ? (l + 1) : l;   // dummy ptrs for last layer
        k_block<<<NTOK / FT2, 256, 0, stream>>>(
            ob, x,
            woT + (size_t)l * 4096, tl_bo + (size_t)l * DD,
            tl_ln1s + (size_t)l * DD, tl_ln1b + (size_t)l * DD,
            w1T + (size_t)l * 16384, tl_fb1 + (size_t)l * DFFC,
            w2T + (size_t)l * 16384, tl_fb2 + (size_t)l * DD,
            tl_ln2s + (size_t)l * DD, tl_ln2b + (size_t)l * DD,
            wqkvT + (size_t)ln * 12288,
            tl_bq + (size_t)ln * DD, tl_bk + (size_t)ln * DD, tl_bv + (size_t)ln * DD,
            qb, kb, vbt,
            (l + 1 < NLAY) ? 1 : 0);
    }

    k_head<<<BB, 64, 0, stream>>>(
        x, proj_vars, param_vars, materials,
        pw1, pb1, pw2, pb2, pw3, pb3, pw4, pb4, pw5, pb5,
        ipw1, ipb1, ipw2, ipb2,
        hw1, hb1, hw2, hb2, hw3, hb3,
        (float*)d_out);
}

// Round 10
// 475.061 us; speedup vs baseline: 1.0017x; 1.0017x over previous
//
#include <hip/hip_runtime.h>
#include <hip/hip_bf16.h>
#include <math.h>

// Problem constants
#define BB   64
#define SS   1024
#define S1C  1025
#define DD   64
#define NHD  4
#define NBH  (BB * NHD)      // 256
#define DHD  16
#define DFFC 256
#define NLAY 3
#define NTOK (BB * S1C)      // 65600 = 32 * 2050
#define SPAD 1056            // padded key/seq length (66 * 16)
#define TGRP3 6              // tile-triple groups: wave covers t0, t0+22, t0+44
#define FTQ   32             // tokens per block (k_encqkv) - 2 token-tiles/wave
#define FT2   32             // tokens per block (k_block) - 2 token-tiles/wave
#define OPAD 68              // ot row stride in floats (ys overlays at 136 shorts)
#define QSCL 0.36067376022224085f   // 0.25 * log2(e) folded into q

typedef const float* fp;
typedef __attribute__((ext_vector_type(8))) short bf16x8;
typedef __attribute__((ext_vector_type(4))) float f32x4;
typedef __attribute__((ext_vector_type(2))) unsigned int u32x2;
typedef __attribute__((ext_vector_type(4))) unsigned int u32x4;

#if __has_builtin(__builtin_amdgcn_exp2f)
#define RAW_EXP2(x) __builtin_amdgcn_exp2f(x)
#else
#define RAW_EXP2(x) __expf(0.6931471805599453f * (x))
#endif
#if __has_builtin(__builtin_amdgcn_rcpf)
#define RAW_RCP(x) __builtin_amdgcn_rcpf(x)
#else
#define RAW_RCP(x) (1.0f / (x))
#endif

__device__ __forceinline__ float gelu_exact(float x) {
    return 0.5f * x * (1.0f + erff(x * 0.7071067811865475f));
}
// A&S 7.1.26 erf approximation, |err| <= 1.5e-7 (<< bf16 rounding noise)
__device__ __forceinline__ float erf_fast(float x) {
    float ax = fabsf(x);
    float t = RAW_RCP(1.0f + 0.3275911f * ax);
    float p = t * (0.254829592f + t * (-0.284496736f + t * (1.421413741f +
              t * (-1.453152027f + t * 1.061405429f))));
    float e = RAW_EXP2(ax * ax * -1.4426950408889634f);
    float r = 1.0f - p * e;
    return copysignf(r, x);
}
__device__ __forceinline__ float gelu_fast(float x) {
    return 0.5f * x * (1.0f + erf_fast(x * 0.7071067811865475f));
}
// RTNE float->bf16 (finite values), 3 ops
__device__ __forceinline__ short f2b(float f) {
    unsigned u = __float_as_uint(f);
    return (short)((u + 0x7fffu + ((u >> 16) & 1u)) >> 16);
}

// pack 4 fp32 exp results -> 4 bf16 in one u32x2 via v_cvt_pk_bf16_f32
__device__ __forceinline__ u32x2 pack4exp(f32x4 c, bool valid) {
    float e0 = valid ? RAW_EXP2(c[0]) : 0.f;
    float e1 = valid ? RAW_EXP2(c[1]) : 0.f;
    float e2 = valid ? RAW_EXP2(c[2]) : 0.f;
    float e3 = valid ? RAW_EXP2(c[3]) : 0.f;
    unsigned r0, r1;
    asm("v_cvt_pk_bf16_f32 %0, %1, %2" : "=v"(r0) : "v"(e0), "v"(e1));
    asm("v_cvt_pk_bf16_f32 %0, %1, %2" : "=v"(r1) : "v"(e2), "v"(e3));
    return (u32x2){r0, r1};
}
// pack 4 fp32 -> 4 bf16 via cvt_pk (RTNE)
__device__ __forceinline__ u32x2 pack4cvt(float x0, float x1, float x2, float x3) {
    unsigned r0, r1;
    asm("v_cvt_pk_bf16_f32 %0, %1, %2" : "=v"(r0) : "v"(x0), "v"(x1));
    asm("v_cvt_pk_bf16_f32 %0, %1, %2" : "=v"(r1) : "v"(x2), "v"(x3));
    return (u32x2){r0, r1};
}

// ---------------------------------------------------------------------------
// Kernel W: one-shot weight convert+transpose to bf16 [n][k] fragments.
// ---------------------------------------------------------------------------
__global__ __launch_bounds__(256) void k_wconv(
    fp wq, fp wk, fp wv, fp wo, fp w1, fp w2,
    short* __restrict__ wqkvT, short* __restrict__ woT,
    short* __restrict__ w1T, short* __restrict__ w2T)
{
    int l = blockIdx.y;
    int i = blockIdx.x * 256 + threadIdx.x;
    if (i < 12288) {
        int p = i >> 12, rem = i & 4095;
        int d = rem >> 6, j = rem & 63;
        fp src = (p == 0 ? wq : p == 1 ? wk : wv) + (size_t)l * 4096;
        float v = src[j * 64 + d];
        if (p == 0) v *= QSCL;
        wqkvT[(size_t)l * 12288 + i] = f2b(v);
    } else if (i < 16384) {
        int rem = i - 12288;
        woT[(size_t)l * 4096 + rem] = f2b(wo[(size_t)l * 4096 + (rem & 63) * 64 + (rem >> 6)]);
    } else if (i < 32768) {
        int rem = i - 16384;
        w1T[(size_t)l * 16384 + rem] = f2b(w1[(size_t)l * 16384 + (rem & 63) * 256 + (rem >> 6)]);
    } else {
        int rem = i - 32768;
        w2T[(size_t)l * 16384 + rem] = f2b(w2[(size_t)l * 16384 + (rem & 255) * 64 + (rem >> 8)]);
    }
}

// ---------------------------------------------------------------------------
// Kernel 0: zero the pad regions of the bf16 q/k/v buffers (rows 1025..1055).
// ---------------------------------------------------------------------------
__global__ __launch_bounds__(64) void k_zero(
    short* __restrict__ qb, short* __restrict__ kb, short* __restrict__ vbt)
{
    int bh = blockIdx.x, t = threadIdx.x;
    for (int i = t; i < 31 * 16; i += 64) {
        int r = i >> 4, c = i & 15;
        size_t idx = ((size_t)bh * SPAD + 1025 + r) * 16 + c;
        qb[idx] = 0; kb[idx] = 0;
    }
    for (int i = t; i < 16 * 31; i += 64) {
        int e = i / 31, c = i % 31;
        vbt[((size_t)bh * 16 + e) * SPAD + 1025 + c] = 0;
    }
}

// ---------------------------------------------------------------------------
// Kernel 1+2 fused (r20): encoder MLP + sos + positional encoding directly
// into an LDS tile (32 tokens), then the layer-0 MFMA Q/K/V projection from
// LDS. Removes the xb global round-trip and one dispatch.
// xs rows padded to 72 shorts (144 B): b128 reads are <=2-way bank aliased.
// ---------------------------------------------------------------------------
__global__ __launch_bounds__(256) void k_encqkv(
    fp in_seq, fp enc_w1, fp enc_b1, fp enc_w2, fp enc_b2, fp sos,
    const short* __restrict__ wqkvT, fp bq, fp bk, fp bv,
    float* __restrict__ x,
    short* __restrict__ qb, short* __restrict__ kb, short* __restrict__ vbt)
{
    int t = threadIdx.x;
    int tok0 = blockIdx.x * FTQ;
    int w = t >> 6, d = t & 63;
    __shared__ float e[4][48];
    __shared__ short xs[FTQ][72];

    // ---- encode phase: 8 passes x 4 tokens (wave w -> token i*4+w) ----
    int i2 = (d >> 1) * 2;
    float factor = RAW_EXP2((float)i2 * (-9.210340371976184f / 64.0f) * 1.4426950408889634f);
    for (int i = 0; i < 8; ++i) {
        int tl = i * 4 + w;
        int tok = tok0 + tl;
        int b = tok / S1C, s = tok % S1C;
        float val;
        if (s == 0) {
            val = sos[d];
        } else {
            float tin = in_seq[b * SS + (s - 1)];
            if (d < 48) e[w][d] = gelu_fast(tin * enc_w1[d] + enc_b1[d]);
            float acc = enc_b2[d];
            for (int j = 0; j < 48; ++j) acc += e[w][j] * enc_w2[j * DD + d];
            val = acc;
        }
        float ang = (float)s * factor;
        val += (d & 1) ? __cosf(ang) : __sinf(ang);
        x[(size_t)tok * DD + d] = val;
        xs[tl][d] = f2b(val);
    }
    __syncthreads();

    // ---- QKV phase (identical to old k_qkv, A-fragments from LDS) ----
    int l = t & 63;
    int quad = l >> 4, lo = l & 15;
    bf16x8 a0 = *(const bf16x8*)&xs[lo][quad * 8];
    bf16x8 a1 = *(const bf16x8*)&xs[lo][32 + quad * 8];
    bf16x8 a2 = *(const bf16x8*)&xs[16 + lo][quad * 8];
    bf16x8 a3 = *(const bf16x8*)&xs[16 + lo][32 + quad * 8];

    int n = w * 16 + lo;
    #pragma unroll
    for (int p = 0; p < 3; ++p) {
        const short* wT = wqkvT + (size_t)p * 4096 + (size_t)n * 64;
        bf16x8 b0 = *(const bf16x8*)(wT + quad * 8);
        bf16x8 b1 = *(const bf16x8*)(wT + 32 + quad * 8);
        f32x4 c0 = __builtin_amdgcn_mfma_f32_16x16x32_bf16(a0, b0, (f32x4){0,0,0,0}, 0, 0, 0);
        c0 = __builtin_amdgcn_mfma_f32_16x16x32_bf16(a1, b1, c0, 0, 0, 0);
        f32x4 c1 = __builtin_amdgcn_mfma_f32_16x16x32_bf16(a2, b0, (f32x4){0,0,0,0}, 0, 0, 0);
        c1 = __builtin_amdgcn_mfma_f32_16x16x32_bf16(a3, b1, c1, 0, 0, 0);
        float bias = (p == 0) ? bq[n] * QSCL : (p == 1) ? bk[n] : bv[n];
        #pragma unroll
        for (int r = 0; r < 4; ++r) {
            int tok = tok0 + quad * 4 + r;
            int bb0 = tok / S1C, ss0 = tok % S1C;
            int bh = bb0 * NHD + w;
            short val = f2b(c0[r] + bias);
            int tok2 = tok + 16;
            int bb1 = tok2 / S1C, ss1 = tok2 % S1C;
            int bh2 = bb1 * NHD + w;
            short val2 = f2b(c1[r] + bias);
            if (p == 0) {
                qb[((size_t)bh * SPAD + ss0) * 16 + lo] = val;
                qb[((size_t)bh2 * SPAD + ss1) * 16 + lo] = val2;
            } else if (p == 1) {
                kb[((size_t)bh * SPAD + ss0) * 16 + lo] = val;
                kb[((size_t)bh2 * SPAD + ss1) * 16 + lo] = val2;
            } else {
                vbt[((size_t)bh * 16 + lo) * SPAD + ss0] = val;
                vbt[((size_t)bh2 * 16 + lo) * SPAD + ss1] = val2;
            }
        }
    }
}

// ---------------------------------------------------------------------------
// Kernel 3: single-pass flash MFMA attention. r23 = r22 (three q-tiles per
// wave, single P buffer) + T5 s_setprio(1) around the pure-MFMA PV cluster:
// waves are barrier-free and independently phased, so priority-boosting the
// MFMA-dense region lets the CU scheduler overlap it with sibling waves'
// exp/load phases (m191 attn pattern).
// ---------------------------------------------------------------------------
__global__ __launch_bounds__(256) void k_attn(
    const short* __restrict__ qb, const short* __restrict__ kb,
    const short* __restrict__ vbt, short* __restrict__ ob)
{
    int bid = blockIdx.x;
    int bh  = bid % NBH;           // 6 blocks of a bh share bid%8 (XCD/L2)
    int grp = bid / NBH;           // 0..5
    int b = bh >> 2, h = bh & 3;
    int t = threadIdx.x;
    int w = t >> 6, l = t & 63;
    int quad = l >> 4, lo = l & 15;
    int t0 = grp * 4 + w;          // 0..23
    if (t0 > 21) t0 = 21;          // clamp: duplicate waves write identical data
    int t1 = t0 + 22;              // 22..43
    int t2 = t0 + 44;              // 44..65
    int qg0 = t0 * 16, qg1 = t1 * 16, qg2 = t2 * 16;

    // Per-wave P^T tiles, SINGLE buffer:
    // [wave][t0 1088B | t1 1088B | t2 1088B], subtile pitch 136 B.
    __shared__ u32x2 ptmem[4][408];
    char* ptc = (char*)&ptmem[w][0];
    unsigned ptbase = (unsigned)(uintptr_t)ptc;

    const short* qbase = qb + (size_t)bh * SPAD * 16;
    const short* kbase = kb + (size_t)bh * SPAD * 16;
    const short* vbase = vbt + (size_t)bh * 16 * SPAD;

    bf16x8 aQ0 = {0,0,0,0,0,0,0,0}, aQ1 = {0,0,0,0,0,0,0,0}, aQ2 = {0,0,0,0,0,0,0,0};
    if (quad < 2) {
        aQ0 = *(const bf16x8*)(qbase + ((size_t)(qg0 + lo)) * 16 + quad * 8);
        aQ1 = *(const bf16x8*)(qbase + ((size_t)(qg1 + lo)) * 16 + quad * 8);
        aQ2 = *(const bf16x8*)(qbase + ((size_t)(qg2 + lo)) * 16 + quad * 8);
    }

    const short ONE = 0x3F80;
    bf16x8 aOne = {ONE, ONE, ONE, ONE, ONE, ONE, ONE, ONE};

    f32x4 oc0 = {0.f,0.f,0.f,0.f}, oc1 = {0.f,0.f,0.f,0.f}, oc2 = {0.f,0.f,0.f,0.f};
    f32x4 dn0 = {0.f,0.f,0.f,0.f}, dn1 = {0.f,0.f,0.f,0.f}, dn2 = {0.f,0.f,0.f,0.f};

    // Write byte-offset within a tile: key k0 = lo (k1 = 16+lo is +544).
    unsigned wo0 = (unsigned)((lo >> 2) * 136 + (lo & 3) * 32 + quad * 8);
    // tr-read byte-offset: group quad reads subtile 2*quad (128 B window)
    unsigned ro = (unsigned)(quad * 272 + lo * 8);
    unsigned rdp = ptbase + ro;            // read addr
    char* wbp = ptc + wo0;                 // write base (lane-resolved)

    // Rotating prefetch registers
    bf16x8 kxA, kyA, kxB, kyB, vA, vB;

    // ---- prologue: issue K(0),V(0),K(1); produce P(0) ----
    {
        const short* k0p = kbase + (size_t)lo * 16 + (quad & 1) * 8;
        kxA = *(const bf16x8*)k0p;
        kyA = *(const bf16x8*)(k0p + 256);
        vA  = *(const bf16x8*)(vbase + (size_t)lo * SPAD + quad * 8);
        const short* k1p = kbase + (size_t)(32 + lo) * 16 + (quad & 1) * 8;
        kxB = *(const bf16x8*)k1p;
        kyB = *(const bf16x8*)(k1p + 256);

        f32x4 c0 = __builtin_amdgcn_mfma_f32_16x16x32_bf16(aQ0, kxA, (f32x4){0.f,0.f,0.f,0.f}, 0, 0, 0);
        f32x4 c1 = __builtin_amdgcn_mfma_f32_16x16x32_bf16(aQ1, kxA, (f32x4){0.f,0.f,0.f,0.f}, 0, 0, 0);
        f32x4 c2 = __builtin_amdgcn_mfma_f32_16x16x32_bf16(aQ2, kxA, (f32x4){0.f,0.f,0.f,0.f}, 0, 0, 0);
        *(u32x2*)(wbp)        = pack4exp(c0, true);
        *(u32x2*)(wbp + 1088) = pack4exp(c1, true);
        *(u32x2*)(wbp + 2176) = pack4exp(c2, true);
        c0 = __builtin_amdgcn_mfma_f32_16x16x32_bf16(aQ0, kyA, (f32x4){0.f,0.f,0.f,0.f}, 0, 0, 0);
        c1 = __builtin_amdgcn_mfma_f32_16x16x32_bf16(aQ1, kyA, (f32x4){0.f,0.f,0.f,0.f}, 0, 0, 0);
        c2 = __builtin_amdgcn_mfma_f32_16x16x32_bf16(aQ2, kyA, (f32x4){0.f,0.f,0.f,0.f}, 0, 0, 0);
        *(u32x2*)(wbp + 544)  = pack4exp(c0, true);
        *(u32x2*)(wbp + 1632) = pack4exp(c1, true);
        *(u32x2*)(wbp + 2720) = pack4exp(c2, true);
    }

// Pipelined step: produce chunk CH, consume chunk CH-1. Single P buffer:
// tr-reads (issued first, drained before writes) rely on in-order DS.
#define STEP(CH, TAIL, KXC, KYC, KXN, KYN, VP, VC) do {                       \
    int ch_ = (CH);                                                            \
    if (!(TAIL)) {                                                             \
        const short* kn_ = kbase + (size_t)((ch_ + 1) * 32 + lo) * 16 + (quad & 1) * 8; \
        KXN = *(const bf16x8*)kn_;                                             \
        KYN = *(const bf16x8*)(kn_ + 256);                                     \
    }                                                                          \
    VC = *(const bf16x8*)(vbase + (size_t)lo * SPAD + ch_ * 32 + quad * 8);    \
    u32x2 p00_, p01_, p10_, p11_, p20_, p21_;                                  \
    asm volatile("ds_read_b64_tr_b16 %0, %1"             : "=v"(p00_) : "v"(rdp) : "memory"); \
    asm volatile("ds_read_b64_tr_b16 %0, %1 offset:136"  : "=v"(p01_) : "v"(rdp) : "memory"); \
    asm volatile("ds_read_b64_tr_b16 %0, %1 offset:1088" : "=v"(p10_) : "v"(rdp) : "memory"); \
    asm volatile("ds_read_b64_tr_b16 %0, %1 offset:1224" : "=v"(p11_) : "v"(rdp) : "memory"); \
    asm volatile("ds_read_b64_tr_b16 %0, %1 offset:2176" : "=v"(p20_) : "v"(rdp) : "memory"); \
    asm volatile("ds_read_b64_tr_b16 %0, %1 offset:2312" : "=v"(p21_) : "v"(rdp) : "memory"); \
    u32x2 wt0x_, wt1x_, wt2x_, wt0y_, wt1y_, wt2y_;                            \
    {                                                                          \
        f32x4 c0_ = __builtin_amdgcn_mfma_f32_16x16x32_bf16(aQ0, KXC, (f32x4){0.f,0.f,0.f,0.f}, 0, 0, 0); \
        f32x4 c1_ = __builtin_amdgcn_mfma_f32_16x16x32_bf16(aQ1, KXC, (f32x4){0.f,0.f,0.f,0.f}, 0, 0, 0); \
        f32x4 c2_ = __builtin_amdgcn_mfma_f32_16x16x32_bf16(aQ2, KXC, (f32x4){0.f,0.f,0.f,0.f}, 0, 0, 0); \
        bool v0_ = !(TAIL) || (lo == 0);                                       \
        wt0x_ = pack4exp(c0_, v0_);                                            \
        wt1x_ = pack4exp(c1_, v0_);                                            \
        wt2x_ = pack4exp(c2_, v0_);                                            \
        c0_ = __builtin_amdgcn_mfma_f32_16x16x32_bf16(aQ0, KYC, (f32x4){0.f,0.f,0.f,0.f}, 0, 0, 0); \
        c1_ = __builtin_amdgcn_mfma_f32_16x16x32_bf16(aQ1, KYC, (f32x4){0.f,0.f,0.f,0.f}, 0, 0, 0); \
        c2_ = __builtin_amdgcn_mfma_f32_16x16x32_bf16(aQ2, KYC, (f32x4){0.f,0.f,0.f,0.f}, 0, 0, 0); \
        bool v1_ = !(TAIL);                                                    \
        wt0y_ = pack4exp(c0_, v1_);                                            \
        wt1y_ = pack4exp(c1_, v1_);                                            \
        wt2y_ = pack4exp(c2_, v1_);                                            \
    }                                                                          \
    asm volatile("s_waitcnt lgkmcnt(0)" ::: "memory");                         \
    __builtin_amdgcn_sched_barrier(0);                                         \
    u32x4 q0_; q0_[0] = p00_[0]; q0_[1] = p00_[1]; q0_[2] = p01_[0]; q0_[3] = p01_[1]; \
    u32x4 q1_; q1_[0] = p10_[0]; q1_[1] = p10_[1]; q1_[2] = p11_[0]; q1_[3] = p11_[1]; \
    u32x4 q2_; q2_[0] = p20_[0]; q2_[1] = p20_[1]; q2_[2] = p21_[0]; q2_[3] = p21_[1]; \
    bf16x8 pB0_ = __builtin_bit_cast(bf16x8, q0_);                             \
    bf16x8 pB1_ = __builtin_bit_cast(bf16x8, q1_);                             \
    bf16x8 pB2_ = __builtin_bit_cast(bf16x8, q2_);                             \
    __builtin_amdgcn_s_setprio(1);                                             \
    oc0 = __builtin_amdgcn_mfma_f32_16x16x32_bf16(VP, pB0_, oc0, 0, 0, 0);     \
    dn0 = __builtin_amdgcn_mfma_f32_16x16x32_bf16(aOne, pB0_, dn0, 0, 0, 0);   \
    oc1 = __builtin_amdgcn_mfma_f32_16x16x32_bf16(VP, pB1_, oc1, 0, 0, 0);     \
    dn1 = __builtin_amdgcn_mfma_f32_16x16x32_bf16(aOne, pB1_, dn1, 0, 0, 0);   \
    oc2 = __builtin_amdgcn_mfma_f32_16x16x32_bf16(VP, pB2_, oc2, 0, 0, 0);     \
    dn2 = __builtin_amdgcn_mfma_f32_16x16x32_bf16(aOne, pB2_, dn2, 0, 0, 0);   \
    __builtin_amdgcn_s_setprio(0);                                             \
    *(u32x2*)(wbp)        = wt0x_;                                             \
    *(u32x2*)(wbp + 544)  = wt0y_;                                             \
    *(u32x2*)(wbp + 1088) = wt1x_;                                             \
    *(u32x2*)(wbp + 1632) = wt1y_;                                             \
    *(u32x2*)(wbp + 2176) = wt2x_;                                             \
    *(u32x2*)(wbp + 2720) = wt2y_;                                             \
} while (0)

    for (int chp = 1; chp < 31; chp += 2) {
        STEP(chp,     0, kxA, kyA, kxB, kyB, vA, vB);
        STEP(chp + 1, 0, kxB, kyB, kxA, kyA, vB, vA);
    }
    STEP(31, 0, kxA, kyA, kxB, kyB, vA, vB);
    STEP(32, 1, kxB, kyB, kxA, kyA, vB, vA);
#undef STEP

    // ---- epilogue: consume P(32), V(32) is in vA ----
    {
        u32x2 p00, p01, p10, p11, p20, p21;
        asm volatile("ds_read_b64_tr_b16 %0, %1"             : "=v"(p00) : "v"(rdp) : "memory");
        asm volatile("ds_read_b64_tr_b16 %0, %1 offset:136"  : "=v"(p01) : "v"(rdp) : "memory");
        asm volatile("ds_read_b64_tr_b16 %0, %1 offset:1088" : "=v"(p10) : "v"(rdp) : "memory");
        asm volatile("ds_read_b64_tr_b16 %0, %1 offset:1224" : "=v"(p11) : "v"(rdp) : "memory");
        asm volatile("ds_read_b64_tr_b16 %0, %1 offset:2176" : "=v"(p20) : "v"(rdp) : "memory");
        asm volatile("ds_read_b64_tr_b16 %0, %1 offset:2312" : "=v"(p21) : "v"(rdp) : "memory");
        asm volatile("s_waitcnt lgkmcnt(0)" ::: "memory");
        __builtin_amdgcn_sched_barrier(0);
        u32x4 q0; q0[0] = p00[0]; q0[1] = p00[1]; q0[2] = p01[0]; q0[3] = p01[1];
        u32x4 q1; q1[0] = p10[0]; q1[1] = p10[1]; q1[2] = p11[0]; q1[3] = p11[1];
        u32x4 q2; q2[0] = p20[0]; q2[1] = p20[1]; q2[2] = p21[0]; q2[3] = p21[1];
        bf16x8 pB0 = __builtin_bit_cast(bf16x8, q0);
        bf16x8 pB1 = __builtin_bit_cast(bf16x8, q1);
        bf16x8 pB2 = __builtin_bit_cast(bf16x8, q2);
        __builtin_amdgcn_s_setprio(1);
        oc0 = __builtin_amdgcn_mfma_f32_16x16x32_bf16(vA, pB0, oc0, 0, 0, 0);
        dn0 = __builtin_amdgcn_mfma_f32_16x16x32_bf16(aOne, pB0, dn0, 0, 0, 0);
        oc1 = __builtin_amdgcn_mfma_f32_16x16x32_bf16(vA, pB1, oc1, 0, 0, 0);
        dn1 = __builtin_amdgcn_mfma_f32_16x16x32_bf16(aOne, pB1, dn1, 0, 0, 0);
        oc2 = __builtin_amdgcn_mfma_f32_16x16x32_bf16(vA, pB2, oc2, 0, 0, 0);
        dn2 = __builtin_amdgcn_mfma_f32_16x16x32_bf16(aOne, pB2, dn2, 0, 0, 0);
        __builtin_amdgcn_s_setprio(0);
    }

    {
        int qrow = qg0 + lo;
        if (qrow < S1C) {
            float inv = 1.0f / dn0[0];
            unsigned p0 = (unsigned short)f2b(oc0[0] * inv) | ((unsigned)(unsigned short)f2b(oc0[1] * inv) << 16);
            unsigned p1 = (unsigned short)f2b(oc0[2] * inv) | ((unsigned)(unsigned short)f2b(oc0[3] * inv) << 16);
            *(uint2*)(ob + ((size_t)b * S1C + qrow) * DD + h * DHD + quad * 4) = make_uint2(p0, p1);
        }
    }
    {
        int qrow = qg1 + lo;
        if (qrow < S1C) {
            float inv = 1.0f / dn1[0];
            unsigned p0 = (unsigned short)f2b(oc1[0] * inv) | ((unsigned)(unsigned short)f2b(oc1[1] * inv) << 16);
            unsigned p1 = (unsigned short)f2b(oc1[2] * inv) | ((unsigned)(unsigned short)f2b(oc1[3] * inv) << 16);
            *(uint2*)(ob + ((size_t)b * S1C + qrow) * DD + h * DHD + quad * 4) = make_uint2(p0, p1);
        }
    }
    {
        int qrow = qg2 + lo;
        if (qrow < S1C) {
            float inv = 1.0f / dn2[0];
            unsigned p0 = (unsigned short)f2b(oc2[0] * inv) | ((unsigned)(unsigned short)f2b(oc2[1] * inv) << 16);
            unsigned p1 = (unsigned short)f2b(oc2[2] * inv) | ((unsigned)(unsigned short)f2b(oc2[3] * inv) << 16);
            *(uint2*)(ob + ((size_t)b * S1C + qrow) * DD + h * DHD + quad * 4) = make_uint2(p0, p1);
        }
    }
}

// ---------------------------------------------------------------------------
// Kernel 4: fused transformer tail (r19 measured-best version).
// ---------------------------------------------------------------------------
__global__ __launch_bounds__(256) void k_block(
    const short* __restrict__ ob, float* __restrict__ x,
    const short* __restrict__ woT, fp bo, fp ln1s, fp ln1b,
    const short* __restrict__ w1T, fp b1, const short* __restrict__ w2T, fp b2,
    fp ln2s, fp ln2b,
    const short* __restrict__ wqkvTn, fp bqn, fp bkn, fp bvn,
    short* __restrict__ qb, short* __restrict__ kb, short* __restrict__ vbt,
    int has_next)
{
    int blk = blockIdx.x, t = threadIdx.x;
    int tok0 = blk * FT2;
    int w = t >> 6, l = t & 63;
    int quad = l >> 4, lo = l & 15;

    __shared__ float otf[FT2][OPAD];          // 8704 B; ys overlays (136-short rows)
    __shared__ u32x2 hidtr[2][8][136];        // 17408 B: [tile][kchunk][subtiles]
    short* ysb = (short*)&otf[0][0];
    char*  hidc = (char*)&hidtr[0][0][0];
    unsigned hidbase = (unsigned)(uintptr_t)hidc;

    // ---- LN lane mapping + entry prefetch (hidden under oproj) ----
    int tt8 = t >> 3;            // token 0..31
    int d8s = (t & 7) * 8;       // dim base
    const float* xrow = x + (size_t)(tok0 + tt8) * DD + d8s;
    float4 xpa = *(const float4*)xrow;
    float4 xpb = *(const float4*)(xrow + 4);
    float4 s1a = *(const float4*)(ln1s + d8s);
    float4 s1b = *(const float4*)(ln1s + d8s + 4);
    float4 b1a = *(const float4*)(ln1b + d8s);
    float4 b1b = *(const float4*)(ln1b + d8s + 4);

    // ---- oproj (both token-tiles, weights loaded once) ----
    {
        const short* obp0 = ob + ((size_t)(tok0 + lo)) * DD;
        const short* obp1 = ob + ((size_t)(tok0 + 16 + lo)) * DD;
        bf16x8 a0 = *(const bf16x8*)(obp0 + quad * 8);
        bf16x8 a1 = *(const bf16x8*)(obp0 + 32 + quad * 8);
        bf16x8 a2 = *(const bf16x8*)(obp1 + quad * 8);
        bf16x8 a3 = *(const bf16x8*)(obp1 + 32 + quad * 8);
        int n = w * 16 + lo;
        const short* wT = woT + (size_t)n * 64;
        bf16x8 b0 = *(const bf16x8*)(wT + quad * 8);
        bf16x8 bb = *(const bf16x8*)(wT + 32 + quad * 8);
        f32x4 c0 = __builtin_amdgcn_mfma_f32_16x16x32_bf16(a0, b0, (f32x4){0,0,0,0}, 0, 0, 0);
        c0 = __builtin_amdgcn_mfma_f32_16x16x32_bf16(a1, bb, c0, 0, 0, 0);
        f32x4 c1 = __builtin_amdgcn_mfma_f32_16x16x32_bf16(a2, b0, (f32x4){0,0,0,0}, 0, 0, 0);
        c1 = __builtin_amdgcn_mfma_f32_16x16x32_bf16(a3, bb, c1, 0, 0, 0);
        float bov = bo[n];
        #pragma unroll
        for (int r = 0; r < 4; ++r) {
            otf[quad * 4 + r][n] = c0[r] + bov;
            otf[16 + quad * 4 + r][n] = c1[r] + bov;
        }
    }
    __syncthreads();

    // ---- LN1 (8 lanes per token) ----
    float yv[8];
    {
        float4 o0 = *(const float4*)&otf[tt8][d8s];
        float4 o1 = *(const float4*)&otf[tt8][d8s + 4];
        float v0 = o0.x + xpa.x, v1 = o0.y + xpa.y, v2 = o0.z + xpa.z, v3 = o0.w + xpa.w;
        float v4 = o1.x + xpb.x, v5 = o1.y + xpb.y, v6 = o1.z + xpb.z, v7 = o1.w + xpb.w;
        float sum = ((v0 + v1) + (v2 + v3)) + ((v4 + v5) + (v6 + v7));
        float vs = v0 * v0;
        vs = fmaf(v1, v1, vs); vs = fmaf(v2, v2, vs); vs = fmaf(v3, v3, vs);
        vs = fmaf(v4, v4, vs); vs = fmaf(v5, v5, vs); vs = fmaf(v6, v6, vs);
        vs = fmaf(v7, v7, vs);
        sum += __shfl_xor(sum, 1, 64); sum += __shfl_xor(sum, 2, 64); sum += __shfl_xor(sum, 4, 64);
        vs  += __shfl_xor(vs , 1, 64); vs  += __shfl_xor(vs , 2, 64); vs  += __shfl_xor(vs , 4, 64);
        float mean = sum * (1.0f / 64.0f);
        float var = vs * (1.0f / 64.0f) - mean * mean;
        float rs = rsqrtf(var + 1e-5f);
        yv[0] = (v0 - mean) * rs * s1a.x + b1a.x;
        yv[1] = (v1 - mean) * rs * s1a.y + b1a.y;
        yv[2] = (v2 - mean) * rs * s1a.z + b1a.z;
        yv[3] = (v3 - mean) * rs * s1a.w + b1a.w;
        yv[4] = (v4 - mean) * rs * s1b.x + b1b.x;
        yv[5] = (v5 - mean) * rs * s1b.y + b1b.y;
        yv[6] = (v6 - mean) * rs * s1b.z + b1b.z;
        yv[7] = (v7 - mean) * rs * s1b.w + b1b.w;
        u32x2 pa = pack4cvt(yv[0], yv[1], yv[2], yv[3]);
        u32x2 pb = pack4cvt(yv[4], yv[5], yv[6], yv[7]);
        *(u32x4*)&ysb[tt8 * 136 + d8s] = (u32x4){pa[0], pa[1], pb[0], pb[1]};
    }
    __syncthreads();

    // ---- FFN1: hid = gelu(y @ w1 + b1), tr-layout packed b64 writes ----
    {
        bf16x8 a0 = *(const bf16x8*)&ysb[(size_t)lo * 136 + quad * 8];
        bf16x8 a1 = *(const bf16x8*)&ysb[(size_t)lo * 136 + 32 + quad * 8];
        bf16x8 a2 = *(const bf16x8*)&ysb[(size_t)(16 + lo) * 136 + quad * 8];
        bf16x8 a3 = *(const bf16x8*)&ysb[(size_t)(16 + lo) * 136 + 32 + quad * 8];
        unsigned hoff = (unsigned)(w * 2176 + (lo >> 2) * 136 + (lo & 3) * 32 + quad * 8);
        #pragma unroll
        for (int i = 0; i < 4; ++i) {
            int n = w * 64 + i * 16 + lo;
            const short* wT = w1T + (size_t)n * 64;
            bf16x8 b0 = *(const bf16x8*)(wT + quad * 8);
            bf16x8 bb = *(const bf16x8*)(wT + 32 + quad * 8);
            f32x4 c0 = __builtin_amdgcn_mfma_f32_16x16x32_bf16(a0, b0, (f32x4){0,0,0,0}, 0, 0, 0);
            c0 = __builtin_amdgcn_mfma_f32_16x16x32_bf16(a1, bb, c0, 0, 0, 0);
            f32x4 c1 = __builtin_amdgcn_mfma_f32_16x16x32_bf16(a2, b0, (f32x4){0,0,0,0}, 0, 0, 0);
            c1 = __builtin_amdgcn_mfma_f32_16x16x32_bf16(a3, bb, c1, 0, 0, 0);
            float b1v = b1[n];
            unsigned off = hoff + (i >> 1) * 1088 + (i & 1) * 544;
            *(u32x2*)(hidc + off) = pack4cvt(
                gelu_fast(c0[0] + b1v), gelu_fast(c0[1] + b1v),
                gelu_fast(c0[2] + b1v), gelu_fast(c0[3] + b1v));
            *(u32x2*)(hidc + 8704 + off) = pack4cvt(
                gelu_fast(c1[0] + b1v), gelu_fast(c1[1] + b1v),
                gelu_fast(c1[2] + b1v), gelu_fast(c1[3] + b1v));
        }
    }
    __syncthreads();

    // ---- FFN2: out = hid @ w2 + b2 (K=256), tr-read A-frags, depth-2 pipe ----
    {
        f32x4 c20 = {0.f,0.f,0.f,0.f}, c21 = {0.f,0.f,0.f,0.f};
        const short* wT2 = w2T + (size_t)(w * 16 + lo) * 256;
        unsigned ro = (unsigned)(quad * 272 + lo * 8);
        unsigned tb0 = hidbase + ro;
        unsigned tb1 = hidbase + 8704 + ro;
        u32x2 pA0, pA1, pA2, pA3, pB0, pB1, pB2, pB3;

#define TRRD(dst, addr, OFFSTR) \
    asm volatile("ds_read_b64_tr_b16 %0, %1 offset:" OFFSTR : "=v"(dst) : "v"(addr))
#define ISS(P0,P1,P2,P3, O1, O2) \
    TRRD(P0, tb0, O1); TRRD(P1, tb0, O2); TRRD(P2, tb1, O1); TRRD(P3, tb1, O2)
#define W4 asm volatile("s_waitcnt lgkmcnt(4)" ::: "memory"); __builtin_amdgcn_sched_barrier(0)
#define W0 asm volatile("s_waitcnt lgkmcnt(0)" ::: "memory"); __builtin_amdgcn_sched_barrier(0)
#define CONS(P0,P1,P2,P3, BF) do { \
    u32x4 q0_; q0_[0]=P0[0]; q0_[1]=P0[1]; q0_[2]=P1[0]; q0_[3]=P1[1]; \
    u32x4 q1_; q1_[0]=P2[0]; q1_[1]=P2[1]; q1_[2]=P3[0]; q1_[3]=P3[1]; \
    c20 = __builtin_amdgcn_mfma_f32_16x16x32_bf16(__builtin_bit_cast(bf16x8,q0_), BF, c20, 0,0,0); \
    c21 = __builtin_amdgcn_mfma_f32_16x16x32_bf16(__builtin_bit_cast(bf16x8,q1_), BF, c21, 0,0,0); \
} while (0)

        bf16x8 bfA = *(const bf16x8*)(wT2 + quad * 8);
        ISS(pA0,pA1,pA2,pA3, "0",    "136");
        bf16x8 bfB = *(const bf16x8*)(wT2 + 32 + quad * 8);
        ISS(pB0,pB1,pB2,pB3, "1088", "1224");
        W4; CONS(pA0,pA1,pA2,pA3, bfA);
        bfA = *(const bf16x8*)(wT2 + 64 + quad * 8);
        ISS(pA0,pA1,pA2,pA3, "2176", "2312");
        W4; CONS(pB0,pB1,pB2,pB3, bfB);
        bfB = *(const bf16x8*)(wT2 + 96 + quad * 8);
        ISS(pB0,pB1,pB2,pB3, "3264", "3400");
        W4; CONS(pA0,pA1,pA2,pA3, bfA);
        bfA = *(const bf16x8*)(wT2 + 128 + quad * 8);
        ISS(pA0,pA1,pA2,pA3, "4352", "4488");
        W4; CONS(pB0,pB1,pB2,pB3, bfB);
        bfB = *(const bf16x8*)(wT2 + 160 + quad * 8);
        ISS(pB0,pB1,pB2,pB3, "5440", "5576");
        W4; CONS(pA0,pA1,pA2,pA3, bfA);
        bfA = *(const bf16x8*)(wT2 + 192 + quad * 8);
        ISS(pA0,pA1,pA2,pA3, "6528", "6664");
        W4; CONS(pB0,pB1,pB2,pB3, bfB);
        bfB = *(const bf16x8*)(wT2 + 224 + quad * 8);
        ISS(pB0,pB1,pB2,pB3, "7616", "7752");
        W4; CONS(pA0,pA1,pA2,pA3, bfA);
        W0; CONS(pB0,pB1,pB2,pB3, bfB);
#undef TRRD
#undef ISS
#undef W4
#undef W0
#undef CONS

        float b2v = b2[w * 16 + lo];
        #pragma unroll
        for (int r = 0; r < 4; ++r) {
            otf[quad * 4 + r][w * 16 + lo] = c20[r] + b2v;
            otf[16 + quad * 4 + r][w * 16 + lo] = c21[r] + b2v;
        }
    }
    __syncthreads();

    // ---- LN2 (8 lanes per token); residual = yv (registers) ----
    {
        float4 s2a = *(const float4*)(ln2s + d8s);
        float4 s2b = *(const float4*)(ln2s + d8s + 4);
        float4 b2a = *(const float4*)(ln2b + d8s);
        float4 b2b = *(const float4*)(ln2b + d8s + 4);
        float4 o0 = *(const float4*)&otf[tt8][d8s];
        float4 o1 = *(const float4*)&otf[tt8][d8s + 4];
        float v0 = o0.x + yv[0], v1 = o0.y + yv[1], v2 = o0.z + yv[2], v3 = o0.w + yv[3];
        float v4 = o1.x + yv[4], v5 = o1.y + yv[5], v6 = o1.z + yv[6], v7 = o1.w + yv[7];
        float sum = ((v0 + v1) + (v2 + v3)) + ((v4 + v5) + (v6 + v7));
        float vs = v0 * v0;
        vs = fmaf(v1, v1, vs); vs = fmaf(v2, v2, vs); vs = fmaf(v3, v3, vs);
        vs = fmaf(v4, v4, vs); vs = fmaf(v5, v5, vs); vs = fmaf(v6, v6, vs);
        vs = fmaf(v7, v7, vs);
        sum += __shfl_xor(sum, 1, 64); sum += __shfl_xor(sum, 2, 64); sum += __shfl_xor(sum, 4, 64);
        vs  += __shfl_xor(vs , 1, 64); vs  += __shfl_xor(vs , 2, 64); vs  += __shfl_xor(vs , 4, 64);
        float mean = sum * (1.0f / 64.0f);
        float var = vs * (1.0f / 64.0f) - mean * mean;
        float rs = rsqrtf(var + 1e-5f);
        float y0 = (v0 - mean) * rs * s2a.x + b2a.x;
        float y1 = (v1 - mean) * rs * s2a.y + b2a.y;
        float y2 = (v2 - mean) * rs * s2a.z + b2a.z;
        float y3 = (v3 - mean) * rs * s2a.w + b2a.w;
        float y4 = (v4 - mean) * rs * s2b.x + b2b.x;
        float y5 = (v5 - mean) * rs * s2b.y + b2b.y;
        float y6 = (v6 - mean) * rs * s2b.z + b2b.z;
        float y7 = (v7 - mean) * rs * s2b.w + b2b.w;
        float* xo = x + (size_t)(tok0 + tt8) * DD + d8s;
        *(float4*)xo = make_float4(y0, y1, y2, y3);
        *(float4*)(xo + 4) = make_float4(y4, y5, y6, y7);
        u32x2 pa = pack4cvt(y0, y1, y2, y3);
        u32x2 pb = pack4cvt(y4, y5, y6, y7);
        *(u32x4*)&ysb[tt8 * 136 + d8s] = (u32x4){pa[0], pa[1], pb[0], pb[1]};
    }
    __syncthreads();

    // ---- next-layer QKV, both tiles ----
    if (has_next) {
        bf16x8 a0 = *(const bf16x8*)&ysb[(size_t)lo * 136 + quad * 8];
        bf16x8 a1 = *(const bf16x8*)&ysb[(size_t)lo * 136 + 32 + quad * 8];
        bf16x8 a2 = *(const bf16x8*)&ysb[(size_t)(16 + lo) * 136 + quad * 8];
        bf16x8 a3 = *(const bf16x8*)&ysb[(size_t)(16 + lo) * 136 + 32 + quad * 8];
        int n = w * 16 + lo;
        #pragma unroll
        for (int p = 0; p < 3; ++p) {
            const short* wT = wqkvTn + (size_t)p * 4096 + (size_t)n * 64;
            bf16x8 b0 = *(const bf16x8*)(wT + quad * 8);
            bf16x8 bb = *(const bf16x8*)(wT + 32 + quad * 8);
            f32x4 c0 = __builtin_amdgcn_mfma_f32_16x16x32_bf16(a0, b0, (f32x4){0,0,0,0}, 0, 0, 0);
            c0 = __builtin_amdgcn_mfma_f32_16x16x32_bf16(a1, bb, c0, 0, 0, 0);
            f32x4 c1 = __builtin_amdgcn_mfma_f32_16x16x32_bf16(a2, b0, (f32x4){0,0,0,0}, 0, 0, 0);
            c1 = __builtin_amdgcn_mfma_f32_16x16x32_bf16(a3, bb, c1, 0, 0, 0);
            float bias = (p == 0) ? bqn[n] * QSCL : (p == 1) ? bkn[n] : bvn[n];
            #pragma unroll
            for (int r = 0; r < 4; ++r) {
                int tok = tok0 + quad * 4 + r;
                int bb0 = tok / S1C, ss0 = tok % S1C;
                int bh = bb0 * NHD + w;
                short val = f2b(c0[r] + bias);
                int tok2 = tok + 16;
                int bb1 = tok2 / S1C, ss1 = tok2 % S1C;
                int bh2 = bb1 * NHD + w;
                short val2 = f2b(c1[r] + bias);
                if (p == 0) {
                    qb[((size_t)bh * SPAD + ss0) * 16 + lo] = val;
                    qb[((size_t)bh2 * SPAD + ss1) * 16 + lo] = val2;
                } else if (p == 1) {
                    kb[((size_t)bh * SPAD + ss0) * 16 + lo] = val;
                    kb[((size_t)bh2 * SPAD + ss1) * 16 + lo] = val2;
                } else {
                    vbt[((size_t)bh * 16 + lo) * SPAD + ss0] = val;
                    vbt[((size_t)bh2 * 16 + lo) * SPAD + ss1] = val2;
                }
            }
        }
    }
}

// ---------------------------------------------------------------------------
// Kernel 6: head MLPs. One block (64 thr) per batch element.
// ---------------------------------------------------------------------------
__global__ __launch_bounds__(64) void k_head(
    const float* __restrict__ x, fp proj_vars, fp param_vars,
    const int* __restrict__ materials,
    fp pw1, fp pb1, fp pw2, fp pb2, fp pw3, fp pb3,
    fp pw4, fp pb4, fp pw5, fp pb5,
    fp ipw1, fp ipb1, fp ipw2, fp ipb2,
    fp hw1, fp hb1, fp hw2, fp hb2, fp hw3, fp hb3,
    float* __restrict__ out)
{
    int b = blockIdx.x;
    int tid = threadIdx.x;
    __shared__ float A[80], Bf[80], pp[8], mi[32];

    if (tid < 3) A[tid] = proj_vars[b * 3 + tid];
    A[3 + tid] = x[((size_t)b * S1C + 0) * DD + tid];
    __syncthreads();

    if (tid < 34) {
        float a = pb1[tid];
        for (int i = 0; i < 67; ++i) a += A[i] * pw1[i * 34 + tid];
        Bf[tid] = gelu_exact(a);
    }
    __syncthreads();
    if (tid < 11) {
        float a = pb2[tid];
        for (int i = 0; i < 34; ++i) a += Bf[i] * pw2[i * 11 + tid];
        A[tid] = gelu_exact(a);
    }
    __syncthreads();
    if (tid < 36) {
        float a = pb3[tid];
        for (int i = 0; i < 11; ++i) a += A[i] * pw3[i * 36 + tid];
        Bf[tid] = gelu_exact(a);
    }
    __syncthreads();
    if (tid < 22) {
        float a = pb4[tid];
        for (int i = 0; i < 36; ++i) a += Bf[i] * pw4[i * 22 + tid];
        A[tid] = gelu_exact(a);
    }
    __syncthreads();
    if (tid < 24) {
        float a = pb5[tid];
        for (int i = 0; i < 22; ++i) a += A[i] * pw5[i * 24 + tid];
        mi[3 + tid] = a;
    }
    if (tid < 3) {
        float a = ipb1[tid];
        for (int i = 0; i < 3; ++i) a += param_vars[b * 3 + i] * ipw1[i * 3 + tid];
        pp[tid] = gelu_exact(a);
    }
    __syncthreads();
    if (tid < 3) {
        float a = ipb2[tid];
        for (int i = 0; i < 3; ++i) a += pp[i] * ipw2[i * 3 + tid];
        mi[tid] = a;
    }
    __syncthreads();

    int m = materials[b];
    if (tid < 15) {
        float a = hb1[m * 15 + tid];
        for (int i = 0; i < 27; ++i) a += mi[i] * hw1[(m * 27 + i) * 15 + tid];
        A[tid] = gelu_exact(a);
    }
    __syncthreads();
    if (tid < 18) {
        float a = hb2[m * 18 + tid];
        for (int i = 0; i < 15; ++i) a += A[i] * hw2[(m * 15 + i) * 18 + tid];
        Bf[tid] = gelu_exact(a);
    }
    __syncthreads();
    if (tid == 0) {
        float a = hb3[m];
        for (int i = 0; i < 18; ++i) a += Bf[i] * hw3[m * 18 + i];
        out[b] = a;
    }
}

// ---------------------------------------------------------------------------
extern "C" void kernel_launch(void* const* d_in, const int* in_sizes, int n_in,
                              void* d_out, int out_size, void* d_ws, size_t ws_size,
                              hipStream_t stream) {
    fp in_seq     = (fp)d_in[0];
    fp proj_vars  = (fp)d_in[1];
    fp param_vars = (fp)d_in[2];
    const int* materials = (const int*)d_in[3];
    fp enc_w1 = (fp)d_in[4];
    fp enc_b1 = (fp)d_in[5];
    fp enc_w2 = (fp)d_in[6];
    fp enc_b2 = (fp)d_in[7];
    fp sos    = (fp)d_in[8];
    fp tl_wq  = (fp)d_in[9];
    fp tl_wk  = (fp)d_in[10];
    fp tl_wv  = (fp)d_in[11];
    fp tl_bq  = (fp)d_in[12];
    fp tl_bk  = (fp)d_in[13];
    fp tl_bv  = (fp)d_in[14];
    fp tl_wo  = (fp)d_in[15];
    fp tl_bo  = (fp)d_in[16];
    fp tl_ln1s = (fp)d_in[17];
    fp tl_ln1b = (fp)d_in[18];
    fp tl_ln2s = (fp)d_in[19];
    fp tl_ln2b = (fp)d_in[20];
    fp tl_fw1 = (fp)d_in[21];
    fp tl_fb1 = (fp)d_in[22];
    fp tl_fw2 = (fp)d_in[23];
    fp tl_fb2 = (fp)d_in[24];
    fp pw1 = (fp)d_in[25]; fp pb1 = (fp)d_in[26];
    fp pw2 = (fp)d_in[27]; fp pb2 = (fp)d_in[28];
    fp pw3 = (fp)d_in[29]; fp pb3 = (fp)d_in[30];
    fp pw4 = (fp)d_in[31]; fp pb4 = (fp)d_in[32];
    fp pw5 = (fp)d_in[33]; fp pb5 = (fp)d_in[34];
    fp ipw1 = (fp)d_in[35]; fp ipb1 = (fp)d_in[36];
    fp ipw2 = (fp)d_in[37]; fp ipb2 = (fp)d_in[38];
    fp hw1 = (fp)d_in[39]; fp hb1 = (fp)d_in[40];
    fp hw2 = (fp)d_in[41]; fp hb2 = (fp)d_in[42];
    fp hw3 = (fp)d_in[43]; fp hb3 = (fp)d_in[44];

    // Workspace layout (xb slot retained but unused since r20 fusion)
    float* x  = (float*)d_ws;                           // NTOK*64 fp32
    short* ob = (short*)(x + (size_t)NTOK * DD);        // NTOK*64 bf16
    short* xb = ob + (size_t)NTOK * DD;                 // NTOK*64 bf16 (unused)
    short* qb = xb + (size_t)NTOK * DD;
    short* kb = qb + (size_t)NBH * SPAD * 16;
    short* vbt = kb + (size_t)NBH * SPAD * 16;
    short* wqkvT = vbt + (size_t)NBH * 16 * SPAD;       // 3 x 12288
    short* woT = wqkvT + (size_t)NLAY * 12288;          // 3 x 4096
    short* w1T = woT + (size_t)NLAY * 4096;             // 3 x 16384
    short* w2T = w1T + (size_t)NLAY * 16384;            // 3 x 16384

    k_wconv<<<dim3(192, NLAY), 256, 0, stream>>>(
        tl_wq, tl_wk, tl_wv, tl_wo, tl_fw1, tl_fw2, wqkvT, woT, w1T, w2T);
    k_zero<<<NBH, 64, 0, stream>>>(qb, kb, vbt);
    k_encqkv<<<NTOK / FTQ, 256, 0, stream>>>(
        in_seq, enc_w1, enc_b1, enc_w2, enc_b2, sos,
        wqkvT, tl_bq, tl_bk, tl_bv,
        x, qb, kb, vbt);

    for (int l = 0; l < NLAY; ++l) {
        k_attn<<<NBH * TGRP3, 256, 0, stream>>>(qb, kb, vbt, ob);
        int ln = (l + 1 < NLAY) ? (l + 1) : l;   // dummy ptrs for last layer
        k_block<<<NTOK / FT2, 256, 0, stream>>>(
            ob, x,
            woT + (size_t)l * 4096, tl_bo + (size_t)l * DD,
            tl_ln1s + (size_t)l * DD, tl_ln1b + (size_t)l * DD,
            w1T + (size_t)l * 16384, tl_fb1 + (size_t)l * DFFC,
            w2T + (size_t)l * 16384, tl_fb2 + (size_t)l * DD,
            tl_ln2s + (size_t)l * DD, tl_ln2b + (size_t)l * DD,
            wqkvT + (size_t)ln * 12288,
            tl_bq + (size_t)ln * DD, tl_bk + (size_t)ln * DD, tl_bv + (size_t)ln * DD,
            qb, kb, vbt,
            (l + 1 < NLAY) ? 1 : 0);
    }

    k_head<<<BB, 64, 0, stream>>>(
        x, proj_vars, param_vars, materials,
        pw1, pb1, pw2, pb2, pw3, pb3, pw4, pb4, pw5, pb5,
        ipw1, ipb1, ipw2, ipb2,
        hw1, hb1, hw2, hb2, hw3, hb3,
        (float*)d_out);
}

// Round 11
// 471.027 us; speedup vs baseline: 1.0103x; 1.0086x over previous
//
#include <hip/hip_runtime.h>
#include <hip/hip_bf16.h>
#include <math.h>

// Problem constants
#define BB   64
#define SS   1024
#define S1C  1025
#define DD   64
#define NHD  4
#define NBH  (BB * NHD)      // 256
#define DHD  16
#define DFFC 256
#define NLAY 3
#define NTOK (BB * S1C)      // 65600 = 32 * 2050
#define SPAD 1056            // padded key/seq length (66 * 16)
#define TGRP 11              // 11 blocks/bh x 2 waves = 22 wave-slots = 66 tiles, 0 waste
#define FTQ   32             // tokens per block (k_encqkv) - 2 token-tiles/wave
#define FT2   32             // tokens per block (k_block) - 2 token-tiles/wave
#define OPAD 68              // ot row stride in floats (ys overlays at 136 shorts)
#define QSCL 0.36067376022224085f   // 0.25 * log2(e) folded into q

typedef const float* fp;
typedef __attribute__((ext_vector_type(8))) short bf16x8;
typedef __attribute__((ext_vector_type(4))) float f32x4;
typedef __attribute__((ext_vector_type(2))) unsigned int u32x2;
typedef __attribute__((ext_vector_type(4))) unsigned int u32x4;

#if __has_builtin(__builtin_amdgcn_exp2f)
#define RAW_EXP2(x) __builtin_amdgcn_exp2f(x)
#else
#define RAW_EXP2(x) __expf(0.6931471805599453f * (x))
#endif
#if __has_builtin(__builtin_amdgcn_rcpf)
#define RAW_RCP(x) __builtin_amdgcn_rcpf(x)
#else
#define RAW_RCP(x) (1.0f / (x))
#endif

__device__ __forceinline__ float gelu_exact(float x) {
    return 0.5f * x * (1.0f + erff(x * 0.7071067811865475f));
}
// A&S 7.1.26 erf approximation, |err| <= 1.5e-7 (<< bf16 rounding noise)
__device__ __forceinline__ float erf_fast(float x) {
    float ax = fabsf(x);
    float t = RAW_RCP(1.0f + 0.3275911f * ax);
    float p = t * (0.254829592f + t * (-0.284496736f + t * (1.421413741f +
              t * (-1.453152027f + t * 1.061405429f))));
    float e = RAW_EXP2(ax * ax * -1.4426950408889634f);
    float r = 1.0f - p * e;
    return copysignf(r, x);
}
__device__ __forceinline__ float gelu_fast(float x) {
    return 0.5f * x * (1.0f + erf_fast(x * 0.7071067811865475f));
}
// RTNE float->bf16 (finite values), 3 ops
__device__ __forceinline__ short f2b(float f) {
    unsigned u = __float_as_uint(f);
    return (short)((u + 0x7fffu + ((u >> 16) & 1u)) >> 16);
}

// pack 4 fp32 exp results -> 4 bf16 in one u32x2 via v_cvt_pk_bf16_f32
__device__ __forceinline__ u32x2 pack4exp(f32x4 c, bool valid) {
    float e0 = valid ? RAW_EXP2(c[0]) : 0.f;
    float e1 = valid ? RAW_EXP2(c[1]) : 0.f;
    float e2 = valid ? RAW_EXP2(c[2]) : 0.f;
    float e3 = valid ? RAW_EXP2(c[3]) : 0.f;
    unsigned r0, r1;
    asm("v_cvt_pk_bf16_f32 %0, %1, %2" : "=v"(r0) : "v"(e0), "v"(e1));
    asm("v_cvt_pk_bf16_f32 %0, %1, %2" : "=v"(r1) : "v"(e2), "v"(e3));
    return (u32x2){r0, r1};
}
// pack 4 fp32 -> 4 bf16 via cvt_pk (RTNE)
__device__ __forceinline__ u32x2 pack4cvt(float x0, float x1, float x2, float x3) {
    unsigned r0, r1;
    asm("v_cvt_pk_bf16_f32 %0, %1, %2" : "=v"(r0) : "v"(x0), "v"(x1));
    asm("v_cvt_pk_bf16_f32 %0, %1, %2" : "=v"(r1) : "v"(x2), "v"(x3));
    return (u32x2){r0, r1};
}

// ---------------------------------------------------------------------------
// Kernel W: one-shot weight convert+transpose to bf16 [n][k] fragments.
// ---------------------------------------------------------------------------
__global__ __launch_bounds__(256) void k_wconv(
    fp wq, fp wk, fp wv, fp wo, fp w1, fp w2,
    short* __restrict__ wqkvT, short* __restrict__ woT,
    short* __restrict__ w1T, short* __restrict__ w2T)
{
    int l = blockIdx.y;
    int i = blockIdx.x * 256 + threadIdx.x;
    if (i < 12288) {
        int p = i >> 12, rem = i & 4095;
        int d = rem >> 6, j = rem & 63;
        fp src = (p == 0 ? wq : p == 1 ? wk : wv) + (size_t)l * 4096;
        float v = src[j * 64 + d];
        if (p == 0) v *= QSCL;
        wqkvT[(size_t)l * 12288 + i] = f2b(v);
    } else if (i < 16384) {
        int rem = i - 12288;
        woT[(size_t)l * 4096 + rem] = f2b(wo[(size_t)l * 4096 + (rem & 63) * 64 + (rem >> 6)]);
    } else if (i < 32768) {
        int rem = i - 16384;
        w1T[(size_t)l * 16384 + rem] = f2b(w1[(size_t)l * 16384 + (rem & 63) * 256 + (rem >> 6)]);
    } else {
        int rem = i - 32768;
        w2T[(size_t)l * 16384 + rem] = f2b(w2[(size_t)l * 16384 + (rem & 255) * 64 + (rem >> 8)]);
    }
}

// ---------------------------------------------------------------------------
// Kernel 0: zero the pad regions of the bf16 q/k/v buffers (rows 1025..1055).
// ---------------------------------------------------------------------------
__global__ __launch_bounds__(64) void k_zero(
    short* __restrict__ qb, short* __restrict__ kb, short* __restrict__ vbt)
{
    int bh = blockIdx.x, t = threadIdx.x;
    for (int i = t; i < 31 * 16; i += 64) {
        int r = i >> 4, c = i & 15;
        size_t idx = ((size_t)bh * SPAD + 1025 + r) * 16 + c;
        qb[idx] = 0; kb[idx] = 0;
    }
    for (int i = t; i < 16 * 31; i += 64) {
        int e = i / 31, c = i % 31;
        vbt[((size_t)bh * 16 + e) * SPAD + 1025 + c] = 0;
    }
}

// ---------------------------------------------------------------------------
// Kernel 1+2 fused (r20): encoder MLP + sos + positional encoding directly
// into an LDS tile (32 tokens), then the layer-0 MFMA Q/K/V projection from
// LDS. Removes the xb global round-trip and one dispatch.
// ---------------------------------------------------------------------------
__global__ __launch_bounds__(256) void k_encqkv(
    fp in_seq, fp enc_w1, fp enc_b1, fp enc_w2, fp enc_b2, fp sos,
    const short* __restrict__ wqkvT, fp bq, fp bk, fp bv,
    float* __restrict__ x,
    short* __restrict__ qb, short* __restrict__ kb, short* __restrict__ vbt)
{
    int t = threadIdx.x;
    int tok0 = blockIdx.x * FTQ;
    int w = t >> 6, d = t & 63;
    __shared__ float e[4][48];
    __shared__ short xs[FTQ][72];

    // ---- encode phase: 8 passes x 4 tokens (wave w -> token i*4+w) ----
    int i2 = (d >> 1) * 2;
    float factor = RAW_EXP2((float)i2 * (-9.210340371976184f / 64.0f) * 1.4426950408889634f);
    for (int i = 0; i < 8; ++i) {
        int tl = i * 4 + w;
        int tok = tok0 + tl;
        int b = tok / S1C, s = tok % S1C;
        float val;
        if (s == 0) {
            val = sos[d];
        } else {
            float tin = in_seq[b * SS + (s - 1)];
            if (d < 48) e[w][d] = gelu_fast(tin * enc_w1[d] + enc_b1[d]);
            float acc = enc_b2[d];
            for (int j = 0; j < 48; ++j) acc += e[w][j] * enc_w2[j * DD + d];
            val = acc;
        }
        float ang = (float)s * factor;
        val += (d & 1) ? __cosf(ang) : __sinf(ang);
        x[(size_t)tok * DD + d] = val;
        xs[tl][d] = f2b(val);
    }
    __syncthreads();

    // ---- QKV phase (identical to old k_qkv, A-fragments from LDS) ----
    int l = t & 63;
    int quad = l >> 4, lo = l & 15;
    bf16x8 a0 = *(const bf16x8*)&xs[lo][quad * 8];
    bf16x8 a1 = *(const bf16x8*)&xs[lo][32 + quad * 8];
    bf16x8 a2 = *(const bf16x8*)&xs[16 + lo][quad * 8];
    bf16x8 a3 = *(const bf16x8*)&xs[16 + lo][32 + quad * 8];

    int n = w * 16 + lo;
    #pragma unroll
    for (int p = 0; p < 3; ++p) {
        const short* wT = wqkvT + (size_t)p * 4096 + (size_t)n * 64;
        bf16x8 b0 = *(const bf16x8*)(wT + quad * 8);
        bf16x8 b1 = *(const bf16x8*)(wT + 32 + quad * 8);
        f32x4 c0 = __builtin_amdgcn_mfma_f32_16x16x32_bf16(a0, b0, (f32x4){0,0,0,0}, 0, 0, 0);
        c0 = __builtin_amdgcn_mfma_f32_16x16x32_bf16(a1, b1, c0, 0, 0, 0);
        f32x4 c1 = __builtin_amdgcn_mfma_f32_16x16x32_bf16(a2, b0, (f32x4){0,0,0,0}, 0, 0, 0);
        c1 = __builtin_amdgcn_mfma_f32_16x16x32_bf16(a3, b1, c1, 0, 0, 0);
        float bias = (p == 0) ? bq[n] * QSCL : (p == 1) ? bk[n] : bv[n];
        #pragma unroll
        for (int r = 0; r < 4; ++r) {
            int tok = tok0 + quad * 4 + r;
            int bb0 = tok / S1C, ss0 = tok % S1C;
            int bh = bb0 * NHD + w;
            short val = f2b(c0[r] + bias);
            int tok2 = tok + 16;
            int bb1 = tok2 / S1C, ss1 = tok2 % S1C;
            int bh2 = bb1 * NHD + w;
            short val2 = f2b(c1[r] + bias);
            if (p == 0) {
                qb[((size_t)bh * SPAD + ss0) * 16 + lo] = val;
                qb[((size_t)bh2 * SPAD + ss1) * 16 + lo] = val2;
            } else if (p == 1) {
                kb[((size_t)bh * SPAD + ss0) * 16 + lo] = val;
                kb[((size_t)bh2 * SPAD + ss1) * 16 + lo] = val2;
            } else {
                vbt[((size_t)bh * 16 + lo) * SPAD + ss0] = val;
                vbt[((size_t)bh2 * 16 + lo) * SPAD + ss1] = val2;
            }
        }
    }
}

// ---------------------------------------------------------------------------
// Kernel 3: single-pass flash MFMA attention. r24 = r22 schedule (three
// q-tiles per wave, single P buffer, drain-free) with ZERO-WASTE tiling:
// 128-thread blocks (2 waves), grid NBH*11 -> 22 wave-slots per bh cover
// exactly 66 q-tiles {W, W+22, W+44} with no duplicate work (r22's 4-wave
// blocks wasted 2/24 slots on the t0>21 clamp). setprio reverted (r23
// measured negative).
// ---------------------------------------------------------------------------
__global__ __launch_bounds__(128) void k_attn(
    const short* __restrict__ qb, const short* __restrict__ kb,
    const short* __restrict__ vbt, short* __restrict__ ob)
{
    int bid = blockIdx.x;
    int bh  = bid % NBH;           // 11 blocks of a bh share bid%8 (XCD/L2)
    int grp = bid / NBH;           // 0..10
    int b = bh >> 2, h = bh & 3;
    int t = threadIdx.x;
    int w = t >> 6, l = t & 63;
    int quad = l >> 4, lo = l & 15;
    int t0 = grp * 2 + w;          // 0..21 (exact cover, no clamp)
    int t1 = t0 + 22;              // 22..43
    int t2 = t0 + 44;              // 44..65
    int qg0 = t0 * 16, qg1 = t1 * 16, qg2 = t2 * 16;

    // Per-wave P^T tiles, SINGLE buffer:
    // [wave][t0 1088B | t1 1088B | t2 1088B], subtile pitch 136 B.
    __shared__ u32x2 ptmem[2][408];
    char* ptc = (char*)&ptmem[w][0];
    unsigned ptbase = (unsigned)(uintptr_t)ptc;

    const short* qbase = qb + (size_t)bh * SPAD * 16;
    const short* kbase = kb + (size_t)bh * SPAD * 16;
    const short* vbase = vbt + (size_t)bh * 16 * SPAD;

    bf16x8 aQ0 = {0,0,0,0,0,0,0,0}, aQ1 = {0,0,0,0,0,0,0,0}, aQ2 = {0,0,0,0,0,0,0,0};
    if (quad < 2) {
        aQ0 = *(const bf16x8*)(qbase + ((size_t)(qg0 + lo)) * 16 + quad * 8);
        aQ1 = *(const bf16x8*)(qbase + ((size_t)(qg1 + lo)) * 16 + quad * 8);
        aQ2 = *(const bf16x8*)(qbase + ((size_t)(qg2 + lo)) * 16 + quad * 8);
    }

    const short ONE = 0x3F80;
    bf16x8 aOne = {ONE, ONE, ONE, ONE, ONE, ONE, ONE, ONE};

    f32x4 oc0 = {0.f,0.f,0.f,0.f}, oc1 = {0.f,0.f,0.f,0.f}, oc2 = {0.f,0.f,0.f,0.f};
    f32x4 dn0 = {0.f,0.f,0.f,0.f}, dn1 = {0.f,0.f,0.f,0.f}, dn2 = {0.f,0.f,0.f,0.f};

    // Write byte-offset within a tile: key k0 = lo (k1 = 16+lo is +544).
    unsigned wo0 = (unsigned)((lo >> 2) * 136 + (lo & 3) * 32 + quad * 8);
    // tr-read byte-offset: group quad reads subtile 2*quad (128 B window)
    unsigned ro = (unsigned)(quad * 272 + lo * 8);
    unsigned rdp = ptbase + ro;            // read addr
    char* wbp = ptc + wo0;                 // write base (lane-resolved)

    // Rotating prefetch registers
    bf16x8 kxA, kyA, kxB, kyB, vA, vB;

    // ---- prologue: issue K(0),V(0),K(1); produce P(0) ----
    {
        const short* k0p = kbase + (size_t)lo * 16 + (quad & 1) * 8;
        kxA = *(const bf16x8*)k0p;
        kyA = *(const bf16x8*)(k0p + 256);
        vA  = *(const bf16x8*)(vbase + (size_t)lo * SPAD + quad * 8);
        const short* k1p = kbase + (size_t)(32 + lo) * 16 + (quad & 1) * 8;
        kxB = *(const bf16x8*)k1p;
        kyB = *(const bf16x8*)(k1p + 256);

        f32x4 c0 = __builtin_amdgcn_mfma_f32_16x16x32_bf16(aQ0, kxA, (f32x4){0.f,0.f,0.f,0.f}, 0, 0, 0);
        f32x4 c1 = __builtin_amdgcn_mfma_f32_16x16x32_bf16(aQ1, kxA, (f32x4){0.f,0.f,0.f,0.f}, 0, 0, 0);
        f32x4 c2 = __builtin_amdgcn_mfma_f32_16x16x32_bf16(aQ2, kxA, (f32x4){0.f,0.f,0.f,0.f}, 0, 0, 0);
        *(u32x2*)(wbp)        = pack4exp(c0, true);
        *(u32x2*)(wbp + 1088) = pack4exp(c1, true);
        *(u32x2*)(wbp + 2176) = pack4exp(c2, true);
        c0 = __builtin_amdgcn_mfma_f32_16x16x32_bf16(aQ0, kyA, (f32x4){0.f,0.f,0.f,0.f}, 0, 0, 0);
        c1 = __builtin_amdgcn_mfma_f32_16x16x32_bf16(aQ1, kyA, (f32x4){0.f,0.f,0.f,0.f}, 0, 0, 0);
        c2 = __builtin_amdgcn_mfma_f32_16x16x32_bf16(aQ2, kyA, (f32x4){0.f,0.f,0.f,0.f}, 0, 0, 0);
        *(u32x2*)(wbp + 544)  = pack4exp(c0, true);
        *(u32x2*)(wbp + 1632) = pack4exp(c1, true);
        *(u32x2*)(wbp + 2720) = pack4exp(c2, true);
    }

// Pipelined step: produce chunk CH, consume chunk CH-1. Single P buffer:
// tr-reads (issued first, drained before writes) rely on in-order DS.
#define STEP(CH, TAIL, KXC, KYC, KXN, KYN, VP, VC) do {                       \
    int ch_ = (CH);                                                            \
    if (!(TAIL)) {                                                             \
        const short* kn_ = kbase + (size_t)((ch_ + 1) * 32 + lo) * 16 + (quad & 1) * 8; \
        KXN = *(const bf16x8*)kn_;                                             \
        KYN = *(const bf16x8*)(kn_ + 256);                                     \
    }                                                                          \
    VC = *(const bf16x8*)(vbase + (size_t)lo * SPAD + ch_ * 32 + quad * 8);    \
    u32x2 p00_, p01_, p10_, p11_, p20_, p21_;                                  \
    asm volatile("ds_read_b64_tr_b16 %0, %1"             : "=v"(p00_) : "v"(rdp) : "memory"); \
    asm volatile("ds_read_b64_tr_b16 %0, %1 offset:136"  : "=v"(p01_) : "v"(rdp) : "memory"); \
    asm volatile("ds_read_b64_tr_b16 %0, %1 offset:1088" : "=v"(p10_) : "v"(rdp) : "memory"); \
    asm volatile("ds_read_b64_tr_b16 %0, %1 offset:1224" : "=v"(p11_) : "v"(rdp) : "memory"); \
    asm volatile("ds_read_b64_tr_b16 %0, %1 offset:2176" : "=v"(p20_) : "v"(rdp) : "memory"); \
    asm volatile("ds_read_b64_tr_b16 %0, %1 offset:2312" : "=v"(p21_) : "v"(rdp) : "memory"); \
    u32x2 wt0x_, wt1x_, wt2x_, wt0y_, wt1y_, wt2y_;                            \
    {                                                                          \
        f32x4 c0_ = __builtin_amdgcn_mfma_f32_16x16x32_bf16(aQ0, KXC, (f32x4){0.f,0.f,0.f,0.f}, 0, 0, 0); \
        f32x4 c1_ = __builtin_amdgcn_mfma_f32_16x16x32_bf16(aQ1, KXC, (f32x4){0.f,0.f,0.f,0.f}, 0, 0, 0); \
        f32x4 c2_ = __builtin_amdgcn_mfma_f32_16x16x32_bf16(aQ2, KXC, (f32x4){0.f,0.f,0.f,0.f}, 0, 0, 0); \
        bool v0_ = !(TAIL) || (lo == 0);                                       \
        wt0x_ = pack4exp(c0_, v0_);                                            \
        wt1x_ = pack4exp(c1_, v0_);                                            \
        wt2x_ = pack4exp(c2_, v0_);                                            \
        c0_ = __builtin_amdgcn_mfma_f32_16x16x32_bf16(aQ0, KYC, (f32x4){0.f,0.f,0.f,0.f}, 0, 0, 0); \
        c1_ = __builtin_amdgcn_mfma_f32_16x16x32_bf16(aQ1, KYC, (f32x4){0.f,0.f,0.f,0.f}, 0, 0, 0); \
        c2_ = __builtin_amdgcn_mfma_f32_16x16x32_bf16(aQ2, KYC, (f32x4){0.f,0.f,0.f,0.f}, 0, 0, 0); \
        bool v1_ = !(TAIL);                                                    \
        wt0y_ = pack4exp(c0_, v1_);                                            \
        wt1y_ = pack4exp(c1_, v1_);                                            \
        wt2y_ = pack4exp(c2_, v1_);                                            \
    }                                                                          \
    asm volatile("s_waitcnt lgkmcnt(0)" ::: "memory");                         \
    __builtin_amdgcn_sched_barrier(0);                                         \
    u32x4 q0_; q0_[0] = p00_[0]; q0_[1] = p00_[1]; q0_[2] = p01_[0]; q0_[3] = p01_[1]; \
    u32x4 q1_; q1_[0] = p10_[0]; q1_[1] = p10_[1]; q1_[2] = p11_[0]; q1_[3] = p11_[1]; \
    u32x4 q2_; q2_[0] = p20_[0]; q2_[1] = p20_[1]; q2_[2] = p21_[0]; q2_[3] = p21_[1]; \
    bf16x8 pB0_ = __builtin_bit_cast(bf16x8, q0_);                             \
    bf16x8 pB1_ = __builtin_bit_cast(bf16x8, q1_);                             \
    bf16x8 pB2_ = __builtin_bit_cast(bf16x8, q2_);                             \
    oc0 = __builtin_amdgcn_mfma_f32_16x16x32_bf16(VP, pB0_, oc0, 0, 0, 0);     \
    dn0 = __builtin_amdgcn_mfma_f32_16x16x32_bf16(aOne, pB0_, dn0, 0, 0, 0);   \
    oc1 = __builtin_amdgcn_mfma_f32_16x16x32_bf16(VP, pB1_, oc1, 0, 0, 0);     \
    dn1 = __builtin_amdgcn_mfma_f32_16x16x32_bf16(aOne, pB1_, dn1, 0, 0, 0);   \
    oc2 = __builtin_amdgcn_mfma_f32_16x16x32_bf16(VP, pB2_, oc2, 0, 0, 0);     \
    dn2 = __builtin_amdgcn_mfma_f32_16x16x32_bf16(aOne, pB2_, dn2, 0, 0, 0);   \
    *(u32x2*)(wbp)        = wt0x_;                                             \
    *(u32x2*)(wbp + 544)  = wt0y_;                                             \
    *(u32x2*)(wbp + 1088) = wt1x_;                                             \
    *(u32x2*)(wbp + 1632) = wt1y_;                                             \
    *(u32x2*)(wbp + 2176) = wt2x_;                                             \
    *(u32x2*)(wbp + 2720) = wt2y_;                                             \
} while (0)

    for (int chp = 1; chp < 31; chp += 2) {
        STEP(chp,     0, kxA, kyA, kxB, kyB, vA, vB);
        STEP(chp + 1, 0, kxB, kyB, kxA, kyA, vB, vA);
    }
    STEP(31, 0, kxA, kyA, kxB, kyB, vA, vB);
    STEP(32, 1, kxB, kyB, kxA, kyA, vB, vA);
#undef STEP

    // ---- epilogue: consume P(32), V(32) is in vA ----
    {
        u32x2 p00, p01, p10, p11, p20, p21;
        asm volatile("ds_read_b64_tr_b16 %0, %1"             : "=v"(p00) : "v"(rdp) : "memory");
        asm volatile("ds_read_b64_tr_b16 %0, %1 offset:136"  : "=v"(p01) : "v"(rdp) : "memory");
        asm volatile("ds_read_b64_tr_b16 %0, %1 offset:1088" : "=v"(p10) : "v"(rdp) : "memory");
        asm volatile("ds_read_b64_tr_b16 %0, %1 offset:1224" : "=v"(p11) : "v"(rdp) : "memory");
        asm volatile("ds_read_b64_tr_b16 %0, %1 offset:2176" : "=v"(p20) : "v"(rdp) : "memory");
        asm volatile("ds_read_b64_tr_b16 %0, %1 offset:2312" : "=v"(p21) : "v"(rdp) : "memory");
        asm volatile("s_waitcnt lgkmcnt(0)" ::: "memory");
        __builtin_amdgcn_sched_barrier(0);
        u32x4 q0; q0[0] = p00[0]; q0[1] = p00[1]; q0[2] = p01[0]; q0[3] = p01[1];
        u32x4 q1; q1[0] = p10[0]; q1[1] = p10[1]; q1[2] = p11[0]; q1[3] = p11[1];
        u32x4 q2; q2[0] = p20[0]; q2[1] = p20[1]; q2[2] = p21[0]; q2[3] = p21[1];
        bf16x8 pB0 = __builtin_bit_cast(bf16x8, q0);
        bf16x8 pB1 = __builtin_bit_cast(bf16x8, q1);
        bf16x8 pB2 = __builtin_bit_cast(bf16x8, q2);
        oc0 = __builtin_amdgcn_mfma_f32_16x16x32_bf16(vA, pB0, oc0, 0, 0, 0);
        dn0 = __builtin_amdgcn_mfma_f32_16x16x32_bf16(aOne, pB0, dn0, 0, 0, 0);
        oc1 = __builtin_amdgcn_mfma_f32_16x16x32_bf16(vA, pB1, oc1, 0, 0, 0);
        dn1 = __builtin_amdgcn_mfma_f32_16x16x32_bf16(aOne, pB1, dn1, 0, 0, 0);
        oc2 = __builtin_amdgcn_mfma_f32_16x16x32_bf16(vA, pB2, oc2, 0, 0, 0);
        dn2 = __builtin_amdgcn_mfma_f32_16x16x32_bf16(aOne, pB2, dn2, 0, 0, 0);
    }

    {
        int qrow = qg0 + lo;
        if (qrow < S1C) {
            float inv = 1.0f / dn0[0];
            unsigned p0 = (unsigned short)f2b(oc0[0] * inv) | ((unsigned)(unsigned short)f2b(oc0[1] * inv) << 16);
            unsigned p1 = (unsigned short)f2b(oc0[2] * inv) | ((unsigned)(unsigned short)f2b(oc0[3] * inv) << 16);
            *(uint2*)(ob + ((size_t)b * S1C + qrow) * DD + h * DHD + quad * 4) = make_uint2(p0, p1);
        }
    }
    {
        int qrow = qg1 + lo;
        if (qrow < S1C) {
            float inv = 1.0f / dn1[0];
            unsigned p0 = (unsigned short)f2b(oc1[0] * inv) | ((unsigned)(unsigned short)f2b(oc1[1] * inv) << 16);
            unsigned p1 = (unsigned short)f2b(oc1[2] * inv) | ((unsigned)(unsigned short)f2b(oc1[3] * inv) << 16);
            *(uint2*)(ob + ((size_t)b * S1C + qrow) * DD + h * DHD + quad * 4) = make_uint2(p0, p1);
        }
    }
    {
        int qrow = qg2 + lo;
        if (qrow < S1C) {
            float inv = 1.0f / dn2[0];
            unsigned p0 = (unsigned short)f2b(oc2[0] * inv) | ((unsigned)(unsigned short)f2b(oc2[1] * inv) << 16);
            unsigned p1 = (unsigned short)f2b(oc2[2] * inv) | ((unsigned)(unsigned short)f2b(oc2[3] * inv) << 16);
            *(uint2*)(ob + ((size_t)b * S1C + qrow) * DD + h * DHD + quad * 4) = make_uint2(p0, p1);
        }
    }
}

// ---------------------------------------------------------------------------
// Kernel 4: fused transformer tail (r19 measured-best version).
// ---------------------------------------------------------------------------
__global__ __launch_bounds__(256) void k_block(
    const short* __restrict__ ob, float* __restrict__ x,
    const short* __restrict__ woT, fp bo, fp ln1s, fp ln1b,
    const short* __restrict__ w1T, fp b1, const short* __restrict__ w2T, fp b2,
    fp ln2s, fp ln2b,
    const short* __restrict__ wqkvTn, fp bqn, fp bkn, fp bvn,
    short* __restrict__ qb, short* __restrict__ kb, short* __restrict__ vbt,
    int has_next)
{
    int blk = blockIdx.x, t = threadIdx.x;
    int tok0 = blk * FT2;
    int w = t >> 6, l = t & 63;
    int quad = l >> 4, lo = l & 15;

    __shared__ float otf[FT2][OPAD];          // 8704 B; ys overlays (136-short rows)
    __shared__ u32x2 hidtr[2][8][136];        // 17408 B: [tile][kchunk][subtiles]
    short* ysb = (short*)&otf[0][0];
    char*  hidc = (char*)&hidtr[0][0][0];
    unsigned hidbase = (unsigned)(uintptr_t)hidc;

    // ---- LN lane mapping + entry prefetch (hidden under oproj) ----
    int tt8 = t >> 3;            // token 0..31
    int d8s = (t & 7) * 8;       // dim base
    const float* xrow = x + (size_t)(tok0 + tt8) * DD + d8s;
    float4 xpa = *(const float4*)xrow;
    float4 xpb = *(const float4*)(xrow + 4);
    float4 s1a = *(const float4*)(ln1s + d8s);
    float4 s1b = *(const float4*)(ln1s + d8s + 4);
    float4 b1a = *(const float4*)(ln1b + d8s);
    float4 b1b = *(const float4*)(ln1b + d8s + 4);

    // ---- oproj (both token-tiles, weights loaded once) ----
    {
        const short* obp0 = ob + ((size_t)(tok0 + lo)) * DD;
        const short* obp1 = ob + ((size_t)(tok0 + 16 + lo)) * DD;
        bf16x8 a0 = *(const bf16x8*)(obp0 + quad * 8);
        bf16x8 a1 = *(const bf16x8*)(obp0 + 32 + quad * 8);
        bf16x8 a2 = *(const bf16x8*)(obp1 + quad * 8);
        bf16x8 a3 = *(const bf16x8*)(obp1 + 32 + quad * 8);
        int n = w * 16 + lo;
        const short* wT = woT + (size_t)n * 64;
        bf16x8 b0 = *(const bf16x8*)(wT + quad * 8);
        bf16x8 bb = *(const bf16x8*)(wT + 32 + quad * 8);
        f32x4 c0 = __builtin_amdgcn_mfma_f32_16x16x32_bf16(a0, b0, (f32x4){0,0,0,0}, 0, 0, 0);
        c0 = __builtin_amdgcn_mfma_f32_16x16x32_bf16(a1, bb, c0, 0, 0, 0);
        f32x4 c1 = __builtin_amdgcn_mfma_f32_16x16x32_bf16(a2, b0, (f32x4){0,0,0,0}, 0, 0, 0);
        c1 = __builtin_amdgcn_mfma_f32_16x16x32_bf16(a3, bb, c1, 0, 0, 0);
        float bov = bo[n];
        #pragma unroll
        for (int r = 0; r < 4; ++r) {
            otf[quad * 4 + r][n] = c0[r] + bov;
            otf[16 + quad * 4 + r][n] = c1[r] + bov;
        }
    }
    __syncthreads();

    // ---- LN1 (8 lanes per token) ----
    float yv[8];
    {
        float4 o0 = *(const float4*)&otf[tt8][d8s];
        float4 o1 = *(const float4*)&otf[tt8][d8s + 4];
        float v0 = o0.x + xpa.x, v1 = o0.y + xpa.y, v2 = o0.z + xpa.z, v3 = o0.w + xpa.w;
        float v4 = o1.x + xpb.x, v5 = o1.y + xpb.y, v6 = o1.z + xpb.z, v7 = o1.w + xpb.w;
        float sum = ((v0 + v1) + (v2 + v3)) + ((v4 + v5) + (v6 + v7));
        float vs = v0 * v0;
        vs = fmaf(v1, v1, vs); vs = fmaf(v2, v2, vs); vs = fmaf(v3, v3, vs);
        vs = fmaf(v4, v4, vs); vs = fmaf(v5, v5, vs); vs = fmaf(v6, v6, vs);
        vs = fmaf(v7, v7, vs);
        sum += __shfl_xor(sum, 1, 64); sum += __shfl_xor(sum, 2, 64); sum += __shfl_xor(sum, 4, 64);
        vs  += __shfl_xor(vs , 1, 64); vs  += __shfl_xor(vs , 2, 64); vs  += __shfl_xor(vs , 4, 64);
        float mean = sum * (1.0f / 64.0f);
        float var = vs * (1.0f / 64.0f) - mean * mean;
        float rs = rsqrtf(var + 1e-5f);
        yv[0] = (v0 - mean) * rs * s1a.x + b1a.x;
        yv[1] = (v1 - mean) * rs * s1a.y + b1a.y;
        yv[2] = (v2 - mean) * rs * s1a.z + b1a.z;
        yv[3] = (v3 - mean) * rs * s1a.w + b1a.w;
        yv[4] = (v4 - mean) * rs * s1b.x + b1b.x;
        yv[5] = (v5 - mean) * rs * s1b.y + b1b.y;
        yv[6] = (v6 - mean) * rs * s1b.z + b1b.z;
        yv[7] = (v7 - mean) * rs * s1b.w + b1b.w;
        u32x2 pa = pack4cvt(yv[0], yv[1], yv[2], yv[3]);
        u32x2 pb = pack4cvt(yv[4], yv[5], yv[6], yv[7]);
        *(u32x4*)&ysb[tt8 * 136 + d8s] = (u32x4){pa[0], pa[1], pb[0], pb[1]};
    }
    __syncthreads();

    // ---- FFN1: hid = gelu(y @ w1 + b1), tr-layout packed b64 writes ----
    {
        bf16x8 a0 = *(const bf16x8*)&ysb[(size_t)lo * 136 + quad * 8];
        bf16x8 a1 = *(const bf16x8*)&ysb[(size_t)lo * 136 + 32 + quad * 8];
        bf16x8 a2 = *(const bf16x8*)&ysb[(size_t)(16 + lo) * 136 + quad * 8];
        bf16x8 a3 = *(const bf16x8*)&ysb[(size_t)(16 + lo) * 136 + 32 + quad * 8];
        unsigned hoff = (unsigned)(w * 2176 + (lo >> 2) * 136 + (lo & 3) * 32 + quad * 8);
        #pragma unroll
        for (int i = 0; i < 4; ++i) {
            int n = w * 64 + i * 16 + lo;
            const short* wT = w1T + (size_t)n * 64;
            bf16x8 b0 = *(const bf16x8*)(wT + quad * 8);
            bf16x8 bb = *(const bf16x8*)(wT + 32 + quad * 8);
            f32x4 c0 = __builtin_amdgcn_mfma_f32_16x16x32_bf16(a0, b0, (f32x4){0,0,0,0}, 0, 0, 0);
            c0 = __builtin_amdgcn_mfma_f32_16x16x32_bf16(a1, bb, c0, 0, 0, 0);
            f32x4 c1 = __builtin_amdgcn_mfma_f32_16x16x32_bf16(a2, b0, (f32x4){0,0,0,0}, 0, 0, 0);
            c1 = __builtin_amdgcn_mfma_f32_16x16x32_bf16(a3, bb, c1, 0, 0, 0);
            float b1v = b1[n];
            unsigned off = hoff + (i >> 1) * 1088 + (i & 1) * 544;
            *(u32x2*)(hidc + off) = pack4cvt(
                gelu_fast(c0[0] + b1v), gelu_fast(c0[1] + b1v),
                gelu_fast(c0[2] + b1v), gelu_fast(c0[3] + b1v));
            *(u32x2*)(hidc + 8704 + off) = pack4cvt(
                gelu_fast(c1[0] + b1v), gelu_fast(c1[1] + b1v),
                gelu_fast(c1[2] + b1v), gelu_fast(c1[3] + b1v));
        }
    }
    __syncthreads();

    // ---- FFN2: out = hid @ w2 + b2 (K=256), tr-read A-frags, depth-2 pipe ----
    {
        f32x4 c20 = {0.f,0.f,0.f,0.f}, c21 = {0.f,0.f,0.f,0.f};
        const short* wT2 = w2T + (size_t)(w * 16 + lo) * 256;
        unsigned ro = (unsigned)(quad * 272 + lo * 8);
        unsigned tb0 = hidbase + ro;
        unsigned tb1 = hidbase + 8704 + ro;
        u32x2 pA0, pA1, pA2, pA3, pB0, pB1, pB2, pB3;

#define TRRD(dst, addr, OFFSTR) \
    asm volatile("ds_read_b64_tr_b16 %0, %1 offset:" OFFSTR : "=v"(dst) : "v"(addr))
#define ISS(P0,P1,P2,P3, O1, O2) \
    TRRD(P0, tb0, O1); TRRD(P1, tb0, O2); TRRD(P2, tb1, O1); TRRD(P3, tb1, O2)
#define W4 asm volatile("s_waitcnt lgkmcnt(4)" ::: "memory"); __builtin_amdgcn_sched_barrier(0)
#define W0 asm volatile("s_waitcnt lgkmcnt(0)" ::: "memory"); __builtin_amdgcn_sched_barrier(0)
#define CONS(P0,P1,P2,P3, BF) do { \
    u32x4 q0_; q0_[0]=P0[0]; q0_[1]=P0[1]; q0_[2]=P1[0]; q0_[3]=P1[1]; \
    u32x4 q1_; q1_[0]=P2[0]; q1_[1]=P2[1]; q1_[2]=P3[0]; q1_[3]=P3[1]; \
    c20 = __builtin_amdgcn_mfma_f32_16x16x32_bf16(__builtin_bit_cast(bf16x8,q0_), BF, c20, 0,0,0); \
    c21 = __builtin_amdgcn_mfma_f32_16x16x32_bf16(__builtin_bit_cast(bf16x8,q1_), BF, c21, 0,0,0); \
} while (0)

        bf16x8 bfA = *(const bf16x8*)(wT2 + quad * 8);
        ISS(pA0,pA1,pA2,pA3, "0",    "136");
        bf16x8 bfB = *(const bf16x8*)(wT2 + 32 + quad * 8);
        ISS(pB0,pB1,pB2,pB3, "1088", "1224");
        W4; CONS(pA0,pA1,pA2,pA3, bfA);
        bfA = *(const bf16x8*)(wT2 + 64 + quad * 8);
        ISS(pA0,pA1,pA2,pA3, "2176", "2312");
        W4; CONS(pB0,pB1,pB2,pB3, bfB);
        bfB = *(const bf16x8*)(wT2 + 96 + quad * 8);
        ISS(pB0,pB1,pB2,pB3, "3264", "3400");
        W4; CONS(pA0,pA1,pA2,pA3, bfA);
        bfA = *(const bf16x8*)(wT2 + 128 + quad * 8);
        ISS(pA0,pA1,pA2,pA3, "4352", "4488");
        W4; CONS(pB0,pB1,pB2,pB3, bfB);
        bfB = *(const bf16x8*)(wT2 + 160 + quad * 8);
        ISS(pB0,pB1,pB2,pB3, "5440", "5576");
        W4; CONS(pA0,pA1,pA2,pA3, bfA);
        bfA = *(const bf16x8*)(wT2 + 192 + quad * 8);
        ISS(pA0,pA1,pA2,pA3, "6528", "6664");
        W4; CONS(pB0,pB1,pB2,pB3, bfB);
        bfB = *(const bf16x8*)(wT2 + 224 + quad * 8);
        ISS(pB0,pB1,pB2,pB3, "7616", "7752");
        W4; CONS(pA0,pA1,pA2,pA3, bfA);
        W0; CONS(pB0,pB1,pB2,pB3, bfB);
#undef TRRD
#undef ISS
#undef W4
#undef W0
#undef CONS

        float b2v = b2[w * 16 + lo];
        #pragma unroll
        for (int r = 0; r < 4; ++r) {
            otf[quad * 4 + r][w * 16 + lo] = c20[r] + b2v;
            otf[16 + quad * 4 + r][w * 16 + lo] = c21[r] + b2v;
        }
    }
    __syncthreads();

    // ---- LN2 (8 lanes per token); residual = yv (registers) ----
    {
        float4 s2a = *(const float4*)(ln2s + d8s);
        float4 s2b = *(const float4*)(ln2s + d8s + 4);
        float4 b2a = *(const float4*)(ln2b + d8s);
        float4 b2b = *(const float4*)(ln2b + d8s + 4);
        float4 o0 = *(const float4*)&otf[tt8][d8s];
        float4 o1 = *(const float4*)&otf[tt8][d8s + 4];
        float v0 = o0.x + yv[0], v1 = o0.y + yv[1], v2 = o0.z + yv[2], v3 = o0.w + yv[3];
        float v4 = o1.x + yv[4], v5 = o1.y + yv[5], v6 = o1.z + yv[6], v7 = o1.w + yv[7];
        float sum = ((v0 + v1) + (v2 + v3)) + ((v4 + v5) + (v6 + v7));
        float vs = v0 * v0;
        vs = fmaf(v1, v1, vs); vs = fmaf(v2, v2, vs); vs = fmaf(v3, v3, vs);
        vs = fmaf(v4, v4, vs); vs = fmaf(v5, v5, vs); vs = fmaf(v6, v6, vs);
        vs = fmaf(v7, v7, vs);
        sum += __shfl_xor(sum, 1, 64); sum += __shfl_xor(sum, 2, 64); sum += __shfl_xor(sum, 4, 64);
        vs  += __shfl_xor(vs , 1, 64); vs  += __shfl_xor(vs , 2, 64); vs  += __shfl_xor(vs , 4, 64);
        float mean = sum * (1.0f / 64.0f);
        float var = vs * (1.0f / 64.0f) - mean * mean;
        float rs = rsqrtf(var + 1e-5f);
        float y0 = (v0 - mean) * rs * s2a.x + b2a.x;
        float y1 = (v1 - mean) * rs * s2a.y + b2a.y;
        float y2 = (v2 - mean) * rs * s2a.z + b2a.z;
        float y3 = (v3 - mean) * rs * s2a.w + b2a.w;
        float y4 = (v4 - mean) * rs * s2b.x + b2b.x;
        float y5 = (v5 - mean) * rs * s2b.y + b2b.y;
        float y6 = (v6 - mean) * rs * s2b.z + b2b.z;
        float y7 = (v7 - mean) * rs * s2b.w + b2b.w;
        float* xo = x + (size_t)(tok0 + tt8) * DD + d8s;
        *(float4*)xo = make_float4(y0, y1, y2, y3);
        *(float4*)(xo + 4) = make_float4(y4, y5, y6, y7);
        u32x2 pa = pack4cvt(y0, y1, y2, y3);
        u32x2 pb = pack4cvt(y4, y5, y6, y7);
        *(u32x4*)&ysb[tt8 * 136 + d8s] = (u32x4){pa[0], pa[1], pb[0], pb[1]};
    }
    __syncthreads();

    // ---- next-layer QKV, both tiles ----
    if (has_next) {
        bf16x8 a0 = *(const bf16x8*)&ysb[(size_t)lo * 136 + quad * 8];
        bf16x8 a1 = *(const bf16x8*)&ysb[(size_t)lo * 136 + 32 + quad * 8];
        bf16x8 a2 = *(const bf16x8*)&ysb[(size_t)(16 + lo) * 136 + quad * 8];
        bf16x8 a3 = *(const bf16x8*)&ysb[(size_t)(16 + lo) * 136 + 32 + quad * 8];
        int n = w * 16 + lo;
        #pragma unroll
        for (int p = 0; p < 3; ++p) {
            const short* wT = wqkvTn + (size_t)p * 4096 + (size_t)n * 64;
            bf16x8 b0 = *(const bf16x8*)(wT + quad * 8);
            bf16x8 bb = *(const bf16x8*)(wT + 32 + quad * 8);
            f32x4 c0 = __builtin_amdgcn_mfma_f32_16x16x32_bf16(a0, b0, (f32x4){0,0,0,0}, 0, 0, 0);
            c0 = __builtin_amdgcn_mfma_f32_16x16x32_bf16(a1, bb, c0, 0, 0, 0);
            f32x4 c1 = __builtin_amdgcn_mfma_f32_16x16x32_bf16(a2, b0, (f32x4){0,0,0,0}, 0, 0, 0);
            c1 = __builtin_amdgcn_mfma_f32_16x16x32_bf16(a3, bb, c1, 0, 0, 0);
            float bias = (p == 0) ? bqn[n] * QSCL : (p == 1) ? bkn[n] : bvn[n];
            #pragma unroll
            for (int r = 0; r < 4; ++r) {
                int tok = tok0 + quad * 4 + r;
                int bb0 = tok / S1C, ss0 = tok % S1C;
                int bh = bb0 * NHD + w;
                short val = f2b(c0[r] + bias);
                int tok2 = tok + 16;
                int bb1 = tok2 / S1C, ss1 = tok2 % S1C;
                int bh2 = bb1 * NHD + w;
                short val2 = f2b(c1[r] + bias);
                if (p == 0) {
                    qb[((size_t)bh * SPAD + ss0) * 16 + lo] = val;
                    qb[((size_t)bh2 * SPAD + ss1) * 16 + lo] = val2;
                } else if (p == 1) {
                    kb[((size_t)bh * SPAD + ss0) * 16 + lo] = val;
                    kb[((size_t)bh2 * SPAD + ss1) * 16 + lo] = val2;
                } else {
                    vbt[((size_t)bh * 16 + lo) * SPAD + ss0] = val;
                    vbt[((size_t)bh2 * 16 + lo) * SPAD + ss1] = val2;
                }
            }
        }
    }
}

// ---------------------------------------------------------------------------
// Kernel 6: head MLPs. One block (64 thr) per batch element.
// ---------------------------------------------------------------------------
__global__ __launch_bounds__(64) void k_head(
    const float* __restrict__ x, fp proj_vars, fp param_vars,
    const int* __restrict__ materials,
    fp pw1, fp pb1, fp pw2, fp pb2, fp pw3, fp pb3,
    fp pw4, fp pb4, fp pw5, fp pb5,
    fp ipw1, fp ipb1, fp ipw2, fp ipb2,
    fp hw1, fp hb1, fp hw2, fp hb2, fp hw3, fp hb3,
    float* __restrict__ out)
{
    int b = blockIdx.x;
    int tid = threadIdx.x;
    __shared__ float A[80], Bf[80], pp[8], mi[32];

    if (tid < 3) A[tid] = proj_vars[b * 3 + tid];
    A[3 + tid] = x[((size_t)b * S1C + 0) * DD + tid];
    __syncthreads();

    if (tid < 34) {
        float a = pb1[tid];
        for (int i = 0; i < 67; ++i) a += A[i] * pw1[i * 34 + tid];
        Bf[tid] = gelu_exact(a);
    }
    __syncthreads();
    if (tid < 11) {
        float a = pb2[tid];
        for (int i = 0; i < 34; ++i) a += Bf[i] * pw2[i * 11 + tid];
        A[tid] = gelu_exact(a);
    }
    __syncthreads();
    if (tid < 36) {
        float a = pb3[tid];
        for (int i = 0; i < 11; ++i) a += A[i] * pw3[i * 36 + tid];
        Bf[tid] = gelu_exact(a);
    }
    __syncthreads();
    if (tid < 22) {
        float a = pb4[tid];
        for (int i = 0; i < 36; ++i) a += Bf[i] * pw4[i * 22 + tid];
        A[tid] = gelu_exact(a);
    }
    __syncthreads();
    if (tid < 24) {
        float a = pb5[tid];
        for (int i = 0; i < 22; ++i) a += A[i] * pw5[i * 24 + tid];
        mi[3 + tid] = a;
    }
    if (tid < 3) {
        float a = ipb1[tid];
        for (int i = 0; i < 3; ++i) a += param_vars[b * 3 + i] * ipw1[i * 3 + tid];
        pp[tid] = gelu_exact(a);
    }
    __syncthreads();
    if (tid < 3) {
        float a = ipb2[tid];
        for (int i = 0; i < 3; ++i) a += pp[i] * ipw2[i * 3 + tid];
        mi[tid] = a;
    }
    __syncthreads();

    int m = materials[b];
    if (tid < 15) {
        float a = hb1[m * 15 + tid];
        for (int i = 0; i < 27; ++i) a += mi[i] * hw1[(m * 27 + i) * 15 + tid];
        A[tid] = gelu_exact(a);
    }
    __syncthreads();
    if (tid < 18) {
        float a = hb2[m * 18 + tid];
        for (int i = 0; i < 15; ++i) a += A[i] * hw2[(m * 15 + i) * 18 + tid];
        Bf[tid] = gelu_exact(a);
    }
    __syncthreads();
    if (tid == 0) {
        float a = hb3[m];
        for (int i = 0; i < 18; ++i) a += Bf[i] * hw3[m * 18 + i];
        out[b] = a;
    }
}

// ---------------------------------------------------------------------------
extern "C" void kernel_launch(void* const* d_in, const int* in_sizes, int n_in,
                              void* d_out, int out_size, void* d_ws, size_t ws_size,
                              hipStream_t stream) {
    fp in_seq     = (fp)d_in[0];
    fp proj_vars  = (fp)d_in[1];
    fp param_vars = (fp)d_in[2];
    const int* materials = (const int*)d_in[3];
    fp enc_w1 = (fp)d_in[4];
    fp enc_b1 = (fp)d_in[5];
    fp enc_w2 = (fp)d_in[6];
    fp enc_b2 = (fp)d_in[7];
    fp sos    = (fp)d_in[8];
    fp tl_wq  = (fp)d_in[9];
    fp tl_wk  = (fp)d_in[10];
    fp tl_wv  = (fp)d_in[11];
    fp tl_bq  = (fp)d_in[12];
    fp tl_bk  = (fp)d_in[13];
    fp tl_bv  = (fp)d_in[14];
    fp tl_wo  = (fp)d_in[15];
    fp tl_bo  = (fp)d_in[16];
    fp tl_ln1s = (fp)d_in[17];
    fp tl_ln1b = (fp)d_in[18];
    fp tl_ln2s = (fp)d_in[19];
    fp tl_ln2b = (fp)d_in[20];
    fp tl_fw1 = (fp)d_in[21];
    fp tl_fb1 = (fp)d_in[22];
    fp tl_fw2 = (fp)d_in[23];
    fp tl_fb2 = (fp)d_in[24];
    fp pw1 = (fp)d_in[25]; fp pb1 = (fp)d_in[26];
    fp pw2 = (fp)d_in[27]; fp pb2 = (fp)d_in[28];
    fp pw3 = (fp)d_in[29]; fp pb3 = (fp)d_in[30];
    fp pw4 = (fp)d_in[31]; fp pb4 = (fp)d_in[32];
    fp pw5 = (fp)d_in[33]; fp pb5 = (fp)d_in[34];
    fp ipw1 = (fp)d_in[35]; fp ipb1 = (fp)d_in[36];
    fp ipw2 = (fp)d_in[37]; fp ipb2 = (fp)d_in[38];
    fp hw1 = (fp)d_in[39]; fp hb1 = (fp)d_in[40];
    fp hw2 = (fp)d_in[41]; fp hb2 = (fp)d_in[42];
    fp hw3 = (fp)d_in[43]; fp hb3 = (fp)d_in[44];

    // Workspace layout (xb slot retained but unused since r20 fusion)
    float* x  = (float*)d_ws;                           // NTOK*64 fp32
    short* ob = (short*)(x + (size_t)NTOK * DD);        // NTOK*64 bf16
    short* xb = ob + (size_t)NTOK * DD;                 // NTOK*64 bf16 (unused)
    short* qb = xb + (size_t)NTOK * DD;
    short* kb = qb + (size_t)NBH * SPAD * 16;
    short* vbt = kb + (size_t)NBH * SPAD * 16;
    short* wqkvT = vbt + (size_t)NBH * 16 * SPAD;       // 3 x 12288
    short* woT = wqkvT + (size_t)NLAY * 12288;          // 3 x 4096
    short* w1T = woT + (size_t)NLAY * 4096;             // 3 x 16384
    short* w2T = w1T + (size_t)NLAY * 16384;            // 3 x 16384

    k_wconv<<<dim3(192, NLAY), 256, 0, stream>>>(
        tl_wq, tl_wk, tl_wv, tl_wo, tl_fw1, tl_fw2, wqkvT, woT, w1T, w2T);
    k_zero<<<NBH, 64, 0, stream>>>(qb, kb, vbt);
    k_encqkv<<<NTOK / FTQ, 256, 0, stream>>>(
        in_seq, enc_w1, enc_b1, enc_w2, enc_b2, sos,
        wqkvT, tl_bq, tl_bk, tl_bv,
        x, qb, kb, vbt);

    for (int l = 0; l < NLAY; ++l) {
        k_attn<<<NBH * TGRP, 128, 0, stream>>>(qb, kb, vbt, ob);
        int ln = (l + 1 < NLAY) ? (l + 1) : l;   // dummy ptrs for last layer
        k_block<<<NTOK / FT2, 256, 0, stream>>>(
            ob, x,
            woT + (size_t)l * 4096, tl_bo + (size_t)l * DD,
            tl_ln1s + (size_t)l * DD, tl_ln1b + (size_t)l * DD,
            w1T + (size_t)l * 16384, tl_fb1 + (size_t)l * DFFC,
            w2T + (size_t)l * 16384, tl_fb2 + (size_t)l * DD,
            tl_ln2s + (size_t)l * DD, tl_ln2b + (size_t)l * DD,
            wqkvT + (size_t)ln * 12288,
            tl_bq + (size_t)ln * DD, tl_bk + (size_t)ln * DD, tl_bv + (size_t)ln * DD,
            qb, kb, vbt,
            (l + 1 < NLAY) ? 1 : 0);
    }

    k_head<<<BB, 64, 0, stream>>>(
        x, proj_vars, param_vars, materials,
        pw1, pb1, pw2, pb2, pw3, pb3, pw4, pb4, pw5, pb5,
        ipw1, ipb1, ipw2, ipb2,
        hw1, hb1, hw2, hb2, hw3, hb3,
        (float*)d_out);
}

// Round 12
// 463.170 us; speedup vs baseline: 1.0274x; 1.0170x over previous
//
#include <hip/hip_runtime.h>
#include <hip/hip_bf16.h>
#include <math.h>

// Problem constants
#define BB   64
#define SS   1024
#define S1C  1025
#define DD   64
#define NHD  4
#define NBH  (BB * NHD)      // 256
#define DHD  16
#define DFFC 256
#define NLAY 3
#define NTOK (BB * S1C)      // 65600 = 32 * 2050
#define SPAD 1056            // padded key/seq length (66 * 16)
#define TGRP 11              // 11 blocks/bh x 2 tile-slots = 22 slots = 66 tiles
#define FTQ   32             // tokens per block (k_encqkv) - 2 token-tiles/wave
#define FT2   32             // tokens per block (k_block) - 2 token-tiles/wave
#define OPAD 68              // ot row stride in floats (ys overlays at 136 shorts)
#define QSCL 0.36067376022224085f   // 0.25 * log2(e) folded into q

typedef const float* fp;
typedef __attribute__((ext_vector_type(8))) short bf16x8;
typedef __attribute__((ext_vector_type(4))) float f32x4;
typedef __attribute__((ext_vector_type(2))) unsigned int u32x2;
typedef __attribute__((ext_vector_type(4))) unsigned int u32x4;

#if __has_builtin(__builtin_amdgcn_exp2f)
#define RAW_EXP2(x) __builtin_amdgcn_exp2f(x)
#else
#define RAW_EXP2(x) __expf(0.6931471805599453f * (x))
#endif
#if __has_builtin(__builtin_amdgcn_rcpf)
#define RAW_RCP(x) __builtin_amdgcn_rcpf(x)
#else
#define RAW_RCP(x) (1.0f / (x))
#endif

__device__ __forceinline__ float gelu_exact(float x) {
    return 0.5f * x * (1.0f + erff(x * 0.7071067811865475f));
}
// A&S 7.1.26 erf approximation, |err| <= 1.5e-7 (<< bf16 rounding noise)
__device__ __forceinline__ float erf_fast(float x) {
    float ax = fabsf(x);
    float t = RAW_RCP(1.0f + 0.3275911f * ax);
    float p = t * (0.254829592f + t * (-0.284496736f + t * (1.421413741f +
              t * (-1.453152027f + t * 1.061405429f))));
    float e = RAW_EXP2(ax * ax * -1.4426950408889634f);
    float r = 1.0f - p * e;
    return copysignf(r, x);
}
__device__ __forceinline__ float gelu_fast(float x) {
    return 0.5f * x * (1.0f + erf_fast(x * 0.7071067811865475f));
}
// RTNE float->bf16 (finite values), 3 ops
__device__ __forceinline__ short f2b(float f) {
    unsigned u = __float_as_uint(f);
    return (short)((u + 0x7fffu + ((u >> 16) & 1u)) >> 16);
}

// pack 4 fp32 exp results -> 4 bf16 in one u32x2 via v_cvt_pk_bf16_f32
__device__ __forceinline__ u32x2 pack4exp(f32x4 c, bool valid) {
    float e0 = valid ? RAW_EXP2(c[0]) : 0.f;
    float e1 = valid ? RAW_EXP2(c[1]) : 0.f;
    float e2 = valid ? RAW_EXP2(c[2]) : 0.f;
    float e3 = valid ? RAW_EXP2(c[3]) : 0.f;
    unsigned r0, r1;
    asm("v_cvt_pk_bf16_f32 %0, %1, %2" : "=v"(r0) : "v"(e0), "v"(e1));
    asm("v_cvt_pk_bf16_f32 %0, %1, %2" : "=v"(r1) : "v"(e2), "v"(e3));
    return (u32x2){r0, r1};
}
// pack 4 fp32 -> 4 bf16 via cvt_pk (RTNE)
__device__ __forceinline__ u32x2 pack4cvt(float x0, float x1, float x2, float x3) {
    unsigned r0, r1;
    asm("v_cvt_pk_bf16_f32 %0, %1, %2" : "=v"(r0) : "v"(x0), "v"(x1));
    asm("v_cvt_pk_bf16_f32 %0, %1, %2" : "=v"(r1) : "v"(x2), "v"(x3));
    return (u32x2){r0, r1};
}

// ---------------------------------------------------------------------------
// Kernel W: one-shot weight convert+transpose to bf16 [n][k] fragments.
// ---------------------------------------------------------------------------
__global__ __launch_bounds__(256) void k_wconv(
    fp wq, fp wk, fp wv, fp wo, fp w1, fp w2,
    short* __restrict__ wqkvT, short* __restrict__ woT,
    short* __restrict__ w1T, short* __restrict__ w2T)
{
    int l = blockIdx.y;
    int i = blockIdx.x * 256 + threadIdx.x;
    if (i < 12288) {
        int p = i >> 12, rem = i & 4095;
        int d = rem >> 6, j = rem & 63;
        fp src = (p == 0 ? wq : p == 1 ? wk : wv) + (size_t)l * 4096;
        float v = src[j * 64 + d];
        if (p == 0) v *= QSCL;
        wqkvT[(size_t)l * 12288 + i] = f2b(v);
    } else if (i < 16384) {
        int rem = i - 12288;
        woT[(size_t)l * 4096 + rem] = f2b(wo[(size_t)l * 4096 + (rem & 63) * 64 + (rem >> 6)]);
    } else if (i < 32768) {
        int rem = i - 16384;
        w1T[(size_t)l * 16384 + rem] = f2b(w1[(size_t)l * 16384 + (rem & 63) * 256 + (rem >> 6)]);
    } else {
        int rem = i - 32768;
        w2T[(size_t)l * 16384 + rem] = f2b(w2[(size_t)l * 16384 + (rem & 255) * 64 + (rem >> 8)]);
    }
}

// ---------------------------------------------------------------------------
// Kernel 0: zero the pad regions of the bf16 q/k/v buffers (rows 1025..1055).
// ---------------------------------------------------------------------------
__global__ __launch_bounds__(64) void k_zero(
    short* __restrict__ qb, short* __restrict__ kb, short* __restrict__ vbt)
{
    int bh = blockIdx.x, t = threadIdx.x;
    for (int i = t; i < 31 * 16; i += 64) {
        int r = i >> 4, c = i & 15;
        size_t idx = ((size_t)bh * SPAD + 1025 + r) * 16 + c;
        qb[idx] = 0; kb[idx] = 0;
    }
    for (int i = t; i < 16 * 31; i += 64) {
        int e = i / 31, c = i % 31;
        vbt[((size_t)bh * 16 + e) * SPAD + 1025 + c] = 0;
    }
}

// ---------------------------------------------------------------------------
// Kernel 1+2 fused (r20): encoder MLP + sos + positional encoding directly
// into an LDS tile (32 tokens), then the layer-0 MFMA Q/K/V projection from
// LDS. Removes the xb global round-trip and one dispatch.
// ---------------------------------------------------------------------------
__global__ __launch_bounds__(256) void k_encqkv(
    fp in_seq, fp enc_w1, fp enc_b1, fp enc_w2, fp enc_b2, fp sos,
    const short* __restrict__ wqkvT, fp bq, fp bk, fp bv,
    float* __restrict__ x,
    short* __restrict__ qb, short* __restrict__ kb, short* __restrict__ vbt)
{
    int t = threadIdx.x;
    int tok0 = blockIdx.x * FTQ;
    int w = t >> 6, d = t & 63;
    __shared__ float e[4][48];
    __shared__ short xs[FTQ][72];

    // ---- encode phase: 8 passes x 4 tokens (wave w -> token i*4+w) ----
    int i2 = (d >> 1) * 2;
    float factor = RAW_EXP2((float)i2 * (-9.210340371976184f / 64.0f) * 1.4426950408889634f);
    for (int i = 0; i < 8; ++i) {
        int tl = i * 4 + w;
        int tok = tok0 + tl;
        int b = tok / S1C, s = tok % S1C;
        float val;
        if (s == 0) {
            val = sos[d];
        } else {
            float tin = in_seq[b * SS + (s - 1)];
            if (d < 48) e[w][d] = gelu_fast(tin * enc_w1[d] + enc_b1[d]);
            float acc = enc_b2[d];
            for (int j = 0; j < 48; ++j) acc += e[w][j] * enc_w2[j * DD + d];
            val = acc;
        }
        float ang = (float)s * factor;
        val += (d & 1) ? __cosf(ang) : __sinf(ang);
        x[(size_t)tok * DD + d] = val;
        xs[tl][d] = f2b(val);
    }
    __syncthreads();

    // ---- QKV phase (identical to old k_qkv, A-fragments from LDS) ----
    int l = t & 63;
    int quad = l >> 4, lo = l & 15;
    bf16x8 a0 = *(const bf16x8*)&xs[lo][quad * 8];
    bf16x8 a1 = *(const bf16x8*)&xs[lo][32 + quad * 8];
    bf16x8 a2 = *(const bf16x8*)&xs[16 + lo][quad * 8];
    bf16x8 a3 = *(const bf16x8*)&xs[16 + lo][32 + quad * 8];

    int n = w * 16 + lo;
    #pragma unroll
    for (int p = 0; p < 3; ++p) {
        const short* wT = wqkvT + (size_t)p * 4096 + (size_t)n * 64;
        bf16x8 b0 = *(const bf16x8*)(wT + quad * 8);
        bf16x8 b1 = *(const bf16x8*)(wT + 32 + quad * 8);
        f32x4 c0 = __builtin_amdgcn_mfma_f32_16x16x32_bf16(a0, b0, (f32x4){0,0,0,0}, 0, 0, 0);
        c0 = __builtin_amdgcn_mfma_f32_16x16x32_bf16(a1, b1, c0, 0, 0, 0);
        f32x4 c1 = __builtin_amdgcn_mfma_f32_16x16x32_bf16(a2, b0, (f32x4){0,0,0,0}, 0, 0, 0);
        c1 = __builtin_amdgcn_mfma_f32_16x16x32_bf16(a3, b1, c1, 0, 0, 0);
        float bias = (p == 0) ? bq[n] * QSCL : (p == 1) ? bk[n] : bv[n];
        #pragma unroll
        for (int r = 0; r < 4; ++r) {
            int tok = tok0 + quad * 4 + r;
            int bb0 = tok / S1C, ss0 = tok % S1C;
            int bh = bb0 * NHD + w;
            short val = f2b(c0[r] + bias);
            int tok2 = tok + 16;
            int bb1 = tok2 / S1C, ss1 = tok2 % S1C;
            int bh2 = bb1 * NHD + w;
            short val2 = f2b(c1[r] + bias);
            if (p == 0) {
                qb[((size_t)bh * SPAD + ss0) * 16 + lo] = val;
                qb[((size_t)bh2 * SPAD + ss1) * 16 + lo] = val2;
            } else if (p == 1) {
                kb[((size_t)bh * SPAD + ss0) * 16 + lo] = val;
                kb[((size_t)bh2 * SPAD + ss1) * 16 + lo] = val2;
            } else {
                vbt[((size_t)bh * 16 + lo) * SPAD + ss0] = val;
                vbt[((size_t)bh2 * 16 + lo) * SPAD + ss1] = val2;
            }
        }
    }
}

// ---------------------------------------------------------------------------
// Kernel 3: flash MFMA attention, r25 SPLIT-K: 4 waves/block. Wave pair
// {half 0: chunks 0..15, half 1: chunks 16..32} computes partial
// (sum exp*V, sum exp) for the SAME tile-slot; since softmax uses raw
// exp(S) (no running max), partials are exactly additive. Partials are
// exchanged via the reused P-LDS region after one __syncthreads; the even
// wave writes the combined output. Serial chain per wave halves (33 -> 16/17
// STEPs) and waves/CU rises 22 -> ~32 for more latency hiding.
// K-rotation phase corrected (consume K(ch), not K(ch-1)).
// ---------------------------------------------------------------------------
__global__ __launch_bounds__(256) void k_attn(
    const short* __restrict__ qb, const short* __restrict__ kb,
    const short* __restrict__ vbt, short* __restrict__ ob)
{
    int bid = blockIdx.x;
    int bh  = bid % NBH;           // 11 blocks of a bh share bid%8 (XCD/L2)
    int grp = bid / NBH;           // 0..10
    int b = bh >> 2, h = bh & 3;
    int t = threadIdx.x;
    int w = t >> 6, l = t & 63;
    int slot = w >> 1, half = w & 1;
    int quad = l >> 4, lo = l & 15;
    int t0 = grp * 2 + slot;       // 0..21 (exact cover)
    int t1 = t0 + 22;              // 22..43
    int t2 = t0 + 44;              // 44..65
    int qg0 = t0 * 16, qg1 = t1 * 16, qg2 = t2 * 16;

    // Per-wave region: P tiles (single buffer, 3264 B) reused afterwards for
    // fp32 partials (64 lanes x 17 floats = 4352 B). 544 u32x2 = 4352 B/wave.
    __shared__ u32x2 ptmem[4][544];
    char* ptc = (char*)&ptmem[w][0];
    unsigned ptbase = (unsigned)(uintptr_t)ptc;

    const short* qbase = qb + (size_t)bh * SPAD * 16;
    const short* kbase = kb + (size_t)bh * SPAD * 16;
    const short* vbase = vbt + (size_t)bh * 16 * SPAD;

    bf16x8 aQ0 = {0,0,0,0,0,0,0,0}, aQ1 = {0,0,0,0,0,0,0,0}, aQ2 = {0,0,0,0,0,0,0,0};
    if (quad < 2) {
        aQ0 = *(const bf16x8*)(qbase + ((size_t)(qg0 + lo)) * 16 + quad * 8);
        aQ1 = *(const bf16x8*)(qbase + ((size_t)(qg1 + lo)) * 16 + quad * 8);
        aQ2 = *(const bf16x8*)(qbase + ((size_t)(qg2 + lo)) * 16 + quad * 8);
    }

    const short ONE = 0x3F80;
    bf16x8 aOne = {ONE, ONE, ONE, ONE, ONE, ONE, ONE, ONE};

    f32x4 oc0 = {0.f,0.f,0.f,0.f}, oc1 = {0.f,0.f,0.f,0.f}, oc2 = {0.f,0.f,0.f,0.f};
    f32x4 dn0 = {0.f,0.f,0.f,0.f}, dn1 = {0.f,0.f,0.f,0.f}, dn2 = {0.f,0.f,0.f,0.f};

    unsigned wo0 = (unsigned)((lo >> 2) * 136 + (lo & 3) * 32 + quad * 8);
    unsigned ro = (unsigned)(quad * 272 + lo * 8);
    unsigned rdp = ptbase + ro;            // P read addr
    char* wbp = ptc + wo0;                 // P write base (lane-resolved)

    bf16x8 kxA, kyA, kxB, kyB, vA, vB;
    int c0 = half << 4;                    // 0 or 16 (first chunk of this half)

    // ---- prologue: load K(c0) -> A (consumed here), V(c0) -> vA,
    //      K(c0+1) -> B; produce P(c0) ----
    {
        const short* k0p = kbase + (size_t)(c0 * 32 + lo) * 16 + (quad & 1) * 8;
        kxA = *(const bf16x8*)k0p;
        kyA = *(const bf16x8*)(k0p + 256);
        vA  = *(const bf16x8*)(vbase + (size_t)lo * SPAD + c0 * 32 + quad * 8);
        const short* k1p = kbase + (size_t)((c0 + 1) * 32 + lo) * 16 + (quad & 1) * 8;
        kxB = *(const bf16x8*)k1p;
        kyB = *(const bf16x8*)(k1p + 256);

        f32x4 c0_ = __builtin_amdgcn_mfma_f32_16x16x32_bf16(aQ0, kxA, (f32x4){0.f,0.f,0.f,0.f}, 0, 0, 0);
        f32x4 c1_ = __builtin_amdgcn_mfma_f32_16x16x32_bf16(aQ1, kxA, (f32x4){0.f,0.f,0.f,0.f}, 0, 0, 0);
        f32x4 c2_ = __builtin_amdgcn_mfma_f32_16x16x32_bf16(aQ2, kxA, (f32x4){0.f,0.f,0.f,0.f}, 0, 0, 0);
        *(u32x2*)(wbp)        = pack4exp(c0_, true);
        *(u32x2*)(wbp + 1088) = pack4exp(c1_, true);
        *(u32x2*)(wbp + 2176) = pack4exp(c2_, true);
        c0_ = __builtin_amdgcn_mfma_f32_16x16x32_bf16(aQ0, kyA, (f32x4){0.f,0.f,0.f,0.f}, 0, 0, 0);
        c1_ = __builtin_amdgcn_mfma_f32_16x16x32_bf16(aQ1, kyA, (f32x4){0.f,0.f,0.f,0.f}, 0, 0, 0);
        c2_ = __builtin_amdgcn_mfma_f32_16x16x32_bf16(aQ2, kyA, (f32x4){0.f,0.f,0.f,0.f}, 0, 0, 0);
        *(u32x2*)(wbp + 544)  = pack4exp(c0_, true);
        *(u32x2*)(wbp + 1632) = pack4exp(c1_, true);
        *(u32x2*)(wbp + 2720) = pack4exp(c2_, true);
    }

// Pipelined step: produce P(CH) from KXC (holds K(CH)), prefetch K(CH+1)
// into KXN, consume P(CH-1) with VP=V(CH-1), load VC=V(CH). Single P buffer:
// tr-reads (issued first, drained before writes) rely on in-order DS.
#define STEP(CH, TAIL, KXC, KYC, KXN, KYN, VP, VC) do {                       \
    int ch_ = (CH);                                                            \
    if (!(TAIL)) {                                                             \
        const short* kn_ = kbase + (size_t)((ch_ + 1) * 32 + lo) * 16 + (quad & 1) * 8; \
        KXN = *(const bf16x8*)kn_;                                             \
        KYN = *(const bf16x8*)(kn_ + 256);                                     \
    }                                                                          \
    VC = *(const bf16x8*)(vbase + (size_t)lo * SPAD + ch_ * 32 + quad * 8);    \
    u32x2 p00_, p01_, p10_, p11_, p20_, p21_;                                  \
    asm volatile("ds_read_b64_tr_b16 %0, %1"             : "=v"(p00_) : "v"(rdp) : "memory"); \
    asm volatile("ds_read_b64_tr_b16 %0, %1 offset:136"  : "=v"(p01_) : "v"(rdp) : "memory"); \
    asm volatile("ds_read_b64_tr_b16 %0, %1 offset:1088" : "=v"(p10_) : "v"(rdp) : "memory"); \
    asm volatile("ds_read_b64_tr_b16 %0, %1 offset:1224" : "=v"(p11_) : "v"(rdp) : "memory"); \
    asm volatile("ds_read_b64_tr_b16 %0, %1 offset:2176" : "=v"(p20_) : "v"(rdp) : "memory"); \
    asm volatile("ds_read_b64_tr_b16 %0, %1 offset:2312" : "=v"(p21_) : "v"(rdp) : "memory"); \
    u32x2 wt0x_, wt1x_, wt2x_, wt0y_, wt1y_, wt2y_;                            \
    {                                                                          \
        f32x4 c0_ = __builtin_amdgcn_mfma_f32_16x16x32_bf16(aQ0, KXC, (f32x4){0.f,0.f,0.f,0.f}, 0, 0, 0); \
        f32x4 c1_ = __builtin_amdgcn_mfma_f32_16x16x32_bf16(aQ1, KXC, (f32x4){0.f,0.f,0.f,0.f}, 0, 0, 0); \
        f32x4 c2_ = __builtin_amdgcn_mfma_f32_16x16x32_bf16(aQ2, KXC, (f32x4){0.f,0.f,0.f,0.f}, 0, 0, 0); \
        bool v0_ = !(TAIL) || (lo == 0);                                       \
        wt0x_ = pack4exp(c0_, v0_);                                            \
        wt1x_ = pack4exp(c1_, v0_);                                            \
        wt2x_ = pack4exp(c2_, v0_);                                            \
        c0_ = __builtin_amdgcn_mfma_f32_16x16x32_bf16(aQ0, KYC, (f32x4){0.f,0.f,0.f,0.f}, 0, 0, 0); \
        c1_ = __builtin_amdgcn_mfma_f32_16x16x32_bf16(aQ1, KYC, (f32x4){0.f,0.f,0.f,0.f}, 0, 0, 0); \
        c2_ = __builtin_amdgcn_mfma_f32_16x16x32_bf16(aQ2, KYC, (f32x4){0.f,0.f,0.f,0.f}, 0, 0, 0); \
        bool v1_ = !(TAIL);                                                    \
        wt0y_ = pack4exp(c0_, v1_);                                            \
        wt1y_ = pack4exp(c1_, v1_);                                            \
        wt2y_ = pack4exp(c2_, v1_);                                            \
    }                                                                          \
    asm volatile("s_waitcnt lgkmcnt(0)" ::: "memory");                         \
    __builtin_amdgcn_sched_barrier(0);                                         \
    u32x4 q0_; q0_[0] = p00_[0]; q0_[1] = p00_[1]; q0_[2] = p01_[0]; q0_[3] = p01_[1]; \
    u32x4 q1_; q1_[0] = p10_[0]; q1_[1] = p10_[1]; q1_[2] = p11_[0]; q1_[3] = p11_[1]; \
    u32x4 q2_; q2_[0] = p20_[0]; q2_[1] = p20_[1]; q2_[2] = p21_[0]; q2_[3] = p21_[1]; \
    bf16x8 pB0_ = __builtin_bit_cast(bf16x8, q0_);                             \
    bf16x8 pB1_ = __builtin_bit_cast(bf16x8, q1_);                             \
    bf16x8 pB2_ = __builtin_bit_cast(bf16x8, q2_);                             \
    oc0 = __builtin_amdgcn_mfma_f32_16x16x32_bf16(VP, pB0_, oc0, 0, 0, 0);     \
    dn0 = __builtin_amdgcn_mfma_f32_16x16x32_bf16(aOne, pB0_, dn0, 0, 0, 0);   \
    oc1 = __builtin_amdgcn_mfma_f32_16x16x32_bf16(VP, pB1_, oc1, 0, 0, 0);     \
    dn1 = __builtin_amdgcn_mfma_f32_16x16x32_bf16(aOne, pB1_, dn1, 0, 0, 0);   \
    oc2 = __builtin_amdgcn_mfma_f32_16x16x32_bf16(VP, pB2_, oc2, 0, 0, 0);     \
    dn2 = __builtin_amdgcn_mfma_f32_16x16x32_bf16(aOne, pB2_, dn2, 0, 0, 0);   \
    *(u32x2*)(wbp)        = wt0x_;                                             \
    *(u32x2*)(wbp + 544)  = wt0y_;                                             \
    *(u32x2*)(wbp + 1088) = wt1x_;                                             \
    *(u32x2*)(wbp + 1632) = wt1y_;                                             \
    *(u32x2*)(wbp + 2176) = wt2x_;                                             \
    *(u32x2*)(wbp + 2720) = wt2y_;                                             \
} while (0)

#define EPILOGUE(VLAST) do {                                                   \
    u32x2 p00, p01, p10, p11, p20, p21;                                        \
    asm volatile("ds_read_b64_tr_b16 %0, %1"             : "=v"(p00) : "v"(rdp) : "memory"); \
    asm volatile("ds_read_b64_tr_b16 %0, %1 offset:136"  : "=v"(p01) : "v"(rdp) : "memory"); \
    asm volatile("ds_read_b64_tr_b16 %0, %1 offset:1088" : "=v"(p10) : "v"(rdp) : "memory"); \
    asm volatile("ds_read_b64_tr_b16 %0, %1 offset:1224" : "=v"(p11) : "v"(rdp) : "memory"); \
    asm volatile("ds_read_b64_tr_b16 %0, %1 offset:2176" : "=v"(p20) : "v"(rdp) : "memory"); \
    asm volatile("ds_read_b64_tr_b16 %0, %1 offset:2312" : "=v"(p21) : "v"(rdp) : "memory"); \
    asm volatile("s_waitcnt lgkmcnt(0)" ::: "memory");                         \
    __builtin_amdgcn_sched_barrier(0);                                         \
    u32x4 q0; q0[0] = p00[0]; q0[1] = p00[1]; q0[2] = p01[0]; q0[3] = p01[1];  \
    u32x4 q1; q1[0] = p10[0]; q1[1] = p10[1]; q1[2] = p11[0]; q1[3] = p11[1];  \
    u32x4 q2; q2[0] = p20[0]; q2[1] = p20[1]; q2[2] = p21[0]; q2[3] = p21[1];  \
    bf16x8 pB0 = __builtin_bit_cast(bf16x8, q0);                               \
    bf16x8 pB1 = __builtin_bit_cast(bf16x8, q1);                               \
    bf16x8 pB2 = __builtin_bit_cast(bf16x8, q2);                               \
    oc0 = __builtin_amdgcn_mfma_f32_16x16x32_bf16(VLAST, pB0, oc0, 0, 0, 0);   \
    dn0 = __builtin_amdgcn_mfma_f32_16x16x32_bf16(aOne, pB0, dn0, 0, 0, 0);    \
    oc1 = __builtin_amdgcn_mfma_f32_16x16x32_bf16(VLAST, pB1, oc1, 0, 0, 0);   \
    dn1 = __builtin_amdgcn_mfma_f32_16x16x32_bf16(aOne, pB1, dn1, 0, 0, 0);    \
    oc2 = __builtin_amdgcn_mfma_f32_16x16x32_bf16(VLAST, pB2, oc2, 0, 0, 0);   \
    dn2 = __builtin_amdgcn_mfma_f32_16x16x32_bf16(aOne, pB2, dn2, 0, 0, 0);    \
} while (0)

    if (half == 0) {
        // chunks 1..15 (15 STEPs), then epilogue consumes P(15) with V(15)=vB
        for (int ch = 1; ch < 15; ch += 2) {
            STEP(ch,     0, kxB, kyB, kxA, kyA, vA, vB);
            STEP(ch + 1, 0, kxA, kyA, kxB, kyB, vB, vA);
        }
        STEP(15, 0, kxB, kyB, kxA, kyA, vA, vB);
        EPILOGUE(vB);
    } else {
        // chunks 17..32 (16 STEPs, TAIL at 32), epilogue consumes P(32) w/ vA
        for (int ch = 17; ch < 31; ch += 2) {
            STEP(ch,     0, kxB, kyB, kxA, kyA, vA, vB);
            STEP(ch + 1, 0, kxA, kyA, kxB, kyB, vB, vA);
        }
        STEP(31, 0, kxB, kyB, kxA, kyA, vA, vB);
        STEP(32, 1, kxA, kyA, kxB, kyB, vB, vA);
        EPILOGUE(vA);
    }
#undef STEP
#undef EPILOGUE

    // ---- store fp32 partials into this wave's LDS region (reuses P space;
    //      epilogue drained all tr-reads, in-order DS makes this safe) ----
    {
        float* pb = (float*)ptc;
        int base = l * 17;   // stride 17 floats: conflict-free (odd stride)
        pb[base + 0] = oc0[0]; pb[base + 1] = oc0[1];
        pb[base + 2] = oc0[2]; pb[base + 3] = oc0[3]; pb[base + 4] = dn0[0];
        pb[base + 5] = oc1[0]; pb[base + 6] = oc1[1];
        pb[base + 7] = oc1[2]; pb[base + 8] = oc1[3]; pb[base + 9] = dn1[0];
        pb[base +10] = oc2[0]; pb[base +11] = oc2[1];
        pb[base +12] = oc2[2]; pb[base +13] = oc2[3]; pb[base +14] = dn2[0];
    }
    __syncthreads();

    // ---- even wave of each pair combines with partner and writes out ----
    if (half == 0) {
        const float* pp = (const float*)&ptmem[w ^ 1][0];
        int base = l * 17;
        {
            int qrow = qg0 + lo;
            if (qrow < S1C) {
                float inv = 1.0f / (dn0[0] + pp[base + 4]);
                float s0 = oc0[0] + pp[base + 0], s1 = oc0[1] + pp[base + 1];
                float s2 = oc0[2] + pp[base + 2], s3 = oc0[3] + pp[base + 3];
                unsigned p0 = (unsigned short)f2b(s0 * inv) | ((unsigned)(unsigned short)f2b(s1 * inv) << 16);
                unsigned p1 = (unsigned short)f2b(s2 * inv) | ((unsigned)(unsigned short)f2b(s3 * inv) << 16);
                *(uint2*)(ob + ((size_t)b * S1C + qrow) * DD + h * DHD + quad * 4) = make_uint2(p0, p1);
            }
        }
        {
            int qrow = qg1 + lo;
            if (qrow < S1C) {
                float inv = 1.0f / (dn1[0] + pp[base + 9]);
                float s0 = oc1[0] + pp[base + 5], s1 = oc1[1] + pp[base + 6];
                float s2 = oc1[2] + pp[base + 7], s3 = oc1[3] + pp[base + 8];
                unsigned p0 = (unsigned short)f2b(s0 * inv) | ((unsigned)(unsigned short)f2b(s1 * inv) << 16);
                unsigned p1 = (unsigned short)f2b(s2 * inv) | ((unsigned)(unsigned short)f2b(s3 * inv) << 16);
                *(uint2*)(ob + ((size_t)b * S1C + qrow) * DD + h * DHD + quad * 4) = make_uint2(p0, p1);
            }
        }
        {
            int qrow = qg2 + lo;
            if (qrow < S1C) {
                float inv = 1.0f / (dn2[0] + pp[base + 14]);
                float s0 = oc2[0] + pp[base + 10], s1 = oc2[1] + pp[base + 11];
                float s2 = oc2[2] + pp[base + 12], s3 = oc2[3] + pp[base + 13];
                unsigned p0 = (unsigned short)f2b(s0 * inv) | ((unsigned)(unsigned short)f2b(s1 * inv) << 16);
                unsigned p1 = (unsigned short)f2b(s2 * inv) | ((unsigned)(unsigned short)f2b(s3 * inv) << 16);
                *(uint2*)(ob + ((size_t)b * S1C + qrow) * DD + h * DHD + quad * 4) = make_uint2(p0, p1);
            }
        }
    }
}

// ---------------------------------------------------------------------------
// Kernel 4: fused transformer tail (r19 measured-best version).
// ---------------------------------------------------------------------------
__global__ __launch_bounds__(256) void k_block(
    const short* __restrict__ ob, float* __restrict__ x,
    const short* __restrict__ woT, fp bo, fp ln1s, fp ln1b,
    const short* __restrict__ w1T, fp b1, const short* __restrict__ w2T, fp b2,
    fp ln2s, fp ln2b,
    const short* __restrict__ wqkvTn, fp bqn, fp bkn, fp bvn,
    short* __restrict__ qb, short* __restrict__ kb, short* __restrict__ vbt,
    int has_next)
{
    int blk = blockIdx.x, t = threadIdx.x;
    int tok0 = blk * FT2;
    int w = t >> 6, l = t & 63;
    int quad = l >> 4, lo = l & 15;

    __shared__ float otf[FT2][OPAD];          // 8704 B; ys overlays (136-short rows)
    __shared__ u32x2 hidtr[2][8][136];        // 17408 B: [tile][kchunk][subtiles]
    short* ysb = (short*)&otf[0][0];
    char*  hidc = (char*)&hidtr[0][0][0];
    unsigned hidbase = (unsigned)(uintptr_t)hidc;

    // ---- LN lane mapping + entry prefetch (hidden under oproj) ----
    int tt8 = t >> 3;            // token 0..31
    int d8s = (t & 7) * 8;       // dim base
    const float* xrow = x + (size_t)(tok0 + tt8) * DD + d8s;
    float4 xpa = *(const float4*)xrow;
    float4 xpb = *(const float4*)(xrow + 4);
    float4 s1a = *(const float4*)(ln1s + d8s);
    float4 s1b = *(const float4*)(ln1s + d8s + 4);
    float4 b1a = *(const float4*)(ln1b + d8s);
    float4 b1b = *(const float4*)(ln1b + d8s + 4);

    // ---- oproj (both token-tiles, weights loaded once) ----
    {
        const short* obp0 = ob + ((size_t)(tok0 + lo)) * DD;
        const short* obp1 = ob + ((size_t)(tok0 + 16 + lo)) * DD;
        bf16x8 a0 = *(const bf16x8*)(obp0 + quad * 8);
        bf16x8 a1 = *(const bf16x8*)(obp0 + 32 + quad * 8);
        bf16x8 a2 = *(const bf16x8*)(obp1 + quad * 8);
        bf16x8 a3 = *(const bf16x8*)(obp1 + 32 + quad * 8);
        int n = w * 16 + lo;
        const short* wT = woT + (size_t)n * 64;
        bf16x8 b0 = *(const bf16x8*)(wT + quad * 8);
        bf16x8 bb = *(const bf16x8*)(wT + 32 + quad * 8);
        f32x4 c0 = __builtin_amdgcn_mfma_f32_16x16x32_bf16(a0, b0, (f32x4){0,0,0,0}, 0, 0, 0);
        c0 = __builtin_amdgcn_mfma_f32_16x16x32_bf16(a1, bb, c0, 0, 0, 0);
        f32x4 c1 = __builtin_amdgcn_mfma_f32_16x16x32_bf16(a2, b0, (f32x4){0,0,0,0}, 0, 0, 0);
        c1 = __builtin_amdgcn_mfma_f32_16x16x32_bf16(a3, bb, c1, 0, 0, 0);
        float bov = bo[n];
        #pragma unroll
        for (int r = 0; r < 4; ++r) {
            otf[quad * 4 + r][n] = c0[r] + bov;
            otf[16 + quad * 4 + r][n] = c1[r] + bov;
        }
    }
    __syncthreads();

    // ---- LN1 (8 lanes per token) ----
    float yv[8];
    {
        float4 o0 = *(const float4*)&otf[tt8][d8s];
        float4 o1 = *(const float4*)&otf[tt8][d8s + 4];
        float v0 = o0.x + xpa.x, v1 = o0.y + xpa.y, v2 = o0.z + xpa.z, v3 = o0.w + xpa.w;
        float v4 = o1.x + xpb.x, v5 = o1.y + xpb.y, v6 = o1.z + xpb.z, v7 = o1.w + xpb.w;
        float sum = ((v0 + v1) + (v2 + v3)) + ((v4 + v5) + (v6 + v7));
        float vs = v0 * v0;
        vs = fmaf(v1, v1, vs); vs = fmaf(v2, v2, vs); vs = fmaf(v3, v3, vs);
        vs = fmaf(v4, v4, vs); vs = fmaf(v5, v5, vs); vs = fmaf(v6, v6, vs);
        vs = fmaf(v7, v7, vs);
        sum += __shfl_xor(sum, 1, 64); sum += __shfl_xor(sum, 2, 64); sum += __shfl_xor(sum, 4, 64);
        vs  += __shfl_xor(vs , 1, 64); vs  += __shfl_xor(vs , 2, 64); vs  += __shfl_xor(vs , 4, 64);
        float mean = sum * (1.0f / 64.0f);
        float var = vs * (1.0f / 64.0f) - mean * mean;
        float rs = rsqrtf(var + 1e-5f);
        yv[0] = (v0 - mean) * rs * s1a.x + b1a.x;
        yv[1] = (v1 - mean) * rs * s1a.y + b1a.y;
        yv[2] = (v2 - mean) * rs * s1a.z + b1a.z;
        yv[3] = (v3 - mean) * rs * s1a.w + b1a.w;
        yv[4] = (v4 - mean) * rs * s1b.x + b1b.x;
        yv[5] = (v5 - mean) * rs * s1b.y + b1b.y;
        yv[6] = (v6 - mean) * rs * s1b.z + b1b.z;
        yv[7] = (v7 - mean) * rs * s1b.w + b1b.w;
        u32x2 pa = pack4cvt(yv[0], yv[1], yv[2], yv[3]);
        u32x2 pb = pack4cvt(yv[4], yv[5], yv[6], yv[7]);
        *(u32x4*)&ysb[tt8 * 136 + d8s] = (u32x4){pa[0], pa[1], pb[0], pb[1]};
    }
    __syncthreads();

    // ---- FFN1: hid = gelu(y @ w1 + b1), tr-layout packed b64 writes ----
    {
        bf16x8 a0 = *(const bf16x8*)&ysb[(size_t)lo * 136 + quad * 8];
        bf16x8 a1 = *(const bf16x8*)&ysb[(size_t)lo * 136 + 32 + quad * 8];
        bf16x8 a2 = *(const bf16x8*)&ysb[(size_t)(16 + lo) * 136 + quad * 8];
        bf16x8 a3 = *(const bf16x8*)&ysb[(size_t)(16 + lo) * 136 + 32 + quad * 8];
        unsigned hoff = (unsigned)(w * 2176 + (lo >> 2) * 136 + (lo & 3) * 32 + quad * 8);
        #pragma unroll
        for (int i = 0; i < 4; ++i) {
            int n = w * 64 + i * 16 + lo;
            const short* wT = w1T + (size_t)n * 64;
            bf16x8 b0 = *(const bf16x8*)(wT + quad * 8);
            bf16x8 bb = *(const bf16x8*)(wT + 32 + quad * 8);
            f32x4 c0 = __builtin_amdgcn_mfma_f32_16x16x32_bf16(a0, b0, (f32x4){0,0,0,0}, 0, 0, 0);
            c0 = __builtin_amdgcn_mfma_f32_16x16x32_bf16(a1, bb, c0, 0, 0, 0);
            f32x4 c1 = __builtin_amdgcn_mfma_f32_16x16x32_bf16(a2, b0, (f32x4){0,0,0,0}, 0, 0, 0);
            c1 = __builtin_amdgcn_mfma_f32_16x16x32_bf16(a3, bb, c1, 0, 0, 0);
            float b1v = b1[n];
            unsigned off = hoff + (i >> 1) * 1088 + (i & 1) * 544;
            *(u32x2*)(hidc + off) = pack4cvt(
                gelu_fast(c0[0] + b1v), gelu_fast(c0[1] + b1v),
                gelu_fast(c0[2] + b1v), gelu_fast(c0[3] + b1v));
            *(u32x2*)(hidc + 8704 + off) = pack4cvt(
                gelu_fast(c1[0] + b1v), gelu_fast(c1[1] + b1v),
                gelu_fast(c1[2] + b1v), gelu_fast(c1[3] + b1v));
        }
    }
    __syncthreads();

    // ---- FFN2: out = hid @ w2 + b2 (K=256), tr-read A-frags, depth-2 pipe ----
    {
        f32x4 c20 = {0.f,0.f,0.f,0.f}, c21 = {0.f,0.f,0.f,0.f};
        const short* wT2 = w2T + (size_t)(w * 16 + lo) * 256;
        unsigned ro = (unsigned)(quad * 272 + lo * 8);
        unsigned tb0 = hidbase + ro;
        unsigned tb1 = hidbase + 8704 + ro;
        u32x2 pA0, pA1, pA2, pA3, pB0, pB1, pB2, pB3;

#define TRRD(dst, addr, OFFSTR) \
    asm volatile("ds_read_b64_tr_b16 %0, %1 offset:" OFFSTR : "=v"(dst) : "v"(addr))
#define ISS(P0,P1,P2,P3, O1, O2) \
    TRRD(P0, tb0, O1); TRRD(P1, tb0, O2); TRRD(P2, tb1, O1); TRRD(P3, tb1, O2)
#define W4 asm volatile("s_waitcnt lgkmcnt(4)" ::: "memory"); __builtin_amdgcn_sched_barrier(0)
#define W0 asm volatile("s_waitcnt lgkmcnt(0)" ::: "memory"); __builtin_amdgcn_sched_barrier(0)
#define CONS(P0,P1,P2,P3, BF) do { \
    u32x4 q0_; q0_[0]=P0[0]; q0_[1]=P0[1]; q0_[2]=P1[0]; q0_[3]=P1[1]; \
    u32x4 q1_; q1_[0]=P2[0]; q1_[1]=P2[1]; q1_[2]=P3[0]; q1_[3]=P3[1]; \
    c20 = __builtin_amdgcn_mfma_f32_16x16x32_bf16(__builtin_bit_cast(bf16x8,q0_), BF, c20, 0,0,0); \
    c21 = __builtin_amdgcn_mfma_f32_16x16x32_bf16(__builtin_bit_cast(bf16x8,q1_), BF, c21, 0,0,0); \
} while (0)

        bf16x8 bfA = *(const bf16x8*)(wT2 + quad * 8);
        ISS(pA0,pA1,pA2,pA3, "0",    "136");
        bf16x8 bfB = *(const bf16x8*)(wT2 + 32 + quad * 8);
        ISS(pB0,pB1,pB2,pB3, "1088", "1224");
        W4; CONS(pA0,pA1,pA2,pA3, bfA);
        bfA = *(const bf16x8*)(wT2 + 64 + quad * 8);
        ISS(pA0,pA1,pA2,pA3, "2176", "2312");
        W4; CONS(pB0,pB1,pB2,pB3, bfB);
        bfB = *(const bf16x8*)(wT2 + 96 + quad * 8);
        ISS(pB0,pB1,pB2,pB3, "3264", "3400");
        W4; CONS(pA0,pA1,pA2,pA3, bfA);
        bfA = *(const bf16x8*)(wT2 + 128 + quad * 8);
        ISS(pA0,pA1,pA2,pA3, "4352", "4488");
        W4; CONS(pB0,pB1,pB2,pB3, bfB);
        bfB = *(const bf16x8*)(wT2 + 160 + quad * 8);
        ISS(pB0,pB1,pB2,pB3, "5440", "5576");
        W4; CONS(pA0,pA1,pA2,pA3, bfA);
        bfA = *(const bf16x8*)(wT2 + 192 + quad * 8);
        ISS(pA0,pA1,pA2,pA3, "6528", "6664");
        W4; CONS(pB0,pB1,pB2,pB3, bfB);
        bfB = *(const bf16x8*)(wT2 + 224 + quad * 8);
        ISS(pB0,pB1,pB2,pB3, "7616", "7752");
        W4; CONS(pA0,pA1,pA2,pA3, bfA);
        W0; CONS(pB0,pB1,pB2,pB3, bfB);
#undef TRRD
#undef ISS
#undef W4
#undef W0
#undef CONS

        float b2v = b2[w * 16 + lo];
        #pragma unroll
        for (int r = 0; r < 4; ++r) {
            otf[quad * 4 + r][w * 16 + lo] = c20[r] + b2v;
            otf[16 + quad * 4 + r][w * 16 + lo] = c21[r] + b2v;
        }
    }
    __syncthreads();

    // ---- LN2 (8 lanes per token); residual = yv (registers) ----
    {
        float4 s2a = *(const float4*)(ln2s + d8s);
        float4 s2b = *(const float4*)(ln2s + d8s + 4);
        float4 b2a = *(const float4*)(ln2b + d8s);
        float4 b2b = *(const float4*)(ln2b + d8s + 4);
        float4 o0 = *(const float4*)&otf[tt8][d8s];
        float4 o1 = *(const float4*)&otf[tt8][d8s + 4];
        float v0 = o0.x + yv[0], v1 = o0.y + yv[1], v2 = o0.z + yv[2], v3 = o0.w + yv[3];
        float v4 = o1.x + yv[4], v5 = o1.y + yv[5], v6 = o1.z + yv[6], v7 = o1.w + yv[7];
        float sum = ((v0 + v1) + (v2 + v3)) + ((v4 + v5) + (v6 + v7));
        float vs = v0 * v0;
        vs = fmaf(v1, v1, vs); vs = fmaf(v2, v2, vs); vs = fmaf(v3, v3, vs);
        vs = fmaf(v4, v4, vs); vs = fmaf(v5, v5, vs); vs = fmaf(v6, v6, vs);
        vs = fmaf(v7, v7, vs);
        sum += __shfl_xor(sum, 1, 64); sum += __shfl_xor(sum, 2, 64); sum += __shfl_xor(sum, 4, 64);
        vs  += __shfl_xor(vs , 1, 64); vs  += __shfl_xor(vs , 2, 64); vs  += __shfl_xor(vs , 4, 64);
        float mean = sum * (1.0f / 64.0f);
        float var = vs * (1.0f / 64.0f) - mean * mean;
        float rs = rsqrtf(var + 1e-5f);
        float y0 = (v0 - mean) * rs * s2a.x + b2a.x;
        float y1 = (v1 - mean) * rs * s2a.y + b2a.y;
        float y2 = (v2 - mean) * rs * s2a.z + b2a.z;
        float y3 = (v3 - mean) * rs * s2a.w + b2a.w;
        float y4 = (v4 - mean) * rs * s2b.x + b2b.x;
        float y5 = (v5 - mean) * rs * s2b.y + b2b.y;
        float y6 = (v6 - mean) * rs * s2b.z + b2b.z;
        float y7 = (v7 - mean) * rs * s2b.w + b2b.w;
        float* xo = x + (size_t)(tok0 + tt8) * DD + d8s;
        *(float4*)xo = make_float4(y0, y1, y2, y3);
        *(float4*)(xo + 4) = make_float4(y4, y5, y6, y7);
        u32x2 pa = pack4cvt(y0, y1, y2, y3);
        u32x2 pb = pack4cvt(y4, y5, y6, y7);
        *(u32x4*)&ysb[tt8 * 136 + d8s] = (u32x4){pa[0], pa[1], pb[0], pb[1]};
    }
    __syncthreads();

    // ---- next-layer QKV, both tiles ----
    if (has_next) {
        bf16x8 a0 = *(const bf16x8*)&ysb[(size_t)lo * 136 + quad * 8];
        bf16x8 a1 = *(const bf16x8*)&ysb[(size_t)lo * 136 + 32 + quad * 8];
        bf16x8 a2 = *(const bf16x8*)&ysb[(size_t)(16 + lo) * 136 + quad * 8];
        bf16x8 a3 = *(const bf16x8*)&ysb[(size_t)(16 + lo) * 136 + 32 + quad * 8];
        int n = w * 16 + lo;
        #pragma unroll
        for (int p = 0; p < 3; ++p) {
            const short* wT = wqkvTn + (size_t)p * 4096 + (size_t)n * 64;
            bf16x8 b0 = *(const bf16x8*)(wT + quad * 8);
            bf16x8 bb = *(const bf16x8*)(wT + 32 + quad * 8);
            f32x4 c0 = __builtin_amdgcn_mfma_f32_16x16x32_bf16(a0, b0, (f32x4){0,0,0,0}, 0, 0, 0);
            c0 = __builtin_amdgcn_mfma_f32_16x16x32_bf16(a1, bb, c0, 0, 0, 0);
            f32x4 c1 = __builtin_amdgcn_mfma_f32_16x16x32_bf16(a2, b0, (f32x4){0,0,0,0}, 0, 0, 0);
            c1 = __builtin_amdgcn_mfma_f32_16x16x32_bf16(a3, bb, c1, 0, 0, 0);
            float bias = (p == 0) ? bqn[n] * QSCL : (p == 1) ? bkn[n] : bvn[n];
            #pragma unroll
            for (int r = 0; r < 4; ++r) {
                int tok = tok0 + quad * 4 + r;
                int bb0 = tok / S1C, ss0 = tok % S1C;
                int bh = bb0 * NHD + w;
                short val = f2b(c0[r] + bias);
                int tok2 = tok + 16;
                int bb1 = tok2 / S1C, ss1 = tok2 % S1C;
                int bh2 = bb1 * NHD + w;
                short val2 = f2b(c1[r] + bias);
                if (p == 0) {
                    qb[((size_t)bh * SPAD + ss0) * 16 + lo] = val;
                    qb[((size_t)bh2 * SPAD + ss1) * 16 + lo] = val2;
                } else if (p == 1) {
                    kb[((size_t)bh * SPAD + ss0) * 16 + lo] = val;
                    kb[((size_t)bh2 * SPAD + ss1) * 16 + lo] = val2;
                } else {
                    vbt[((size_t)bh * 16 + lo) * SPAD + ss0] = val;
                    vbt[((size_t)bh2 * 16 + lo) * SPAD + ss1] = val2;
                }
            }
        }
    }
}

// ---------------------------------------------------------------------------
// Kernel 6: head MLPs. One block (64 thr) per batch element.
// ---------------------------------------------------------------------------
__global__ __launch_bounds__(64) void k_head(
    const float* __restrict__ x, fp proj_vars, fp param_vars,
    const int* __restrict__ materials,
    fp pw1, fp pb1, fp pw2, fp pb2, fp pw3, fp pb3,
    fp pw4, fp pb4, fp pw5, fp pb5,
    fp ipw1, fp ipb1, fp ipw2, fp ipb2,
    fp hw1, fp hb1, fp hw2, fp hb2, fp hw3, fp hb3,
    float* __restrict__ out)
{
    int b = blockIdx.x;
    int tid = threadIdx.x;
    __shared__ float A[80], Bf[80], pp[8], mi[32];

    if (tid < 3) A[tid] = proj_vars[b * 3 + tid];
    A[3 + tid] = x[((size_t)b * S1C + 0) * DD + tid];
    __syncthreads();

    if (tid < 34) {
        float a = pb1[tid];
        for (int i = 0; i < 67; ++i) a += A[i] * pw1[i * 34 + tid];
        Bf[tid] = gelu_exact(a);
    }
    __syncthreads();
    if (tid < 11) {
        float a = pb2[tid];
        for (int i = 0; i < 34; ++i) a += Bf[i] * pw2[i * 11 + tid];
        A[tid] = gelu_exact(a);
    }
    __syncthreads();
    if (tid < 36) {
        float a = pb3[tid];
        for (int i = 0; i < 11; ++i) a += A[i] * pw3[i * 36 + tid];
        Bf[tid] = gelu_exact(a);
    }
    __syncthreads();
    if (tid < 22) {
        float a = pb4[tid];
        for (int i = 0; i < 36; ++i) a += Bf[i] * pw4[i * 22 + tid];
        A[tid] = gelu_exact(a);
    }
    __syncthreads();
    if (tid < 24) {
        float a = pb5[tid];
        for (int i = 0; i < 22; ++i) a += A[i] * pw5[i * 24 + tid];
        mi[3 + tid] = a;
    }
    if (tid < 3) {
        float a = ipb1[tid];
        for (int i = 0; i < 3; ++i) a += param_vars[b * 3 + i] * ipw1[i * 3 + tid];
        pp[tid] = gelu_exact(a);
    }
    __syncthreads();
    if (tid < 3) {
        float a = ipb2[tid];
        for (int i = 0; i < 3; ++i) a += pp[i] * ipw2[i * 3 + tid];
        mi[tid] = a;
    }
    __syncthreads();

    int m = materials[b];
    if (tid < 15) {
        float a = hb1[m * 15 + tid];
        for (int i = 0; i < 27; ++i) a += mi[i] * hw1[(m * 27 + i) * 15 + tid];
        A[tid] = gelu_exact(a);
    }
    __syncthreads();
    if (tid < 18) {
        float a = hb2[m * 18 + tid];
        for (int i = 0; i < 15; ++i) a += A[i] * hw2[(m * 15 + i) * 18 + tid];
        Bf[tid] = gelu_exact(a);
    }
    __syncthreads();
    if (tid == 0) {
        float a = hb3[m];
        for (int i = 0; i < 18; ++i) a += Bf[i] * hw3[m * 18 + i];
        out[b] = a;
    }
}

// ---------------------------------------------------------------------------
extern "C" void kernel_launch(void* const* d_in, const int* in_sizes, int n_in,
                              void* d_out, int out_size, void* d_ws, size_t ws_size,
                              hipStream_t stream) {
    fp in_seq     = (fp)d_in[0];
    fp proj_vars  = (fp)d_in[1];
    fp param_vars = (fp)d_in[2];
    const int* materials = (const int*)d_in[3];
    fp enc_w1 = (fp)d_in[4];
    fp enc_b1 = (fp)d_in[5];
    fp enc_w2 = (fp)d_in[6];
    fp enc_b2 = (fp)d_in[7];
    fp sos    = (fp)d_in[8];
    fp tl_wq  = (fp)d_in[9];
    fp tl_wk  = (fp)d_in[10];
    fp tl_wv  = (fp)d_in[11];
    fp tl_bq  = (fp)d_in[12];
    fp tl_bk  = (fp)d_in[13];
    fp tl_bv  = (fp)d_in[14];
    fp tl_wo  = (fp)d_in[15];
    fp tl_bo  = (fp)d_in[16];
    fp tl_ln1s = (fp)d_in[17];
    fp tl_ln1b = (fp)d_in[18];
    fp tl_ln2s = (fp)d_in[19];
    fp tl_ln2b = (fp)d_in[20];
    fp tl_fw1 = (fp)d_in[21];
    fp tl_fb1 = (fp)d_in[22];
    fp tl_fw2 = (fp)d_in[23];
    fp tl_fb2 = (fp)d_in[24];
    fp pw1 = (fp)d_in[25]; fp pb1 = (fp)d_in[26];
    fp pw2 = (fp)d_in[27]; fp pb2 = (fp)d_in[28];
    fp pw3 = (fp)d_in[29]; fp pb3 = (fp)d_in[30];
    fp pw4 = (fp)d_in[31]; fp pb4 = (fp)d_in[32];
    fp pw5 = (fp)d_in[33]; fp pb5 = (fp)d_in[34];
    fp ipw1 = (fp)d_in[35]; fp ipb1 = (fp)d_in[36];
    fp ipw2 = (fp)d_in[37]; fp ipb2 = (fp)d_in[38];
    fp hw1 = (fp)d_in[39]; fp hb1 = (fp)d_in[40];
    fp hw2 = (fp)d_in[41]; fp hb2 = (fp)d_in[42];
    fp hw3 = (fp)d_in[43]; fp hb3 = (fp)d_in[44];

    // Workspace layout (xb slot retained but unused since r20 fusion)
    float* x  = (float*)d_ws;                           // NTOK*64 fp32
    short* ob = (short*)(x + (size_t)NTOK * DD);        // NTOK*64 bf16
    short* xb = ob + (size_t)NTOK * DD;                 // NTOK*64 bf16 (unused)
    short* qb = xb + (size_t)NTOK * DD;
    short* kb = qb + (size_t)NBH * SPAD * 16;
    short* vbt = kb + (size_t)NBH * SPAD * 16;
    short* wqkvT = vbt + (size_t)NBH * 16 * SPAD;       // 3 x 12288
    short* woT = wqkvT + (size_t)NLAY * 12288;          // 3 x 4096
    short* w1T = woT + (size_t)NLAY * 4096;             // 3 x 16384
    short* w2T = w1T + (size_t)NLAY * 16384;            // 3 x 16384

    k_wconv<<<dim3(192, NLAY), 256, 0, stream>>>(
        tl_wq, tl_wk, tl_wv, tl_wo, tl_fw1, tl_fw2, wqkvT, woT, w1T, w2T);
    k_zero<<<NBH, 64, 0, stream>>>(qb, kb, vbt);
    k_encqkv<<<NTOK / FTQ, 256, 0, stream>>>(
        in_seq, enc_w1, enc_b1, enc_w2, enc_b2, sos,
        wqkvT, tl_bq, tl_bk, tl_bv,
        x, qb, kb, vbt);

    for (int l = 0; l < NLAY; ++l) {
        k_attn<<<NBH * TGRP, 256, 0, stream>>>(qb, kb, vbt, ob);
        int ln = (l + 1 < NLAY) ? (l + 1) : l;   // dummy ptrs for last layer
        k_block<<<NTOK / FT2, 256, 0, stream>>>(
            ob, x,
            woT + (size_t)l * 4096, tl_bo + (size_t)l * DD,
            tl_ln1s + (size_t)l * DD, tl_ln1b + (size_t)l * DD,
            w1T + (size_t)l * 16384, tl_fb1 + (size_t)l * DFFC,
            w2T + (size_t)l * 16384, tl_fb2 + (size_t)l * DD,
            tl_ln2s + (size_t)l * DD, tl_ln2b + (size_t)l * DD,
            wqkvT + (size_t)ln * 12288,
            tl_bq + (size_t)ln * DD, tl_bk + (size_t)ln * DD, tl_bv + (size_t)ln * DD,
            qb, kb, vbt,
            (l + 1 < NLAY) ? 1 : 0);
    }

    k_head<<<BB, 64, 0, stream>>>(
        x, proj_vars, param_vars, materials,
        pw1, pb1, pw2, pb2, pw3, pb3, pw4, pb4, pw5, pb5,
        ipw1, ipb1, ipw2, ipb2,
        hw1, hb1, hw2, hb2, hw3, hb3,
        (float*)d_out);
}

// Round 13
// 462.951 us; speedup vs baseline: 1.0279x; 1.0005x over previous
//
#include <hip/hip_runtime.h>
#include <hip/hip_bf16.h>
#include <math.h>

// Problem constants
#define BB   64
#define SS   1024
#define S1C  1025
#define DD   64
#define NHD  4
#define NBH  (BB * NHD)      // 256
#define DHD  16
#define DFFC 256
#define NLAY 3
#define NTOK (BB * S1C)      // 65600 = 32 * 2050
#define SPAD 1056            // padded key/seq length (66 * 16)
#define TGRP 11              // 11 blocks/bh x 2 tile-slots = 22 slots = 66 tiles
#define FTQ   32             // tokens per block (k_encqkv) - 2 token-tiles/wave
#define FT2   32             // tokens per block (k_block) - 2 token-tiles/wave
#define OPAD 68              // ot row stride in floats (ys overlays at 136 shorts)
#define QSCL 0.36067376022224085f   // 0.25 * log2(e) folded into q

typedef const float* fp;
typedef __attribute__((ext_vector_type(8))) short bf16x8;
typedef __attribute__((ext_vector_type(4))) float f32x4;
typedef __attribute__((ext_vector_type(2))) unsigned int u32x2;
typedef __attribute__((ext_vector_type(4))) unsigned int u32x4;

#if __has_builtin(__builtin_amdgcn_exp2f)
#define RAW_EXP2(x) __builtin_amdgcn_exp2f(x)
#else
#define RAW_EXP2(x) __expf(0.6931471805599453f * (x))
#endif
#if __has_builtin(__builtin_amdgcn_rcpf)
#define RAW_RCP(x) __builtin_amdgcn_rcpf(x)
#else
#define RAW_RCP(x) (1.0f / (x))
#endif

__device__ __forceinline__ float gelu_exact(float x) {
    return 0.5f * x * (1.0f + erff(x * 0.7071067811865475f));
}
// A&S 7.1.26 erf approximation, |err| <= 1.5e-7 (<< bf16 rounding noise)
__device__ __forceinline__ float erf_fast(float x) {
    float ax = fabsf(x);
    float t = RAW_RCP(1.0f + 0.3275911f * ax);
    float p = t * (0.254829592f + t * (-0.284496736f + t * (1.421413741f +
              t * (-1.453152027f + t * 1.061405429f))));
    float e = RAW_EXP2(ax * ax * -1.4426950408889634f);
    float r = 1.0f - p * e;
    return copysignf(r, x);
}
__device__ __forceinline__ float gelu_fast(float x) {
    return 0.5f * x * (1.0f + erf_fast(x * 0.7071067811865475f));
}
// RTNE float->bf16 (finite values), 3 ops
__device__ __forceinline__ short f2b(float f) {
    unsigned u = __float_as_uint(f);
    return (short)((u + 0x7fffu + ((u >> 16) & 1u)) >> 16);
}

// pack 4 fp32 exp results -> 4 bf16 in one u32x2 via v_cvt_pk_bf16_f32
__device__ __forceinline__ u32x2 pack4exp(f32x4 c, bool valid) {
    float e0 = valid ? RAW_EXP2(c[0]) : 0.f;
    float e1 = valid ? RAW_EXP2(c[1]) : 0.f;
    float e2 = valid ? RAW_EXP2(c[2]) : 0.f;
    float e3 = valid ? RAW_EXP2(c[3]) : 0.f;
    unsigned r0, r1;
    asm("v_cvt_pk_bf16_f32 %0, %1, %2" : "=v"(r0) : "v"(e0), "v"(e1));
    asm("v_cvt_pk_bf16_f32 %0, %1, %2" : "=v"(r1) : "v"(e2), "v"(e3));
    return (u32x2){r0, r1};
}
// pack 4 fp32 -> 4 bf16 via cvt_pk (RTNE)
__device__ __forceinline__ u32x2 pack4cvt(float x0, float x1, float x2, float x3) {
    unsigned r0, r1;
    asm("v_cvt_pk_bf16_f32 %0, %1, %2" : "=v"(r0) : "v"(x0), "v"(x1));
    asm("v_cvt_pk_bf16_f32 %0, %1, %2" : "=v"(r1) : "v"(x2), "v"(x3));
    return (u32x2){r0, r1};
}

// ---------------------------------------------------------------------------
// Kernel W (r26): weight convert+transpose AND pad-zeroing fused into one
// dispatch. Grid dim3(256, NLAY): x<192 blocks do conversion (as before),
// and all y==0 blocks additionally zero the pad rows of bh = blockIdx.x.
// ---------------------------------------------------------------------------
__global__ __launch_bounds__(256) void k_wconv(
    fp wq, fp wk, fp wv, fp wo, fp w1, fp w2,
    short* __restrict__ wqkvT, short* __restrict__ woT,
    short* __restrict__ w1T, short* __restrict__ w2T,
    short* __restrict__ qb, short* __restrict__ kb, short* __restrict__ vbt)
{
    int l = blockIdx.y;
    if (blockIdx.x < 192) {
        int i = blockIdx.x * 256 + threadIdx.x;
        if (i < 12288) {
            int p = i >> 12, rem = i & 4095;
            int d = rem >> 6, j = rem & 63;
            fp src = (p == 0 ? wq : p == 1 ? wk : wv) + (size_t)l * 4096;
            float v = src[j * 64 + d];
            if (p == 0) v *= QSCL;
            wqkvT[(size_t)l * 12288 + i] = f2b(v);
        } else if (i < 16384) {
            int rem = i - 12288;
            woT[(size_t)l * 4096 + rem] = f2b(wo[(size_t)l * 4096 + (rem & 63) * 64 + (rem >> 6)]);
        } else if (i < 32768) {
            int rem = i - 16384;
            w1T[(size_t)l * 16384 + rem] = f2b(w1[(size_t)l * 16384 + (rem & 63) * 256 + (rem >> 6)]);
        } else {
            int rem = i - 32768;
            w2T[(size_t)l * 16384 + rem] = f2b(w2[(size_t)l * 16384 + (rem & 255) * 64 + (rem >> 8)]);
        }
    }
    if (l == 0) {
        int bh = blockIdx.x, t = threadIdx.x;
        for (int i = t; i < 31 * 16; i += 256) {
            int r = i >> 4, c = i & 15;
            size_t idx = ((size_t)bh * SPAD + 1025 + r) * 16 + c;
            qb[idx] = 0; kb[idx] = 0;
        }
        for (int i = t; i < 16 * 31; i += 256) {
            int e = i / 31, c = i % 31;
            vbt[((size_t)bh * 16 + e) * SPAD + 1025 + c] = 0;
        }
    }
}

// ---------------------------------------------------------------------------
// Kernel 1+2 fused (r20): encoder MLP + sos + positional encoding directly
// into an LDS tile (32 tokens), then the layer-0 MFMA Q/K/V projection from
// LDS. Removes the xb global round-trip and one dispatch.
// ---------------------------------------------------------------------------
__global__ __launch_bounds__(256) void k_encqkv(
    fp in_seq, fp enc_w1, fp enc_b1, fp enc_w2, fp enc_b2, fp sos,
    const short* __restrict__ wqkvT, fp bq, fp bk, fp bv,
    float* __restrict__ x,
    short* __restrict__ qb, short* __restrict__ kb, short* __restrict__ vbt)
{
    int t = threadIdx.x;
    int tok0 = blockIdx.x * FTQ;
    int w = t >> 6, d = t & 63;
    __shared__ float e[4][48];
    __shared__ short xs[FTQ][72];

    // ---- encode phase: 8 passes x 4 tokens (wave w -> token i*4+w) ----
    int i2 = (d >> 1) * 2;
    float factor = RAW_EXP2((float)i2 * (-9.210340371976184f / 64.0f) * 1.4426950408889634f);
    for (int i = 0; i < 8; ++i) {
        int tl = i * 4 + w;
        int tok = tok0 + tl;
        int b = tok / S1C, s = tok % S1C;
        float val;
        if (s == 0) {
            val = sos[d];
        } else {
            float tin = in_seq[b * SS + (s - 1)];
            if (d < 48) e[w][d] = gelu_fast(tin * enc_w1[d] + enc_b1[d]);
            float acc = enc_b2[d];
            for (int j = 0; j < 48; ++j) acc += e[w][j] * enc_w2[j * DD + d];
            val = acc;
        }
        float ang = (float)s * factor;
        val += (d & 1) ? __cosf(ang) : __sinf(ang);
        x[(size_t)tok * DD + d] = val;
        xs[tl][d] = f2b(val);
    }
    __syncthreads();

    // ---- QKV phase (identical to old k_qkv, A-fragments from LDS) ----
    int l = t & 63;
    int quad = l >> 4, lo = l & 15;
    bf16x8 a0 = *(const bf16x8*)&xs[lo][quad * 8];
    bf16x8 a1 = *(const bf16x8*)&xs[lo][32 + quad * 8];
    bf16x8 a2 = *(const bf16x8*)&xs[16 + lo][quad * 8];
    bf16x8 a3 = *(const bf16x8*)&xs[16 + lo][32 + quad * 8];

    int n = w * 16 + lo;
    #pragma unroll
    for (int p = 0; p < 3; ++p) {
        const short* wT = wqkvT + (size_t)p * 4096 + (size_t)n * 64;
        bf16x8 b0 = *(const bf16x8*)(wT + quad * 8);
        bf16x8 b1 = *(const bf16x8*)(wT + 32 + quad * 8);
        f32x4 c0 = __builtin_amdgcn_mfma_f32_16x16x32_bf16(a0, b0, (f32x4){0,0,0,0}, 0, 0, 0);
        c0 = __builtin_amdgcn_mfma_f32_16x16x32_bf16(a1, b1, c0, 0, 0, 0);
        f32x4 c1 = __builtin_amdgcn_mfma_f32_16x16x32_bf16(a2, b0, (f32x4){0,0,0,0}, 0, 0, 0);
        c1 = __builtin_amdgcn_mfma_f32_16x16x32_bf16(a3, b1, c1, 0, 0, 0);
        float bias = (p == 0) ? bq[n] * QSCL : (p == 1) ? bk[n] : bv[n];
        #pragma unroll
        for (int r = 0; r < 4; ++r) {
            int tok = tok0 + quad * 4 + r;
            int bb0 = tok / S1C, ss0 = tok % S1C;
            int bh = bb0 * NHD + w;
            short val = f2b(c0[r] + bias);
            int tok2 = tok + 16;
            int bb1 = tok2 / S1C, ss1 = tok2 % S1C;
            int bh2 = bb1 * NHD + w;
            short val2 = f2b(c1[r] + bias);
            if (p == 0) {
                qb[((size_t)bh * SPAD + ss0) * 16 + lo] = val;
                qb[((size_t)bh2 * SPAD + ss1) * 16 + lo] = val2;
            } else if (p == 1) {
                kb[((size_t)bh * SPAD + ss0) * 16 + lo] = val;
                kb[((size_t)bh2 * SPAD + ss1) * 16 + lo] = val2;
            } else {
                vbt[((size_t)bh * 16 + lo) * SPAD + ss0] = val;
                vbt[((size_t)bh2 * 16 + lo) * SPAD + ss1] = val2;
            }
        }
    }
}

// ---------------------------------------------------------------------------
// Kernel 3: flash MFMA attention (r25 measured-best SPLIT-K version).
// ---------------------------------------------------------------------------
__global__ __launch_bounds__(256) void k_attn(
    const short* __restrict__ qb, const short* __restrict__ kb,
    const short* __restrict__ vbt, short* __restrict__ ob)
{
    int bid = blockIdx.x;
    int bh  = bid % NBH;           // 11 blocks of a bh share bid%8 (XCD/L2)
    int grp = bid / NBH;           // 0..10
    int b = bh >> 2, h = bh & 3;
    int t = threadIdx.x;
    int w = t >> 6, l = t & 63;
    int slot = w >> 1, half = w & 1;
    int quad = l >> 4, lo = l & 15;
    int t0 = grp * 2 + slot;       // 0..21 (exact cover)
    int t1 = t0 + 22;              // 22..43
    int t2 = t0 + 44;              // 44..65
    int qg0 = t0 * 16, qg1 = t1 * 16, qg2 = t2 * 16;

    __shared__ u32x2 ptmem[4][544];
    char* ptc = (char*)&ptmem[w][0];
    unsigned ptbase = (unsigned)(uintptr_t)ptc;

    const short* qbase = qb + (size_t)bh * SPAD * 16;
    const short* kbase = kb + (size_t)bh * SPAD * 16;
    const short* vbase = vbt + (size_t)bh * 16 * SPAD;

    bf16x8 aQ0 = {0,0,0,0,0,0,0,0}, aQ1 = {0,0,0,0,0,0,0,0}, aQ2 = {0,0,0,0,0,0,0,0};
    if (quad < 2) {
        aQ0 = *(const bf16x8*)(qbase + ((size_t)(qg0 + lo)) * 16 + quad * 8);
        aQ1 = *(const bf16x8*)(qbase + ((size_t)(qg1 + lo)) * 16 + quad * 8);
        aQ2 = *(const bf16x8*)(qbase + ((size_t)(qg2 + lo)) * 16 + quad * 8);
    }

    const short ONE = 0x3F80;
    bf16x8 aOne = {ONE, ONE, ONE, ONE, ONE, ONE, ONE, ONE};

    f32x4 oc0 = {0.f,0.f,0.f,0.f}, oc1 = {0.f,0.f,0.f,0.f}, oc2 = {0.f,0.f,0.f,0.f};
    f32x4 dn0 = {0.f,0.f,0.f,0.f}, dn1 = {0.f,0.f,0.f,0.f}, dn2 = {0.f,0.f,0.f,0.f};

    unsigned wo0 = (unsigned)((lo >> 2) * 136 + (lo & 3) * 32 + quad * 8);
    unsigned ro = (unsigned)(quad * 272 + lo * 8);
    unsigned rdp = ptbase + ro;            // P read addr
    char* wbp = ptc + wo0;                 // P write base (lane-resolved)

    bf16x8 kxA, kyA, kxB, kyB, vA, vB;
    int c0 = half << 4;                    // 0 or 16 (first chunk of this half)

    // ---- prologue: load K(c0) -> A (consumed here), V(c0) -> vA,
    //      K(c0+1) -> B; produce P(c0) ----
    {
        const short* k0p = kbase + (size_t)(c0 * 32 + lo) * 16 + (quad & 1) * 8;
        kxA = *(const bf16x8*)k0p;
        kyA = *(const bf16x8*)(k0p + 256);
        vA  = *(const bf16x8*)(vbase + (size_t)lo * SPAD + c0 * 32 + quad * 8);
        const short* k1p = kbase + (size_t)((c0 + 1) * 32 + lo) * 16 + (quad & 1) * 8;
        kxB = *(const bf16x8*)k1p;
        kyB = *(const bf16x8*)(k1p + 256);

        f32x4 c0_ = __builtin_amdgcn_mfma_f32_16x16x32_bf16(aQ0, kxA, (f32x4){0.f,0.f,0.f,0.f}, 0, 0, 0);
        f32x4 c1_ = __builtin_amdgcn_mfma_f32_16x16x32_bf16(aQ1, kxA, (f32x4){0.f,0.f,0.f,0.f}, 0, 0, 0);
        f32x4 c2_ = __builtin_amdgcn_mfma_f32_16x16x32_bf16(aQ2, kxA, (f32x4){0.f,0.f,0.f,0.f}, 0, 0, 0);
        *(u32x2*)(wbp)        = pack4exp(c0_, true);
        *(u32x2*)(wbp + 1088) = pack4exp(c1_, true);
        *(u32x2*)(wbp + 2176) = pack4exp(c2_, true);
        c0_ = __builtin_amdgcn_mfma_f32_16x16x32_bf16(aQ0, kyA, (f32x4){0.f,0.f,0.f,0.f}, 0, 0, 0);
        c1_ = __builtin_amdgcn_mfma_f32_16x16x32_bf16(aQ1, kyA, (f32x4){0.f,0.f,0.f,0.f}, 0, 0, 0);
        c2_ = __builtin_amdgcn_mfma_f32_16x16x32_bf16(aQ2, kyA, (f32x4){0.f,0.f,0.f,0.f}, 0, 0, 0);
        *(u32x2*)(wbp + 544)  = pack4exp(c0_, true);
        *(u32x2*)(wbp + 1632) = pack4exp(c1_, true);
        *(u32x2*)(wbp + 2720) = pack4exp(c2_, true);
    }

#define STEP(CH, TAIL, KXC, KYC, KXN, KYN, VP, VC) do {                       \
    int ch_ = (CH);                                                            \
    if (!(TAIL)) {                                                             \
        const short* kn_ = kbase + (size_t)((ch_ + 1) * 32 + lo) * 16 + (quad & 1) * 8; \
        KXN = *(const bf16x8*)kn_;                                             \
        KYN = *(const bf16x8*)(kn_ + 256);                                     \
    }                                                                          \
    VC = *(const bf16x8*)(vbase + (size_t)lo * SPAD + ch_ * 32 + quad * 8);    \
    u32x2 p00_, p01_, p10_, p11_, p20_, p21_;                                  \
    asm volatile("ds_read_b64_tr_b16 %0, %1"             : "=v"(p00_) : "v"(rdp) : "memory"); \
    asm volatile("ds_read_b64_tr_b16 %0, %1 offset:136"  : "=v"(p01_) : "v"(rdp) : "memory"); \
    asm volatile("ds_read_b64_tr_b16 %0, %1 offset:1088" : "=v"(p10_) : "v"(rdp) : "memory"); \
    asm volatile("ds_read_b64_tr_b16 %0, %1 offset:1224" : "=v"(p11_) : "v"(rdp) : "memory"); \
    asm volatile("ds_read_b64_tr_b16 %0, %1 offset:2176" : "=v"(p20_) : "v"(rdp) : "memory"); \
    asm volatile("ds_read_b64_tr_b16 %0, %1 offset:2312" : "=v"(p21_) : "v"(rdp) : "memory"); \
    u32x2 wt0x_, wt1x_, wt2x_, wt0y_, wt1y_, wt2y_;                            \
    {                                                                          \
        f32x4 c0_ = __builtin_amdgcn_mfma_f32_16x16x32_bf16(aQ0, KXC, (f32x4){0.f,0.f,0.f,0.f}, 0, 0, 0); \
        f32x4 c1_ = __builtin_amdgcn_mfma_f32_16x16x32_bf16(aQ1, KXC, (f32x4){0.f,0.f,0.f,0.f}, 0, 0, 0); \
        f32x4 c2_ = __builtin_amdgcn_mfma_f32_16x16x32_bf16(aQ2, KXC, (f32x4){0.f,0.f,0.f,0.f}, 0, 0, 0); \
        bool v0_ = !(TAIL) || (lo == 0);                                       \
        wt0x_ = pack4exp(c0_, v0_);                                            \
        wt1x_ = pack4exp(c1_, v0_);                                            \
        wt2x_ = pack4exp(c2_, v0_);                                            \
        c0_ = __builtin_amdgcn_mfma_f32_16x16x32_bf16(aQ0, KYC, (f32x4){0.f,0.f,0.f,0.f}, 0, 0, 0); \
        c1_ = __builtin_amdgcn_mfma_f32_16x16x32_bf16(aQ1, KYC, (f32x4){0.f,0.f,0.f,0.f}, 0, 0, 0); \
        c2_ = __builtin_amdgcn_mfma_f32_16x16x32_bf16(aQ2, KYC, (f32x4){0.f,0.f,0.f,0.f}, 0, 0, 0); \
        bool v1_ = !(TAIL);                                                    \
        wt0y_ = pack4exp(c0_, v1_);                                            \
        wt1y_ = pack4exp(c1_, v1_);                                            \
        wt2y_ = pack4exp(c2_, v1_);                                            \
    }                                                                          \
    asm volatile("s_waitcnt lgkmcnt(0)" ::: "memory");                         \
    __builtin_amdgcn_sched_barrier(0);                                         \
    u32x4 q0_; q0_[0] = p00_[0]; q0_[1] = p00_[1]; q0_[2] = p01_[0]; q0_[3] = p01_[1]; \
    u32x4 q1_; q1_[0] = p10_[0]; q1_[1] = p10_[1]; q1_[2] = p11_[0]; q1_[3] = p11_[1]; \
    u32x4 q2_; q2_[0] = p20_[0]; q2_[1] = p20_[1]; q2_[2] = p21_[0]; q2_[3] = p21_[1]; \
    bf16x8 pB0_ = __builtin_bit_cast(bf16x8, q0_);                             \
    bf16x8 pB1_ = __builtin_bit_cast(bf16x8, q1_);                             \
    bf16x8 pB2_ = __builtin_bit_cast(bf16x8, q2_);                             \
    oc0 = __builtin_amdgcn_mfma_f32_16x16x32_bf16(VP, pB0_, oc0, 0, 0, 0);     \
    dn0 = __builtin_amdgcn_mfma_f32_16x16x32_bf16(aOne, pB0_, dn0, 0, 0, 0);   \
    oc1 = __builtin_amdgcn_mfma_f32_16x16x32_bf16(VP, pB1_, oc1, 0, 0, 0);     \
    dn1 = __builtin_amdgcn_mfma_f32_16x16x32_bf16(aOne, pB1_, dn1, 0, 0, 0);   \
    oc2 = __builtin_amdgcn_mfma_f32_16x16x32_bf16(VP, pB2_, oc2, 0, 0, 0);     \
    dn2 = __builtin_amdgcn_mfma_f32_16x16x32_bf16(aOne, pB2_, dn2, 0, 0, 0);   \
    *(u32x2*)(wbp)        = wt0x_;                                             \
    *(u32x2*)(wbp + 544)  = wt0y_;                                             \
    *(u32x2*)(wbp + 1088) = wt1x_;                                             \
    *(u32x2*)(wbp + 1632) = wt1y_;                                             \
    *(u32x2*)(wbp + 2176) = wt2x_;                                             \
    *(u32x2*)(wbp + 2720) = wt2y_;                                             \
} while (0)

#define EPILOGUE(VLAST) do {                                                   \
    u32x2 p00, p01, p10, p11, p20, p21;                                        \
    asm volatile("ds_read_b64_tr_b16 %0, %1"             : "=v"(p00) : "v"(rdp) : "memory"); \
    asm volatile("ds_read_b64_tr_b16 %0, %1 offset:136"  : "=v"(p01) : "v"(rdp) : "memory"); \
    asm volatile("ds_read_b64_tr_b16 %0, %1 offset:1088" : "=v"(p10) : "v"(rdp) : "memory"); \
    asm volatile("ds_read_b64_tr_b16 %0, %1 offset:1224" : "=v"(p11) : "v"(rdp) : "memory"); \
    asm volatile("ds_read_b64_tr_b16 %0, %1 offset:2176" : "=v"(p20) : "v"(rdp) : "memory"); \
    asm volatile("ds_read_b64_tr_b16 %0, %1 offset:2312" : "=v"(p21) : "v"(rdp) : "memory"); \
    asm volatile("s_waitcnt lgkmcnt(0)" ::: "memory");                         \
    __builtin_amdgcn_sched_barrier(0);                                         \
    u32x4 q0; q0[0] = p00[0]; q0[1] = p00[1]; q0[2] = p01[0]; q0[3] = p01[1];  \
    u32x4 q1; q1[0] = p10[0]; q1[1] = p10[1]; q1[2] = p11[0]; q1[3] = p11[1];  \
    u32x4 q2; q2[0] = p20[0]; q2[1] = p20[1]; q2[2] = p21[0]; q2[3] = p21[1];  \
    bf16x8 pB0 = __builtin_bit_cast(bf16x8, q0);                               \
    bf16x8 pB1 = __builtin_bit_cast(bf16x8, q1);                               \
    bf16x8 pB2 = __builtin_bit_cast(bf16x8, q2);                               \
    oc0 = __builtin_amdgcn_mfma_f32_16x16x32_bf16(VLAST, pB0, oc0, 0, 0, 0);   \
    dn0 = __builtin_amdgcn_mfma_f32_16x16x32_bf16(aOne, pB0, dn0, 0, 0, 0);    \
    oc1 = __builtin_amdgcn_mfma_f32_16x16x32_bf16(VLAST, pB1, oc1, 0, 0, 0);   \
    dn1 = __builtin_amdgcn_mfma_f32_16x16x32_bf16(aOne, pB1, dn1, 0, 0, 0);    \
    oc2 = __builtin_amdgcn_mfma_f32_16x16x32_bf16(VLAST, pB2, oc2, 0, 0, 0);   \
    dn2 = __builtin_amdgcn_mfma_f32_16x16x32_bf16(aOne, pB2, dn2, 0, 0, 0);    \
} while (0)

    if (half == 0) {
        for (int ch = 1; ch < 15; ch += 2) {
            STEP(ch,     0, kxB, kyB, kxA, kyA, vA, vB);
            STEP(ch + 1, 0, kxA, kyA, kxB, kyB, vB, vA);
        }
        STEP(15, 0, kxB, kyB, kxA, kyA, vA, vB);
        EPILOGUE(vB);
    } else {
        for (int ch = 17; ch < 31; ch += 2) {
            STEP(ch,     0, kxB, kyB, kxA, kyA, vA, vB);
            STEP(ch + 1, 0, kxA, kyA, kxB, kyB, vB, vA);
        }
        STEP(31, 0, kxB, kyB, kxA, kyA, vA, vB);
        STEP(32, 1, kxA, kyA, kxB, kyB, vB, vA);
        EPILOGUE(vA);
    }
#undef STEP
#undef EPILOGUE

    // ---- store fp32 partials into this wave's LDS region ----
    {
        float* pb = (float*)ptc;
        int base = l * 17;   // stride 17 floats: conflict-free (odd stride)
        pb[base + 0] = oc0[0]; pb[base + 1] = oc0[1];
        pb[base + 2] = oc0[2]; pb[base + 3] = oc0[3]; pb[base + 4] = dn0[0];
        pb[base + 5] = oc1[0]; pb[base + 6] = oc1[1];
        pb[base + 7] = oc1[2]; pb[base + 8] = oc1[3]; pb[base + 9] = dn1[0];
        pb[base +10] = oc2[0]; pb[base +11] = oc2[1];
        pb[base +12] = oc2[2]; pb[base +13] = oc2[3]; pb[base +14] = dn2[0];
    }
    __syncthreads();

    // ---- even wave of each pair combines with partner and writes out ----
    if (half == 0) {
        const float* pp = (const float*)&ptmem[w ^ 1][0];
        int base = l * 17;
        {
            int qrow = qg0 + lo;
            if (qrow < S1C) {
                float inv = 1.0f / (dn0[0] + pp[base + 4]);
                float s0 = oc0[0] + pp[base + 0], s1 = oc0[1] + pp[base + 1];
                float s2 = oc0[2] + pp[base + 2], s3 = oc0[3] + pp[base + 3];
                unsigned p0 = (unsigned short)f2b(s0 * inv) | ((unsigned)(unsigned short)f2b(s1 * inv) << 16);
                unsigned p1 = (unsigned short)f2b(s2 * inv) | ((unsigned)(unsigned short)f2b(s3 * inv) << 16);
                *(uint2*)(ob + ((size_t)b * S1C + qrow) * DD + h * DHD + quad * 4) = make_uint2(p0, p1);
            }
        }
        {
            int qrow = qg1 + lo;
            if (qrow < S1C) {
                float inv = 1.0f / (dn1[0] + pp[base + 9]);
                float s0 = oc1[0] + pp[base + 5], s1 = oc1[1] + pp[base + 6];
                float s2 = oc1[2] + pp[base + 7], s3 = oc1[3] + pp[base + 8];
                unsigned p0 = (unsigned short)f2b(s0 * inv) | ((unsigned)(unsigned short)f2b(s1 * inv) << 16);
                unsigned p1 = (unsigned short)f2b(s2 * inv) | ((unsigned)(unsigned short)f2b(s3 * inv) << 16);
                *(uint2*)(ob + ((size_t)b * S1C + qrow) * DD + h * DHD + quad * 4) = make_uint2(p0, p1);
            }
        }
        {
            int qrow = qg2 + lo;
            if (qrow < S1C) {
                float inv = 1.0f / (dn2[0] + pp[base + 14]);
                float s0 = oc2[0] + pp[base + 10], s1 = oc2[1] + pp[base + 11];
                float s2 = oc2[2] + pp[base + 12], s3 = oc2[3] + pp[base + 13];
                unsigned p0 = (unsigned short)f2b(s0 * inv) | ((unsigned)(unsigned short)f2b(s1 * inv) << 16);
                unsigned p1 = (unsigned short)f2b(s2 * inv) | ((unsigned)(unsigned short)f2b(s3 * inv) << 16);
                *(uint2*)(ob + ((size_t)b * S1C + qrow) * DD + h * DHD + quad * 4) = make_uint2(p0, p1);
            }
        }
    }
}

// ---------------------------------------------------------------------------
// Kernel 4: fused transformer tail (r19 measured-best version).
// ---------------------------------------------------------------------------
__global__ __launch_bounds__(256) void k_block(
    const short* __restrict__ ob, float* __restrict__ x,
    const short* __restrict__ woT, fp bo, fp ln1s, fp ln1b,
    const short* __restrict__ w1T, fp b1, const short* __restrict__ w2T, fp b2,
    fp ln2s, fp ln2b,
    const short* __restrict__ wqkvTn, fp bqn, fp bkn, fp bvn,
    short* __restrict__ qb, short* __restrict__ kb, short* __restrict__ vbt,
    int has_next)
{
    int blk = blockIdx.x, t = threadIdx.x;
    int tok0 = blk * FT2;
    int w = t >> 6, l = t & 63;
    int quad = l >> 4, lo = l & 15;

    __shared__ float otf[FT2][OPAD];          // 8704 B; ys overlays (136-short rows)
    __shared__ u32x2 hidtr[2][8][136];        // 17408 B: [tile][kchunk][subtiles]
    short* ysb = (short*)&otf[0][0];
    char*  hidc = (char*)&hidtr[0][0][0];
    unsigned hidbase = (unsigned)(uintptr_t)hidc;

    // ---- LN lane mapping + entry prefetch (hidden under oproj) ----
    int tt8 = t >> 3;            // token 0..31
    int d8s = (t & 7) * 8;       // dim base
    const float* xrow = x + (size_t)(tok0 + tt8) * DD + d8s;
    float4 xpa = *(const float4*)xrow;
    float4 xpb = *(const float4*)(xrow + 4);
    float4 s1a = *(const float4*)(ln1s + d8s);
    float4 s1b = *(const float4*)(ln1s + d8s + 4);
    float4 b1a = *(const float4*)(ln1b + d8s);
    float4 b1b = *(const float4*)(ln1b + d8s + 4);

    // ---- oproj (both token-tiles, weights loaded once) ----
    {
        const short* obp0 = ob + ((size_t)(tok0 + lo)) * DD;
        const short* obp1 = ob + ((size_t)(tok0 + 16 + lo)) * DD;
        bf16x8 a0 = *(const bf16x8*)(obp0 + quad * 8);
        bf16x8 a1 = *(const bf16x8*)(obp0 + 32 + quad * 8);
        bf16x8 a2 = *(const bf16x8*)(obp1 + quad * 8);
        bf16x8 a3 = *(const bf16x8*)(obp1 + 32 + quad * 8);
        int n = w * 16 + lo;
        const short* wT = woT + (size_t)n * 64;
        bf16x8 b0 = *(const bf16x8*)(wT + quad * 8);
        bf16x8 bb = *(const bf16x8*)(wT + 32 + quad * 8);
        f32x4 c0 = __builtin_amdgcn_mfma_f32_16x16x32_bf16(a0, b0, (f32x4){0,0,0,0}, 0, 0, 0);
        c0 = __builtin_amdgcn_mfma_f32_16x16x32_bf16(a1, bb, c0, 0, 0, 0);
        f32x4 c1 = __builtin_amdgcn_mfma_f32_16x16x32_bf16(a2, b0, (f32x4){0,0,0,0}, 0, 0, 0);
        c1 = __builtin_amdgcn_mfma_f32_16x16x32_bf16(a3, bb, c1, 0, 0, 0);
        float bov = bo[n];
        #pragma unroll
        for (int r = 0; r < 4; ++r) {
            otf[quad * 4 + r][n] = c0[r] + bov;
            otf[16 + quad * 4 + r][n] = c1[r] + bov;
        }
    }
    __syncthreads();

    // ---- LN1 (8 lanes per token) ----
    float yv[8];
    {
        float4 o0 = *(const float4*)&otf[tt8][d8s];
        float4 o1 = *(const float4*)&otf[tt8][d8s + 4];
        float v0 = o0.x + xpa.x, v1 = o0.y + xpa.y, v2 = o0.z + xpa.z, v3 = o0.w + xpa.w;
        float v4 = o1.x + xpb.x, v5 = o1.y + xpb.y, v6 = o1.z + xpb.z, v7 = o1.w + xpb.w;
        float sum = ((v0 + v1) + (v2 + v3)) + ((v4 + v5) + (v6 + v7));
        float vs = v0 * v0;
        vs = fmaf(v1, v1, vs); vs = fmaf(v2, v2, vs); vs = fmaf(v3, v3, vs);
        vs = fmaf(v4, v4, vs); vs = fmaf(v5, v5, vs); vs = fmaf(v6, v6, vs);
        vs = fmaf(v7, v7, vs);
        sum += __shfl_xor(sum, 1, 64); sum += __shfl_xor(sum, 2, 64); sum += __shfl_xor(sum, 4, 64);
        vs  += __shfl_xor(vs , 1, 64); vs  += __shfl_xor(vs , 2, 64); vs  += __shfl_xor(vs , 4, 64);
        float mean = sum * (1.0f / 64.0f);
        float var = vs * (1.0f / 64.0f) - mean * mean;
        float rs = rsqrtf(var + 1e-5f);
        yv[0] = (v0 - mean) * rs * s1a.x + b1a.x;
        yv[1] = (v1 - mean) * rs * s1a.y + b1a.y;
        yv[2] = (v2 - mean) * rs * s1a.z + b1a.z;
        yv[3] = (v3 - mean) * rs * s1a.w + b1a.w;
        yv[4] = (v4 - mean) * rs * s1b.x + b1b.x;
        yv[5] = (v5 - mean) * rs * s1b.y + b1b.y;
        yv[6] = (v6 - mean) * rs * s1b.z + b1b.z;
        yv[7] = (v7 - mean) * rs * s1b.w + b1b.w;
        u32x2 pa = pack4cvt(yv[0], yv[1], yv[2], yv[3]);
        u32x2 pb = pack4cvt(yv[4], yv[5], yv[6], yv[7]);
        *(u32x4*)&ysb[tt8 * 136 + d8s] = (u32x4){pa[0], pa[1], pb[0], pb[1]};
    }
    __syncthreads();

    // ---- FFN1: hid = gelu(y @ w1 + b1), tr-layout packed b64 writes ----
    {
        bf16x8 a0 = *(const bf16x8*)&ysb[(size_t)lo * 136 + quad * 8];
        bf16x8 a1 = *(const bf16x8*)&ysb[(size_t)lo * 136 + 32 + quad * 8];
        bf16x8 a2 = *(const bf16x8*)&ysb[(size_t)(16 + lo) * 136 + quad * 8];
        bf16x8 a3 = *(const bf16x8*)&ysb[(size_t)(16 + lo) * 136 + 32 + quad * 8];
        unsigned hoff = (unsigned)(w * 2176 + (lo >> 2) * 136 + (lo & 3) * 32 + quad * 8);
        #pragma unroll
        for (int i = 0; i < 4; ++i) {
            int n = w * 64 + i * 16 + lo;
            const short* wT = w1T + (size_t)n * 64;
            bf16x8 b0 = *(const bf16x8*)(wT + quad * 8);
            bf16x8 bb = *(const bf16x8*)(wT + 32 + quad * 8);
            f32x4 c0 = __builtin_amdgcn_mfma_f32_16x16x32_bf16(a0, b0, (f32x4){0,0,0,0}, 0, 0, 0);
            c0 = __builtin_amdgcn_mfma_f32_16x16x32_bf16(a1, bb, c0, 0, 0, 0);
            f32x4 c1 = __builtin_amdgcn_mfma_f32_16x16x32_bf16(a2, b0, (f32x4){0,0,0,0}, 0, 0, 0);
            c1 = __builtin_amdgcn_mfma_f32_16x16x32_bf16(a3, bb, c1, 0, 0, 0);
            float b1v = b1[n];
            unsigned off = hoff + (i >> 1) * 1088 + (i & 1) * 544;
            *(u32x2*)(hidc + off) = pack4cvt(
                gelu_fast(c0[0] + b1v), gelu_fast(c0[1] + b1v),
                gelu_fast(c0[2] + b1v), gelu_fast(c0[3] + b1v));
            *(u32x2*)(hidc + 8704 + off) = pack4cvt(
                gelu_fast(c1[0] + b1v), gelu_fast(c1[1] + b1v),
                gelu_fast(c1[2] + b1v), gelu_fast(c1[3] + b1v));
        }
    }
    __syncthreads();

    // ---- FFN2: out = hid @ w2 + b2 (K=256), tr-read A-frags, depth-2 pipe ----
    {
        f32x4 c20 = {0.f,0.f,0.f,0.f}, c21 = {0.f,0.f,0.f,0.f};
        const short* wT2 = w2T + (size_t)(w * 16 + lo) * 256;
        unsigned ro = (unsigned)(quad * 272 + lo * 8);
        unsigned tb0 = hidbase + ro;
        unsigned tb1 = hidbase + 8704 + ro;
        u32x2 pA0, pA1, pA2, pA3, pB0, pB1, pB2, pB3;

#define TRRD(dst, addr, OFFSTR) \
    asm volatile("ds_read_b64_tr_b16 %0, %1 offset:" OFFSTR : "=v"(dst) : "v"(addr))
#define ISS(P0,P1,P2,P3, O1, O2) \
    TRRD(P0, tb0, O1); TRRD(P1, tb0, O2); TRRD(P2, tb1, O1); TRRD(P3, tb1, O2)
#define W4 asm volatile("s_waitcnt lgkmcnt(4)" ::: "memory"); __builtin_amdgcn_sched_barrier(0)
#define W0 asm volatile("s_waitcnt lgkmcnt(0)" ::: "memory"); __builtin_amdgcn_sched_barrier(0)
#define CONS(P0,P1,P2,P3, BF) do { \
    u32x4 q0_; q0_[0]=P0[0]; q0_[1]=P0[1]; q0_[2]=P1[0]; q0_[3]=P1[1]; \
    u32x4 q1_; q1_[0]=P2[0]; q1_[1]=P2[1]; q1_[2]=P3[0]; q1_[3]=P3[1]; \
    c20 = __builtin_amdgcn_mfma_f32_16x16x32_bf16(__builtin_bit_cast(bf16x8,q0_), BF, c20, 0,0,0); \
    c21 = __builtin_amdgcn_mfma_f32_16x16x32_bf16(__builtin_bit_cast(bf16x8,q1_), BF, c21, 0,0,0); \
} while (0)

        bf16x8 bfA = *(const bf16x8*)(wT2 + quad * 8);
        ISS(pA0,pA1,pA2,pA3, "0",    "136");
        bf16x8 bfB = *(const bf16x8*)(wT2 + 32 + quad * 8);
        ISS(pB0,pB1,pB2,pB3, "1088", "1224");
        W4; CONS(pA0,pA1,pA2,pA3, bfA);
        bfA = *(const bf16x8*)(wT2 + 64 + quad * 8);
        ISS(pA0,pA1,pA2,pA3, "2176", "2312");
        W4; CONS(pB0,pB1,pB2,pB3, bfB);
        bfB = *(const bf16x8*)(wT2 + 96 + quad * 8);
        ISS(pB0,pB1,pB2,pB3, "3264", "3400");
        W4; CONS(pA0,pA1,pA2,pA3, bfA);
        bfA = *(const bf16x8*)(wT2 + 128 + quad * 8);
        ISS(pA0,pA1,pA2,pA3, "4352", "4488");
        W4; CONS(pB0,pB1,pB2,pB3, bfB);
        bfB = *(const bf16x8*)(wT2 + 160 + quad * 8);
        ISS(pB0,pB1,pB2,pB3, "5440", "5576");
        W4; CONS(pA0,pA1,pA2,pA3, bfA);
        bfA = *(const bf16x8*)(wT2 + 192 + quad * 8);
        ISS(pA0,pA1,pA2,pA3, "6528", "6664");
        W4; CONS(pB0,pB1,pB2,pB3, bfB);
        bfB = *(const bf16x8*)(wT2 + 224 + quad * 8);
        ISS(pB0,pB1,pB2,pB3, "7616", "7752");
        W4; CONS(pA0,pA1,pA2,pA3, bfA);
        W0; CONS(pB0,pB1,pB2,pB3, bfB);
#undef TRRD
#undef ISS
#undef W4
#undef W0
#undef CONS

        float b2v = b2[w * 16 + lo];
        #pragma unroll
        for (int r = 0; r < 4; ++r) {
            otf[quad * 4 + r][w * 16 + lo] = c20[r] + b2v;
            otf[16 + quad * 4 + r][w * 16 + lo] = c21[r] + b2v;
        }
    }
    __syncthreads();

    // ---- LN2 (8 lanes per token); residual = yv (registers) ----
    {
        float4 s2a = *(const float4*)(ln2s + d8s);
        float4 s2b = *(const float4*)(ln2s + d8s + 4);
        float4 b2a = *(const float4*)(ln2b + d8s);
        float4 b2b = *(const float4*)(ln2b + d8s + 4);
        float4 o0 = *(const float4*)&otf[tt8][d8s];
        float4 o1 = *(const float4*)&otf[tt8][d8s + 4];
        float v0 = o0.x + yv[0], v1 = o0.y + yv[1], v2 = o0.z + yv[2], v3 = o0.w + yv[3];
        float v4 = o1.x + yv[4], v5 = o1.y + yv[5], v6 = o1.z + yv[6], v7 = o1.w + yv[7];
        float sum = ((v0 + v1) + (v2 + v3)) + ((v4 + v5) + (v6 + v7));
        float vs = v0 * v0;
        vs = fmaf(v1, v1, vs); vs = fmaf(v2, v2, vs); vs = fmaf(v3, v3, vs);
        vs = fmaf(v4, v4, vs); vs = fmaf(v5, v5, vs); vs = fmaf(v6, v6, vs);
        vs = fmaf(v7, v7, vs);
        sum += __shfl_xor(sum, 1, 64); sum += __shfl_xor(sum, 2, 64); sum += __shfl_xor(sum, 4, 64);
        vs  += __shfl_xor(vs , 1, 64); vs  += __shfl_xor(vs , 2, 64); vs  += __shfl_xor(vs , 4, 64);
        float mean = sum * (1.0f / 64.0f);
        float var = vs * (1.0f / 64.0f) - mean * mean;
        float rs = rsqrtf(var + 1e-5f);
        float y0 = (v0 - mean) * rs * s2a.x + b2a.x;
        float y1 = (v1 - mean) * rs * s2a.y + b2a.y;
        float y2 = (v2 - mean) * rs * s2a.z + b2a.z;
        float y3 = (v3 - mean) * rs * s2a.w + b2a.w;
        float y4 = (v4 - mean) * rs * s2b.x + b2b.x;
        float y5 = (v5 - mean) * rs * s2b.y + b2b.y;
        float y6 = (v6 - mean) * rs * s2b.z + b2b.z;
        float y7 = (v7 - mean) * rs * s2b.w + b2b.w;
        float* xo = x + (size_t)(tok0 + tt8) * DD + d8s;
        *(float4*)xo = make_float4(y0, y1, y2, y3);
        *(float4*)(xo + 4) = make_float4(y4, y5, y6, y7);
        u32x2 pa = pack4cvt(y0, y1, y2, y3);
        u32x2 pb = pack4cvt(y4, y5, y6, y7);
        *(u32x4*)&ysb[tt8 * 136 + d8s] = (u32x4){pa[0], pa[1], pb[0], pb[1]};
    }
    __syncthreads();

    // ---- next-layer QKV, both tiles ----
    if (has_next) {
        bf16x8 a0 = *(const bf16x8*)&ysb[(size_t)lo * 136 + quad * 8];
        bf16x8 a1 = *(const bf16x8*)&ysb[(size_t)lo * 136 + 32 + quad * 8];
        bf16x8 a2 = *(const bf16x8*)&ysb[(size_t)(16 + lo) * 136 + quad * 8];
        bf16x8 a3 = *(const bf16x8*)&ysb[(size_t)(16 + lo) * 136 + 32 + quad * 8];
        int n = w * 16 + lo;
        #pragma unroll
        for (int p = 0; p < 3; ++p) {
            const short* wT = wqkvTn + (size_t)p * 4096 + (size_t)n * 64;
            bf16x8 b0 = *(const bf16x8*)(wT + quad * 8);
            bf16x8 bb = *(const bf16x8*)(wT + 32 + quad * 8);
            f32x4 c0 = __builtin_amdgcn_mfma_f32_16x16x32_bf16(a0, b0, (f32x4){0,0,0,0}, 0, 0, 0);
            c0 = __builtin_amdgcn_mfma_f32_16x16x32_bf16(a1, bb, c0, 0, 0, 0);
            f32x4 c1 = __builtin_amdgcn_mfma_f32_16x16x32_bf16(a2, b0, (f32x4){0,0,0,0}, 0, 0, 0);
            c1 = __builtin_amdgcn_mfma_f32_16x16x32_bf16(a3, bb, c1, 0, 0, 0);
            float bias = (p == 0) ? bqn[n] * QSCL : (p == 1) ? bkn[n] : bvn[n];
            #pragma unroll
            for (int r = 0; r < 4; ++r) {
                int tok = tok0 + quad * 4 + r;
                int bb0 = tok / S1C, ss0 = tok % S1C;
                int bh = bb0 * NHD + w;
                short val = f2b(c0[r] + bias);
                int tok2 = tok + 16;
                int bb1 = tok2 / S1C, ss1 = tok2 % S1C;
                int bh2 = bb1 * NHD + w;
                short val2 = f2b(c1[r] + bias);
                if (p == 0) {
                    qb[((size_t)bh * SPAD + ss0) * 16 + lo] = val;
                    qb[((size_t)bh2 * SPAD + ss1) * 16 + lo] = val2;
                } else if (p == 1) {
                    kb[((size_t)bh * SPAD + ss0) * 16 + lo] = val;
                    kb[((size_t)bh2 * SPAD + ss1) * 16 + lo] = val2;
                } else {
                    vbt[((size_t)bh * 16 + lo) * SPAD + ss0] = val;
                    vbt[((size_t)bh2 * 16 + lo) * SPAD + ss1] = val2;
                }
            }
        }
    }
}

// ---------------------------------------------------------------------------
// Kernel 6: head MLPs. One block (64 thr) per batch element.
// ---------------------------------------------------------------------------
__global__ __launch_bounds__(64) void k_head(
    const float* __restrict__ x, fp proj_vars, fp param_vars,
    const int* __restrict__ materials,
    fp pw1, fp pb1, fp pw2, fp pb2, fp pw3, fp pb3,
    fp pw4, fp pb4, fp pw5, fp pb5,
    fp ipw1, fp ipb1, fp ipw2, fp ipb2,
    fp hw1, fp hb1, fp hw2, fp hb2, fp hw3, fp hb3,
    float* __restrict__ out)
{
    int b = blockIdx.x;
    int tid = threadIdx.x;
    __shared__ float A[80], Bf[80], pp[8], mi[32];

    if (tid < 3) A[tid] = proj_vars[b * 3 + tid];
    A[3 + tid] = x[((size_t)b * S1C + 0) * DD + tid];
    __syncthreads();

    if (tid < 34) {
        float a = pb1[tid];
        for (int i = 0; i < 67; ++i) a += A[i] * pw1[i * 34 + tid];
        Bf[tid] = gelu_exact(a);
    }
    __syncthreads();
    if (tid < 11) {
        float a = pb2[tid];
        for (int i = 0; i < 34; ++i) a += Bf[i] * pw2[i * 11 + tid];
        A[tid] = gelu_exact(a);
    }
    __syncthreads();
    if (tid < 36) {
        float a = pb3[tid];
        for (int i = 0; i < 11; ++i) a += A[i] * pw3[i * 36 + tid];
        Bf[tid] = gelu_exact(a);
    }
    __syncthreads();
    if (tid < 22) {
        float a = pb4[tid];
        for (int i = 0; i < 36; ++i) a += Bf[i] * pw4[i * 22 + tid];
        A[tid] = gelu_exact(a);
    }
    __syncthreads();
    if (tid < 24) {
        float a = pb5[tid];
        for (int i = 0; i < 22; ++i) a += A[i] * pw5[i * 24 + tid];
        mi[3 + tid] = a;
    }
    if (tid < 3) {
        float a = ipb1[tid];
        for (int i = 0; i < 3; ++i) a += param_vars[b * 3 + i] * ipw1[i * 3 + tid];
        pp[tid] = gelu_exact(a);
    }
    __syncthreads();
    if (tid < 3) {
        float a = ipb2[tid];
        for (int i = 0; i < 3; ++i) a += pp[i] * ipw2[i * 3 + tid];
        mi[tid] = a;
    }
    __syncthreads();

    int m = materials[b];
    if (tid < 15) {
        float a = hb1[m * 15 + tid];
        for (int i = 0; i < 27; ++i) a += mi[i] * hw1[(m * 27 + i) * 15 + tid];
        A[tid] = gelu_exact(a);
    }
    __syncthreads();
    if (tid < 18) {
        float a = hb2[m * 18 + tid];
        for (int i = 0; i < 15; ++i) a += A[i] * hw2[(m * 15 + i) * 18 + tid];
        Bf[tid] = gelu_exact(a);
    }
    __syncthreads();
    if (tid == 0) {
        float a = hb3[m];
        for (int i = 0; i < 18; ++i) a += Bf[i] * hw3[m * 18 + i];
        out[b] = a;
    }
}

// ---------------------------------------------------------------------------
extern "C" void kernel_launch(void* const* d_in, const int* in_sizes, int n_in,
                              void* d_out, int out_size, void* d_ws, size_t ws_size,
                              hipStream_t stream) {
    fp in_seq     = (fp)d_in[0];
    fp proj_vars  = (fp)d_in[1];
    fp param_vars = (fp)d_in[2];
    const int* materials = (const int*)d_in[3];
    fp enc_w1 = (fp)d_in[4];
    fp enc_b1 = (fp)d_in[5];
    fp enc_w2 = (fp)d_in[6];
    fp enc_b2 = (fp)d_in[7];
    fp sos    = (fp)d_in[8];
    fp tl_wq  = (fp)d_in[9];
    fp tl_wk  = (fp)d_in[10];
    fp tl_wv  = (fp)d_in[11];
    fp tl_bq  = (fp)d_in[12];
    fp tl_bk  = (fp)d_in[13];
    fp tl_bv  = (fp)d_in[14];
    fp tl_wo  = (fp)d_in[15];
    fp tl_bo  = (fp)d_in[16];
    fp tl_ln1s = (fp)d_in[17];
    fp tl_ln1b = (fp)d_in[18];
    fp tl_ln2s = (fp)d_in[19];
    fp tl_ln2b = (fp)d_in[20];
    fp tl_fw1 = (fp)d_in[21];
    fp tl_fb1 = (fp)d_in[22];
    fp tl_fw2 = (fp)d_in[23];
    fp tl_fb2 = (fp)d_in[24];
    fp pw1 = (fp)d_in[25]; fp pb1 = (fp)d_in[26];
    fp pw2 = (fp)d_in[27]; fp pb2 = (fp)d_in[28];
    fp pw3 = (fp)d_in[29]; fp pb3 = (fp)d_in[30];
    fp pw4 = (fp)d_in[31]; fp pb4 = (fp)d_in[32];
    fp pw5 = (fp)d_in[33]; fp pb5 = (fp)d_in[34];
    fp ipw1 = (fp)d_in[35]; fp ipb1 = (fp)d_in[36];
    fp ipw2 = (fp)d_in[37]; fp ipb2 = (fp)d_in[38];
    fp hw1 = (fp)d_in[39]; fp hb1 = (fp)d_in[40];
    fp hw2 = (fp)d_in[41]; fp hb2 = (fp)d_in[42];
    fp hw3 = (fp)d_in[43]; fp hb3 = (fp)d_in[44];

    // Workspace layout (xb slot retained but unused since r20 fusion)
    float* x  = (float*)d_ws;                           // NTOK*64 fp32
    short* ob = (short*)(x + (size_t)NTOK * DD);        // NTOK*64 bf16
    short* xb = ob + (size_t)NTOK * DD;                 // NTOK*64 bf16 (unused)
    short* qb = xb + (size_t)NTOK * DD;
    short* kb = qb + (size_t)NBH * SPAD * 16;
    short* vbt = kb + (size_t)NBH * SPAD * 16;
    short* wqkvT = vbt + (size_t)NBH * 16 * SPAD;       // 3 x 12288
    short* woT = wqkvT + (size_t)NLAY * 12288;          // 3 x 4096
    short* w1T = woT + (size_t)NLAY * 4096;             // 3 x 16384
    short* w2T = w1T + (size_t)NLAY * 16384;            // 3 x 16384

    k_wconv<<<dim3(256, NLAY), 256, 0, stream>>>(
        tl_wq, tl_wk, tl_wv, tl_wo, tl_fw1, tl_fw2, wqkvT, woT, w1T, w2T,
        qb, kb, vbt);
    k_encqkv<<<NTOK / FTQ, 256, 0, stream>>>(
        in_seq, enc_w1, enc_b1, enc_w2, enc_b2, sos,
        wqkvT, tl_bq, tl_bk, tl_bv,
        x, qb, kb, vbt);

    for (int l = 0; l < NLAY; ++l) {
        k_attn<<<NBH * TGRP, 256, 0, stream>>>(qb, kb, vbt, ob);
        int ln = (l + 1 < NLAY) ? (l + 1) : l;   // dummy ptrs for last layer
        k_block<<<NTOK / FT2, 256, 0, stream>>>(
            ob, x,
            woT + (size_t)l * 4096, tl_bo + (size_t)l * DD,
            tl_ln1s + (size_t)l * DD, tl_ln1b + (size_t)l * DD,
            w1T + (size_t)l * 16384, tl_fb1 + (size_t)l * DFFC,
            w2T + (size_t)l * 16384, tl_fb2 + (size_t)l * DD,
            tl_ln2s + (size_t)l * DD, tl_ln2b + (size_t)l * DD,
            wqkvT + (size_t)ln * 12288,
            tl_bq + (size_t)ln * DD, tl_bk + (size_t)ln * DD, tl_bv + (size_t)ln * DD,
            qb, kb, vbt,
            (l + 1 < NLAY) ? 1 : 0);
    }

    k_head<<<BB, 64, 0, stream>>>(
        x, proj_vars, param_vars, materials,
        pw1, pb1, pw2, pb2, pw3, pb3, pw4, pb4, pw5, pb5,
        ipw1, ipb1, ipw2, ipb2,
        hw1, hb1, hw2, hb2, hw3, hb3,
        (float*)d_out);
}